// Round 1
// baseline (1699.203 us; speedup 1.0000x reference)
//
#include <hip/hip_runtime.h>
#include <cmath>

#define NROWS 4096   // B*L
#define H_    640
#define DIN_  1280
#define DXZ   2560
#define DTR_  40
#define DST_  16
#define LSEQ  2048
#define EPS_  1e-6f

// ---------------- reductions ----------------
__device__ __forceinline__ float block_reduce_sum256(float v, float* red) {
    int tid = threadIdx.x;
    red[tid] = v; __syncthreads();
    for (int o = 128; o; o >>= 1) { if (tid < o) red[tid] += red[tid + o]; __syncthreads(); }
    float r = red[0]; __syncthreads();
    return r;
}
__device__ __forceinline__ float block_reduce_max256(float v, float* red) {
    int tid = threadIdx.x;
    red[tid] = v; __syncthreads();
    for (int o = 128; o; o >>= 1) { if (tid < o) red[tid] = fmaxf(red[tid], red[tid + o]); __syncthreads(); }
    float r = red[0]; __syncthreads();
    return r;
}

// ---------------- alpha = max(mean|w|, 1e-10) ----------------
__global__ __launch_bounds__(256) void absmean_partial(const float* __restrict__ w, int n,
                                                       float* __restrict__ partials) {
    __shared__ float red[256];
    float s = 0.f;
    for (int i = blockIdx.x * 256 + threadIdx.x; i < n; i += gridDim.x * 256) s += fabsf(w[i]);
    red[threadIdx.x] = s; __syncthreads();
    for (int o = 128; o; o >>= 1) { if (threadIdx.x < o) red[threadIdx.x] += red[threadIdx.x + o]; __syncthreads(); }
    if (threadIdx.x == 0) partials[blockIdx.x] = red[0];
}
__global__ __launch_bounds__(256) void absmean_final(const float* __restrict__ partials, int nb, int n,
                                                     float* __restrict__ alpha_out) {
    __shared__ double red[256];
    double s = 0.0;
    for (int i = threadIdx.x; i < nb; i += 256) s += (double)partials[i];
    red[threadIdx.x] = s; __syncthreads();
    for (int o = 128; o; o >>= 1) { if (threadIdx.x < o) red[threadIdx.x] += red[threadIdx.x + o]; __syncthreads(); }
    if (threadIdx.x == 0) alpha_out[0] = fmaxf((float)(red[0] / (double)n), 1e-10f);
}
// wq = clip(round(w/alpha), -1, 1)
__global__ __launch_bounds__(256) void quant_w(const float* __restrict__ w, int n,
                                               const float* __restrict__ alpha_p, float* __restrict__ wq) {
    float a = alpha_p[0];
    for (int i = blockIdx.x * 256 + threadIdx.x; i < n; i += gridDim.x * 256)
        wq[i] = fminf(fmaxf(rintf(w[i] / a), -1.f), 1.f);
}

// ---------------- rmsnorm(x,norm_w) -> rmsnorm(.,in_nw) -> int8 quant ----------------
__global__ __launch_bounds__(256) void k_norm_quant_in(const float* __restrict__ x,
                                                       const float* __restrict__ norm_w,
                                                       const float* __restrict__ in_nw,
                                                       float* __restrict__ xq, float* __restrict__ gamma) {
    const int r = blockIdx.x, tid = threadIdx.x;
    const float* xr = x + (size_t)r * H_;
    __shared__ float red[256];
    const bool has2 = (tid < H_ - 512);
    float v0 = xr[tid], v1 = xr[tid + 256], v2 = has2 ? xr[tid + 512] : 0.f;
    float ss = v0 * v0 + v1 * v1 + v2 * v2;
    float sum = block_reduce_sum256(ss, red);
    float r1 = 1.f / sqrtf(sum / H_ + EPS_);
    v0 *= r1 * norm_w[tid];
    v1 *= r1 * norm_w[tid + 256];
    if (has2) v2 *= r1 * norm_w[tid + 512];
    ss = v0 * v0 + v1 * v1 + v2 * v2;
    sum = block_reduce_sum256(ss, red);
    float r2 = 1.f / sqrtf(sum / H_ + EPS_);
    v0 *= r2 * in_nw[tid];
    v1 *= r2 * in_nw[tid + 256];
    if (has2) v2 *= r2 * in_nw[tid + 512];
    float mx = fmaxf(fmaxf(fabsf(v0), fabsf(v1)), fabsf(v2));
    float g = fmaxf(block_reduce_max256(mx, red), 1e-10f);
    if (tid == 0) gamma[r] = g;
    float s = 127.f / g;
    float* o = xq + (size_t)r * H_;
    o[tid]       = fminf(fmaxf(rintf(v0 * s), -128.f), 127.f);
    o[tid + 256] = fminf(fmaxf(rintf(v1 * s), -128.f), 127.f);
    if (has2) o[tid + 512] = fminf(fmaxf(rintf(v2 * s), -128.f), 127.f);
}

// ---------------- generic quantized GEMM: out[r,o]=dot(Aq[r,:],Wq[o,:])*alpha*gamma[r]/127 (+res) ----
__global__ __launch_bounds__(256) void k_gemm(const float* __restrict__ Aq, const float* __restrict__ Wq,
                                              const float* __restrict__ alpha_p, const float* __restrict__ gamma,
                                              const float* __restrict__ residual, float* __restrict__ out,
                                              int M, int N, int K) {
    __shared__ float As[16][65];
    __shared__ float Ws[16][65];
    const int tid = threadIdx.x;
    const int tx = tid & 15, ty = tid >> 4;
    const int row0 = blockIdx.y * 64, col0 = blockIdx.x * 64;
    float acc[4][4] = {};
    for (int k0 = 0; k0 < K; k0 += 16) {
        for (int i = tid; i < 1024; i += 256) {
            int rr = i >> 4, kk = i & 15;
            As[kk][rr] = Aq[(size_t)(row0 + rr) * K + k0 + kk];
            Ws[kk][rr] = Wq[(size_t)(col0 + rr) * K + k0 + kk];
        }
        __syncthreads();
#pragma unroll
        for (int kk = 0; kk < 16; ++kk) {
            float a[4], b[4];
#pragma unroll
            for (int i = 0; i < 4; i++) a[i] = As[kk][ty * 4 + i];
#pragma unroll
            for (int j = 0; j < 4; j++) b[j] = Ws[kk][tx * 4 + j];
#pragma unroll
            for (int i = 0; i < 4; i++)
#pragma unroll
                for (int j = 0; j < 4; j++) acc[i][j] = fmaf(a[i], b[j], acc[i][j]);
        }
        __syncthreads();
    }
    const float alpha = alpha_p[0];
#pragma unroll
    for (int i = 0; i < 4; i++) {
        int row = row0 + ty * 4 + i;
        float s = alpha * gamma[row] * (1.f / 127.f);
#pragma unroll
        for (int j = 0; j < 4; j++) {
            int col = col0 + tx * 4 + j;
            float o = acc[i][j] * s;
            if (residual) o += residual[(size_t)row * N + col];
            out[(size_t)row * N + col] = o;
        }
    }
}

// ---------------- causal depthwise conv (k=4) + silu ----------------
__global__ __launch_bounds__(256) void k_conv_silu(const float* __restrict__ xz,
                                                   const float* __restrict__ cw, const float* __restrict__ cb,
                                                   float* __restrict__ xp) {
    size_t idx = (size_t)blockIdx.x * 256 + threadIdx.x;
    int d = (int)(idx % DIN_);
    size_t row = idx / DIN_;
    int l = (int)(row % LSEQ);
    float s = cb[d];
    const float* c = cw + (size_t)d * 4;
#pragma unroll
    for (int k = 0; k < 4; k++)
        if (l - k >= 0) s += xz[(row - (size_t)k) * DXZ + d] * c[k];
    xp[idx] = s / (1.f + expf(-s));   // silu
}

// ---------------- rmsnorm of x_path (shared) + 3 gammas (dtu/Bp/Cp) ----------------
__global__ __launch_bounds__(256) void k_norm_xp(const float* __restrict__ xp,
                                                 const float* __restrict__ dtu_nw,
                                                 const float* __restrict__ Bp_nw,
                                                 const float* __restrict__ Cp_nw,
                                                 float* __restrict__ xpn, float* __restrict__ g3) {
    const int r = blockIdx.x, tid = threadIdx.x;
    const float* xr = xp + (size_t)r * DIN_;
    __shared__ float red[256];
    float v[5];
    float ss = 0.f;
#pragma unroll
    for (int j = 0; j < 5; j++) { v[j] = xr[tid + j * 256]; ss += v[j] * v[j]; }
    float sum = block_reduce_sum256(ss, red);
    float rms = 1.f / sqrtf(sum / DIN_ + EPS_);
    float m0 = 0.f, m1 = 0.f, m2 = 0.f;
#pragma unroll
    for (int j = 0; j < 5; j++) {
        int i = tid + j * 256;
        float t = v[j] * rms;
        xpn[(size_t)r * DIN_ + i] = t;
        m0 = fmaxf(m0, fabsf(t * dtu_nw[i]));
        m1 = fmaxf(m1, fabsf(t * Bp_nw[i]));
        m2 = fmaxf(m2, fabsf(t * Cp_nw[i]));
    }
    float g0 = block_reduce_max256(m0, red);
    float g1 = block_reduce_max256(m1, red);
    float g2 = block_reduce_max256(m2, red);
    if (tid == 0) {
        g3[r]             = fmaxf(g0, 1e-10f);
        g3[NROWS + r]     = fmaxf(g1, 1e-10f);
        g3[2 * NROWS + r] = fmaxf(g2, 1e-10f);
    }
}

// ---------------- fused skinny projections: dtu(40) + Bp(16) + Cp(16) ----------------
__global__ __launch_bounds__(128) void k_skinny(const float* __restrict__ xpn,
                                                const float* __restrict__ dtu_nw,
                                                const float* __restrict__ Bp_nw,
                                                const float* __restrict__ Cp_nw,
                                                const float* __restrict__ g3,
                                                const float* __restrict__ alphas,
                                                const float* __restrict__ wq_dtu,
                                                const float* __restrict__ wq_Bp,
                                                const float* __restrict__ wq_Cp,
                                                float* __restrict__ dtu_out,
                                                float* __restrict__ Bmat, float* __restrict__ Cmat) {
    const int r = blockIdx.x, tid = threadIdx.x;
    __shared__ float q[3][DIN_];
    float g0 = g3[r], g1 = g3[NROWS + r], g2 = g3[2 * NROWS + r];
    float s0 = 127.f / g0, s1 = 127.f / g1, s2 = 127.f / g2;
    for (int i = tid; i < DIN_; i += 128) {
        float t = xpn[(size_t)r * DIN_ + i];
        q[0][i] = fminf(fmaxf(rintf(t * dtu_nw[i] * s0), -128.f), 127.f);
        q[1][i] = fminf(fmaxf(rintf(t * Bp_nw[i]  * s1), -128.f), 127.f);
        q[2][i] = fminf(fmaxf(rintf(t * Cp_nw[i]  * s2), -128.f), 127.f);
    }
    __syncthreads();
    if (tid < 72) {
        int m, o; const float* w; float g, alpha;
        if (tid < 40)      { m = 0; o = tid;      w = wq_dtu + (size_t)o * DIN_; g = g0; alpha = alphas[1]; }
        else if (tid < 56) { m = 1; o = tid - 40; w = wq_Bp  + (size_t)o * DIN_; g = g1; alpha = alphas[2]; }
        else               { m = 2; o = tid - 56; w = wq_Cp  + (size_t)o * DIN_; g = g2; alpha = alphas[3]; }
        float s = 0.f;
        for (int k = 0; k < DIN_; k++) s += q[m][k] * w[k];
        s *= alpha * g * (1.f / 127.f);
        if (m == 0)      dtu_out[(size_t)r * DTR_ + o] = s;
        else if (m == 1) Bmat[(size_t)r * DST_ + o] = s;
        else             Cmat[(size_t)r * DST_ + o] = s;
    }
}

// ---------------- dt = softplus(dtu_out @ dtd_w.T + dtd_b) ----------------
__global__ __launch_bounds__(256) void k_dtd(const float* __restrict__ dtu_out,
                                             const float* __restrict__ dtd_w,
                                             const float* __restrict__ dtd_b, float* __restrict__ dt) {
    const int r = blockIdx.x, tid = threadIdx.x;
    __shared__ float u[DTR_];
    if (tid < DTR_) u[tid] = dtu_out[(size_t)r * DTR_ + tid];
    __syncthreads();
    for (int d = tid; d < DIN_; d += 256) {
        const float* wr = dtd_w + (size_t)d * DTR_;
        float s = dtd_b[d];
#pragma unroll
        for (int t = 0; t < DTR_; t++) s += u[t] * wr[t];
        dt[(size_t)r * DIN_ + d] = (s > 0.f) ? (s + log1pf(expf(-s))) : log1pf(expf(s));
    }
}

// ---------------- selective scan + y=(y+x*D)*silu(z), LDS double-buffered chunks ----------------
#define SCH 32
__global__ __launch_bounds__(256) void k_scan(const float* __restrict__ dt, const float* __restrict__ xp,
                                              const float* __restrict__ Bm, const float* __restrict__ Cm,
                                              const float* __restrict__ xz, const float* __restrict__ A_log,
                                              const float* __restrict__ Dvec, float* __restrict__ y) {
    const int tid = threadIdx.x;
    const int g = tid >> 4;      // channel within block (0..15)
    const int n = tid & 15;      // state index
    const int blk = blockIdx.x;  // 0..159
    const int b = blk / (DIN_ / 16);
    const int d0 = (blk % (DIN_ / 16)) * 16;
    const int d = d0 + g;
    const float A = -expf(A_log[(size_t)d * DST_ + n]);
    const float Dd = Dvec[d];
    __shared__ float s_dt[2][SCH][16];
    __shared__ float s_xp[2][SCH][16];
    __shared__ float s_z [2][SCH][16];
    __shared__ float s_B [2][SCH][16];
    __shared__ float s_C [2][SCH][16];

    auto stage = [&](int c, int p) {
        int l0 = c * SCH;
        for (int i = tid; i < SCH * 16; i += 256) {
            int ll = i >> 4, dd = i & 15;
            size_t row = (size_t)(b * LSEQ + l0 + ll);
            s_dt[p][ll][dd] = dt[row * DIN_ + d0 + dd];
            s_xp[p][ll][dd] = xp[row * DIN_ + d0 + dd];
            s_z [p][ll][dd] = xz[row * DXZ + DIN_ + d0 + dd];
            s_B [p][ll][dd] = Bm[row * DST_ + dd];
            s_C [p][ll][dd] = Cm[row * DST_ + dd];
        }
    };

    float h = 0.f;
    stage(0, 0);
    __syncthreads();
    const int NC = LSEQ / SCH;
    for (int c = 0; c < NC; ++c) {
        int p = c & 1;
        if (c + 1 < NC) stage(c + 1, p ^ 1);
        for (int ll = 0; ll < SCH; ++ll) {
            float dtv = s_dt[p][ll][g];
            float xv  = s_xp[p][ll][g];
            float Bv  = s_B [p][ll][n];
            float Cv  = s_C [p][ll][n];
            float dA = expf(A * dtv);
            h = dA * h + dtv * Bv * xv;
            float contrib = h * Cv;
            contrib += __shfl_xor(contrib, 1);
            contrib += __shfl_xor(contrib, 2);
            contrib += __shfl_xor(contrib, 4);
            contrib += __shfl_xor(contrib, 8);
            if (n == 0) {
                float zv = s_z[p][ll][g];
                float yv = contrib + xv * Dd;
                yv *= zv / (1.f + expf(-zv));
                y[(size_t)(b * LSEQ + c * SCH + ll) * DIN_ + d] = yv;
            }
        }
        __syncthreads();
    }
}

// ---------------- rmsnorm(y,out_nw) + quant ----------------
__global__ __launch_bounds__(256) void k_norm_y(const float* __restrict__ y,
                                                const float* __restrict__ out_nw,
                                                float* __restrict__ yq, float* __restrict__ gy) {
    const int r = blockIdx.x, tid = threadIdx.x;
    const float* yr = y + (size_t)r * DIN_;
    __shared__ float red[256];
    float v[5];
    float ss = 0.f;
#pragma unroll
    for (int j = 0; j < 5; j++) { v[j] = yr[tid + j * 256]; ss += v[j] * v[j]; }
    float sum = block_reduce_sum256(ss, red);
    float rms = 1.f / sqrtf(sum / DIN_ + EPS_);
    float mx = 0.f;
#pragma unroll
    for (int j = 0; j < 5; j++) {
        int i = tid + j * 256;
        v[j] = v[j] * rms * out_nw[i];
        mx = fmaxf(mx, fabsf(v[j]));
    }
    float g = fmaxf(block_reduce_max256(mx, red), 1e-10f);
    if (tid == 0) gy[r] = g;
    float s = 127.f / g;
#pragma unroll
    for (int j = 0; j < 5; j++) {
        int i = tid + j * 256;
        yq[(size_t)r * DIN_ + i] = fminf(fmaxf(rintf(v[j] * s), -128.f), 127.f);
    }
}

extern "C" void kernel_launch(void* const* d_in, const int* in_sizes, int n_in,
                              void* d_out, int out_size, void* d_ws, size_t ws_size,
                              hipStream_t stream) {
    (void)in_sizes; (void)n_in; (void)out_size;
    const float* x      = (const float*)d_in[0];
    const float* norm_w = (const float*)d_in[1];
    const float* in_w   = (const float*)d_in[2];
    const float* in_nw  = (const float*)d_in[3];
    const float* conv_w = (const float*)d_in[4];
    const float* conv_b = (const float*)d_in[5];
    const float* dtu_w  = (const float*)d_in[6];
    const float* dtu_nw = (const float*)d_in[7];
    const float* dtd_w  = (const float*)d_in[8];
    const float* dtd_b  = (const float*)d_in[9];
    const float* Bp_w   = (const float*)d_in[10];
    const float* Bp_nw  = (const float*)d_in[11];
    const float* Cp_w   = (const float*)d_in[12];
    const float* Cp_nw  = (const float*)d_in[13];
    const float* A_log  = (const float*)d_in[14];
    const float* Dv     = (const float*)d_in[15];
    const float* out_w  = (const float*)d_in[16];
    const float* out_nw = (const float*)d_in[17];

    float* ws = (float*)d_ws;
    float* alphas   = ws;                      // 8
    float* partials = ws + 8;                  // 1024
    float* xq1      = ws + 1040;
    float* gamma1   = xq1 + (size_t)NROWS * H_;
    float* xz       = gamma1 + NROWS;
    float* xp       = xz + (size_t)NROWS * DXZ;
    float* xpn      = xp + (size_t)NROWS * DIN_;       // later reused as y
    float* g3       = xpn + (size_t)NROWS * DIN_;
    float* dtu_out  = g3 + 3 * NROWS;
    float* Bmat     = dtu_out + (size_t)NROWS * DTR_;
    float* Cmat     = Bmat + (size_t)NROWS * DST_;
    float* dtb      = Cmat + (size_t)NROWS * DST_;     // later reused as yq
    float* gy       = dtb + (size_t)NROWS * DIN_;
    float* wq_in    = gy + NROWS;
    float* wq_dtu   = wq_in + (size_t)DXZ * H_;
    float* wq_Bp    = wq_dtu + (size_t)DTR_ * DIN_;
    float* wq_Cp    = wq_Bp + (size_t)DST_ * DIN_;
    float* wq_out   = wq_Cp + (size_t)DST_ * DIN_;
    size_t need = (size_t)((wq_out + (size_t)H_ * DIN_) - ws) * sizeof(float);
    if (ws_size < need) return;  // insufficient scratch: fail loudly (poisoned output)

    struct WSpec { const float* w; int n; float* alpha; float* wq; };
    WSpec W[5] = {
        { in_w,  DXZ * H_,    alphas + 0, wq_in  },
        { dtu_w, DTR_ * DIN_, alphas + 1, wq_dtu },
        { Bp_w,  DST_ * DIN_, alphas + 2, wq_Bp  },
        { Cp_w,  DST_ * DIN_, alphas + 3, wq_Cp  },
        { out_w, H_ * DIN_,   alphas + 4, wq_out },
    };
    for (int i = 0; i < 5; i++) {
        int nb = (W[i].n + 255) / 256; if (nb > 256) nb = 256;
        hipLaunchKernelGGL(absmean_partial, dim3(nb), dim3(256), 0, stream, W[i].w, W[i].n, partials);
        hipLaunchKernelGGL(absmean_final, dim3(1), dim3(256), 0, stream, partials, nb, W[i].n, W[i].alpha);
        int nq = (W[i].n + 255) / 256; if (nq > 1024) nq = 1024;
        hipLaunchKernelGGL(quant_w, dim3(nq), dim3(256), 0, stream, W[i].w, W[i].n, W[i].alpha, W[i].wq);
    }

    hipLaunchKernelGGL(k_norm_quant_in, dim3(NROWS), dim3(256), 0, stream, x, norm_w, in_nw, xq1, gamma1);
    hipLaunchKernelGGL(k_gemm, dim3(DXZ / 64, NROWS / 64), dim3(256), 0, stream,
                       xq1, wq_in, alphas + 0, gamma1, (const float*)nullptr, xz, NROWS, DXZ, H_);
    hipLaunchKernelGGL(k_conv_silu, dim3((NROWS * DIN_) / 256), dim3(256), 0, stream, xz, conv_w, conv_b, xp);
    hipLaunchKernelGGL(k_norm_xp, dim3(NROWS), dim3(256), 0, stream, xp, dtu_nw, Bp_nw, Cp_nw, xpn, g3);
    hipLaunchKernelGGL(k_skinny, dim3(NROWS), dim3(128), 0, stream,
                       xpn, dtu_nw, Bp_nw, Cp_nw, g3, alphas, wq_dtu, wq_Bp, wq_Cp, dtu_out, Bmat, Cmat);
    hipLaunchKernelGGL(k_dtd, dim3(NROWS), dim3(256), 0, stream, dtu_out, dtd_w, dtd_b, dtb);
    hipLaunchKernelGGL(k_scan, dim3((2 * DIN_) / 16), dim3(256), 0, stream,
                       dtb, xp, Bmat, Cmat, xz, A_log, Dv, xpn /*y*/);
    hipLaunchKernelGGL(k_norm_y, dim3(NROWS), dim3(256), 0, stream, xpn /*y*/, out_nw, dtb /*yq*/, gy);
    hipLaunchKernelGGL(k_gemm, dim3(H_ / 64, NROWS / 64), dim3(256), 0, stream,
                       dtb /*yq*/, wq_out, alphas + 4, gy, x /*residual*/, (float*)d_out, NROWS, H_, DIN_);
}

// Round 2
// 1089.895 us; speedup vs baseline: 1.5591x; 1.5591x over previous
//
#include <hip/hip_runtime.h>
#include <cmath>

#define NROWS 4096   // B*L
#define H_    640
#define DIN_  1280
#define DXZ   2560
#define DTR_  40
#define DST_  16
#define LSEQ  2048
#define EPS_  1e-6f
#define NCH   32     // scan chunks
#define CL    64     // chunk length (NCH*CL == LSEQ)

// ---------------- reductions ----------------
__device__ __forceinline__ float block_reduce_sum256(float v, float* red) {
    int tid = threadIdx.x;
    red[tid] = v; __syncthreads();
    for (int o = 128; o; o >>= 1) { if (tid < o) red[tid] += red[tid + o]; __syncthreads(); }
    float r = red[0]; __syncthreads();
    return r;
}
__device__ __forceinline__ float block_reduce_max256(float v, float* red) {
    int tid = threadIdx.x;
    red[tid] = v; __syncthreads();
    for (int o = 128; o; o >>= 1) { if (tid < o) red[tid] = fmaxf(red[tid], red[tid + o]); __syncthreads(); }
    float r = red[0]; __syncthreads();
    return r;
}

// ---------------- batched alpha = max(mean|w|,1e-10) for 5 weights ----------------
__global__ __launch_bounds__(256) void absmean_partial5(const float* __restrict__ w0, const float* __restrict__ w1,
                                                        const float* __restrict__ w2, const float* __restrict__ w3,
                                                        const float* __restrict__ w4,
                                                        int n0, int n1, int n2, int n3, int n4,
                                                        float* __restrict__ partials /*[5][256]*/) {
    const int wi = blockIdx.y;
    const float* w = (wi == 0) ? w0 : (wi == 1) ? w1 : (wi == 2) ? w2 : (wi == 3) ? w3 : w4;
    const int n = (wi == 0) ? n0 : (wi == 1) ? n1 : (wi == 2) ? n2 : (wi == 3) ? n3 : n4;
    __shared__ float red[256];
    float s = 0.f;
    for (int i = blockIdx.x * 256 + threadIdx.x; i < n; i += gridDim.x * 256) s += fabsf(w[i]);
    red[threadIdx.x] = s; __syncthreads();
    for (int o = 128; o; o >>= 1) { if (threadIdx.x < o) red[threadIdx.x] += red[threadIdx.x + o]; __syncthreads(); }
    if (threadIdx.x == 0) partials[wi * 256 + blockIdx.x] = red[0];
}
__global__ __launch_bounds__(256) void absmean_final5(const float* __restrict__ partials,
                                                      int n0, int n1, int n2, int n3, int n4,
                                                      float* __restrict__ alphas) {
    const int wi = blockIdx.x;
    const int n = (wi == 0) ? n0 : (wi == 1) ? n1 : (wi == 2) ? n2 : (wi == 3) ? n3 : n4;
    __shared__ double red[256];
    double s = (threadIdx.x < 256) ? (double)partials[wi * 256 + threadIdx.x] : 0.0;
    red[threadIdx.x] = s; __syncthreads();
    for (int o = 128; o; o >>= 1) { if (threadIdx.x < o) red[threadIdx.x] += red[threadIdx.x + o]; __syncthreads(); }
    if (threadIdx.x == 0) alphas[wi] = fmaxf((float)(red[0] / (double)n), 1e-10f);
}
__global__ __launch_bounds__(256) void quant_w5(const float* __restrict__ w0, const float* __restrict__ w1,
                                                const float* __restrict__ w2, const float* __restrict__ w3,
                                                const float* __restrict__ w4,
                                                int n0, int n1, int n2, int n3, int n4,
                                                const float* __restrict__ alphas,
                                                float* __restrict__ q0, float* __restrict__ q1,
                                                float* __restrict__ q2, float* __restrict__ q3,
                                                float* __restrict__ q4) {
    const int wi = blockIdx.y;
    const float* w = (wi == 0) ? w0 : (wi == 1) ? w1 : (wi == 2) ? w2 : (wi == 3) ? w3 : w4;
    float* q = (wi == 0) ? q0 : (wi == 1) ? q1 : (wi == 2) ? q2 : (wi == 3) ? q3 : q4;
    const int n = (wi == 0) ? n0 : (wi == 1) ? n1 : (wi == 2) ? n2 : (wi == 3) ? n3 : n4;
    float a = alphas[wi];
    for (int i = blockIdx.x * 256 + threadIdx.x; i < n; i += gridDim.x * 256)
        q[i] = fminf(fmaxf(rintf(w[i] / a), -1.f), 1.f);
}

// ---------------- rmsnorm(x,norm_w) -> rmsnorm(.,in_nw) -> int8 quant ----------------
__global__ __launch_bounds__(256) void k_norm_quant_in(const float* __restrict__ x,
                                                       const float* __restrict__ norm_w,
                                                       const float* __restrict__ in_nw,
                                                       float* __restrict__ xq, float* __restrict__ gamma) {
    const int r = blockIdx.x, tid = threadIdx.x;
    const float* xr = x + (size_t)r * H_;
    __shared__ float red[256];
    const bool has2 = (tid < H_ - 512);
    float v0 = xr[tid], v1 = xr[tid + 256], v2 = has2 ? xr[tid + 512] : 0.f;
    float ss = v0 * v0 + v1 * v1 + v2 * v2;
    float sum = block_reduce_sum256(ss, red);
    float r1 = 1.f / sqrtf(sum / H_ + EPS_);
    v0 *= r1 * norm_w[tid];
    v1 *= r1 * norm_w[tid + 256];
    if (has2) v2 *= r1 * norm_w[tid + 512];
    ss = v0 * v0 + v1 * v1 + v2 * v2;
    sum = block_reduce_sum256(ss, red);
    float r2 = 1.f / sqrtf(sum / H_ + EPS_);
    v0 *= r2 * in_nw[tid];
    v1 *= r2 * in_nw[tid + 256];
    if (has2) v2 *= r2 * in_nw[tid + 512];
    float mx = fmaxf(fmaxf(fabsf(v0), fabsf(v1)), fabsf(v2));
    float g = fmaxf(block_reduce_max256(mx, red), 1e-10f);
    if (tid == 0) gamma[r] = g;
    float s = 127.f / g;
    float* o = xq + (size_t)r * H_;
    o[tid]       = fminf(fmaxf(rintf(v0 * s), -128.f), 127.f);
    o[tid + 256] = fminf(fmaxf(rintf(v1 * s), -128.f), 127.f);
    if (has2) o[tid + 512] = fminf(fmaxf(rintf(v2 * s), -128.f), 127.f);
}

// ---------------- generic quantized GEMM ----------------
__global__ __launch_bounds__(256) void k_gemm(const float* __restrict__ Aq, const float* __restrict__ Wq,
                                              const float* __restrict__ alpha_p, const float* __restrict__ gamma,
                                              const float* __restrict__ residual, float* __restrict__ out,
                                              int M, int N, int K) {
    __shared__ float As[16][65];
    __shared__ float Ws[16][65];
    const int tid = threadIdx.x;
    const int tx = tid & 15, ty = tid >> 4;
    const int row0 = blockIdx.y * 64, col0 = blockIdx.x * 64;
    float acc[4][4] = {};
    for (int k0 = 0; k0 < K; k0 += 16) {
        for (int i = tid; i < 1024; i += 256) {
            int rr = i >> 4, kk = i & 15;
            As[kk][rr] = Aq[(size_t)(row0 + rr) * K + k0 + kk];
            Ws[kk][rr] = Wq[(size_t)(col0 + rr) * K + k0 + kk];
        }
        __syncthreads();
#pragma unroll
        for (int kk = 0; kk < 16; ++kk) {
            float a[4], b[4];
#pragma unroll
            for (int i = 0; i < 4; i++) a[i] = As[kk][ty * 4 + i];
#pragma unroll
            for (int j = 0; j < 4; j++) b[j] = Ws[kk][tx * 4 + j];
#pragma unroll
            for (int i = 0; i < 4; i++)
#pragma unroll
                for (int j = 0; j < 4; j++) acc[i][j] = fmaf(a[i], b[j], acc[i][j]);
        }
        __syncthreads();
    }
    const float alpha = alpha_p[0];
#pragma unroll
    for (int i = 0; i < 4; i++) {
        int row = row0 + ty * 4 + i;
        float s = alpha * gamma[row] * (1.f / 127.f);
#pragma unroll
        for (int j = 0; j < 4; j++) {
            int col = col0 + tx * 4 + j;
            float o = acc[i][j] * s;
            if (residual) o += residual[(size_t)row * N + col];
            out[(size_t)row * N + col] = o;
        }
    }
}

// ---------------- causal depthwise conv (k=4) + silu ----------------
__global__ __launch_bounds__(256) void k_conv_silu(const float* __restrict__ xz,
                                                   const float* __restrict__ cw, const float* __restrict__ cb,
                                                   float* __restrict__ xp) {
    size_t idx = (size_t)blockIdx.x * 256 + threadIdx.x;
    int d = (int)(idx % DIN_);
    size_t row = idx / DIN_;
    int l = (int)(row % LSEQ);
    float s = cb[d];
    const float* c = cw + (size_t)d * 4;
#pragma unroll
    for (int k = 0; k < 4; k++)
        if (l - k >= 0) s += xz[(row - (size_t)k) * DXZ + d] * c[k];
    xp[idx] = s / (1.f + expf(-s));   // silu
}

// ---------------- rmsnorm of x_path + 3 gammas ----------------
__global__ __launch_bounds__(256) void k_norm_xp(const float* __restrict__ xp,
                                                 const float* __restrict__ dtu_nw,
                                                 const float* __restrict__ Bp_nw,
                                                 const float* __restrict__ Cp_nw,
                                                 float* __restrict__ xpn, float* __restrict__ g3) {
    const int r = blockIdx.x, tid = threadIdx.x;
    const float* xr = xp + (size_t)r * DIN_;
    __shared__ float red[256];
    float v[5];
    float ss = 0.f;
#pragma unroll
    for (int j = 0; j < 5; j++) { v[j] = xr[tid + j * 256]; ss += v[j] * v[j]; }
    float sum = block_reduce_sum256(ss, red);
    float rms = 1.f / sqrtf(sum / DIN_ + EPS_);
    float m0 = 0.f, m1 = 0.f, m2 = 0.f;
#pragma unroll
    for (int j = 0; j < 5; j++) {
        int i = tid + j * 256;
        float t = v[j] * rms;
        xpn[(size_t)r * DIN_ + i] = t;
        m0 = fmaxf(m0, fabsf(t * dtu_nw[i]));
        m1 = fmaxf(m1, fabsf(t * Bp_nw[i]));
        m2 = fmaxf(m2, fabsf(t * Cp_nw[i]));
    }
    float g0 = block_reduce_max256(m0, red);
    float g1 = block_reduce_max256(m1, red);
    float g2 = block_reduce_max256(m2, red);
    if (tid == 0) {
        g3[r]             = fmaxf(g0, 1e-10f);
        g3[NROWS + r]     = fmaxf(g1, 1e-10f);
        g3[2 * NROWS + r] = fmaxf(g2, 1e-10f);
    }
}

// ---------------- fused skinny projections ----------------
__global__ __launch_bounds__(128) void k_skinny(const float* __restrict__ xpn,
                                                const float* __restrict__ dtu_nw,
                                                const float* __restrict__ Bp_nw,
                                                const float* __restrict__ Cp_nw,
                                                const float* __restrict__ g3,
                                                const float* __restrict__ alphas,
                                                const float* __restrict__ wq_dtu,
                                                const float* __restrict__ wq_Bp,
                                                const float* __restrict__ wq_Cp,
                                                float* __restrict__ dtu_out,
                                                float* __restrict__ Bmat, float* __restrict__ Cmat) {
    const int r = blockIdx.x, tid = threadIdx.x;
    __shared__ float q[3][DIN_];
    float g0 = g3[r], g1 = g3[NROWS + r], g2 = g3[2 * NROWS + r];
    float s0 = 127.f / g0, s1 = 127.f / g1, s2 = 127.f / g2;
    for (int i = tid; i < DIN_; i += 128) {
        float t = xpn[(size_t)r * DIN_ + i];
        q[0][i] = fminf(fmaxf(rintf(t * dtu_nw[i] * s0), -128.f), 127.f);
        q[1][i] = fminf(fmaxf(rintf(t * Bp_nw[i]  * s1), -128.f), 127.f);
        q[2][i] = fminf(fmaxf(rintf(t * Cp_nw[i]  * s2), -128.f), 127.f);
    }
    __syncthreads();
    if (tid < 72) {
        int m, o; const float* w; float g, alpha;
        if (tid < 40)      { m = 0; o = tid;      w = wq_dtu + (size_t)o * DIN_; g = g0; alpha = alphas[1]; }
        else if (tid < 56) { m = 1; o = tid - 40; w = wq_Bp  + (size_t)o * DIN_; g = g1; alpha = alphas[2]; }
        else               { m = 2; o = tid - 56; w = wq_Cp  + (size_t)o * DIN_; g = g2; alpha = alphas[3]; }
        float s = 0.f;
        for (int k = 0; k < DIN_; k++) s += q[m][k] * w[k];
        s *= alpha * g * (1.f / 127.f);
        if (m == 0)      dtu_out[(size_t)r * DTR_ + o] = s;
        else if (m == 1) Bmat[(size_t)r * DST_ + o] = s;
        else             Cmat[(size_t)r * DST_ + o] = s;
    }
}

// ---------------- dt = softplus(dtu_out @ dtd_w.T + dtd_b) ----------------
__global__ __launch_bounds__(256) void k_dtd(const float* __restrict__ dtu_out,
                                             const float* __restrict__ dtd_w,
                                             const float* __restrict__ dtd_b, float* __restrict__ dt) {
    const int r = blockIdx.x, tid = threadIdx.x;
    __shared__ float u[DTR_];
    if (tid < DTR_) u[tid] = dtu_out[(size_t)r * DTR_ + tid];
    __syncthreads();
    for (int d = tid; d < DIN_; d += 256) {
        const float* wr = dtd_w + (size_t)d * DTR_;
        float s = dtd_b[d];
#pragma unroll
        for (int t = 0; t < DTR_; t++) s += u[t] * wr[t];
        dt[(size_t)r * DIN_ + d] = (s > 0.f) ? (s + log1pf(expf(-s))) : log1pf(expf(s));
    }
}

// ======== chunked selective scan ========
// Phase A: per-chunk local scan from h=0; emit final local h and P=prod(dA).
// Layout of hloc/Pp: [b][chunk][d][n]  (plane = 1280*16 = 20480)
__global__ __launch_bounds__(256) void k_scan_a(const float* __restrict__ dt, const float* __restrict__ xp,
                                                const float* __restrict__ Bm, const float* __restrict__ A_log,
                                                float* __restrict__ hloc, float* __restrict__ Pp) {
    const int blk = blockIdx.x;
    const int c = blk % NCH;
    const int dg = (blk / NCH) % (DIN_ / 16);
    const int b = blk / (NCH * (DIN_ / 16));
    const int d0 = dg * 16;
    const int tid = threadIdx.x, g = tid >> 4, n = tid & 15;
    const int d = d0 + g;
    const float A = -expf(A_log[(size_t)d * DST_ + n]);
    __shared__ float s_dt[CL][16], s_xp[CL][16], s_B[CL][16];
    const int l0 = c * CL;
    for (int i = tid; i < CL * 16; i += 256) {
        int ll = i >> 4, dd = i & 15;
        size_t row = (size_t)(b * LSEQ + l0 + ll);
        s_dt[ll][dd] = dt[row * DIN_ + d0 + dd];
        s_xp[ll][dd] = xp[row * DIN_ + d0 + dd];
        s_B[ll][dd]  = Bm[row * DST_ + dd];
    }
    __syncthreads();
    float h = 0.f, P = 1.f;
#pragma unroll 4
    for (int ll = 0; ll < CL; ++ll) {
        float dtv = s_dt[ll][g], xv = s_xp[ll][g], Bv = s_B[ll][n];
        float dA = expf(A * dtv);
        h = dA * h + dtv * Bv * xv;
        P *= dA;
    }
    size_t idx = (size_t)(b * NCH + c) * 20480 + (size_t)d0 * 16 + tid;
    hloc[idx] = h;
    Pp[idx] = P;
}

// Phase B: serial combine over chunks per (b,d,n); Hinit written in place over hloc.
__global__ __launch_bounds__(256) void k_scan_b(float* __restrict__ hloc, const float* __restrict__ Pp) {
    int i = blockIdx.x * 256 + threadIdx.x;           // 0 .. 2*20480-1
    int b = i / 20480, dn = i % 20480;
    size_t base = (size_t)b * NCH * 20480 + dn;
    float H = 0.f;
    for (int c = 0; c < NCH; ++c) {
        size_t off = base + (size_t)c * 20480;
        float hl = hloc[off], p = Pp[off];
        hloc[off] = H;                                // Hinit for chunk c
        H = p * H + hl;
    }
}

// Phase C: per-chunk scan from Hinit + C-dot + epilogue.
__global__ __launch_bounds__(256) void k_scan_c(const float* __restrict__ dt, const float* __restrict__ xp,
                                                const float* __restrict__ Bm, const float* __restrict__ Cm,
                                                const float* __restrict__ xz, const float* __restrict__ A_log,
                                                const float* __restrict__ Dvec, const float* __restrict__ Hinit,
                                                float* __restrict__ y) {
    const int blk = blockIdx.x;
    const int c = blk % NCH;
    const int dg = (blk / NCH) % (DIN_ / 16);
    const int b = blk / (NCH * (DIN_ / 16));
    const int d0 = dg * 16;
    const int tid = threadIdx.x, g = tid >> 4, n = tid & 15;
    const int d = d0 + g;
    const float A = -expf(A_log[(size_t)d * DST_ + n]);
    const float Dd = Dvec[d];
    __shared__ float s_dt[CL][16], s_xp[CL][16], s_B[CL][16], s_C[CL][16], s_z[CL][16];
    const int l0 = c * CL;
    for (int i = tid; i < CL * 16; i += 256) {
        int ll = i >> 4, dd = i & 15;
        size_t row = (size_t)(b * LSEQ + l0 + ll);
        s_dt[ll][dd] = dt[row * DIN_ + d0 + dd];
        s_xp[ll][dd] = xp[row * DIN_ + d0 + dd];
        s_B[ll][dd]  = Bm[row * DST_ + dd];
        s_C[ll][dd]  = Cm[row * DST_ + dd];
        s_z[ll][dd]  = xz[row * DXZ + DIN_ + d0 + dd];
    }
    __syncthreads();
    float h = Hinit[(size_t)(b * NCH + c) * 20480 + (size_t)d0 * 16 + tid];
    for (int ll = 0; ll < CL; ++ll) {
        float dtv = s_dt[ll][g], xv = s_xp[ll][g];
        float Bv = s_B[ll][n], Cv = s_C[ll][n];
        float dA = expf(A * dtv);
        h = dA * h + dtv * Bv * xv;
        float contrib = h * Cv;
        contrib += __shfl_xor(contrib, 1);
        contrib += __shfl_xor(contrib, 2);
        contrib += __shfl_xor(contrib, 4);
        contrib += __shfl_xor(contrib, 8);
        if (n == 0) {
            float zv = s_z[ll][g];
            float yv = contrib + xv * Dd;
            yv *= zv / (1.f + expf(-zv));
            y[(size_t)(b * LSEQ + l0 + ll) * DIN_ + d] = yv;
        }
    }
}

// ---------------- rmsnorm(y,out_nw) + quant ----------------
__global__ __launch_bounds__(256) void k_norm_y(const float* __restrict__ y,
                                                const float* __restrict__ out_nw,
                                                float* __restrict__ yq, float* __restrict__ gy) {
    const int r = blockIdx.x, tid = threadIdx.x;
    const float* yr = y + (size_t)r * DIN_;
    __shared__ float red[256];
    float v[5];
    float ss = 0.f;
#pragma unroll
    for (int j = 0; j < 5; j++) { v[j] = yr[tid + j * 256]; ss += v[j] * v[j]; }
    float sum = block_reduce_sum256(ss, red);
    float rms = 1.f / sqrtf(sum / DIN_ + EPS_);
    float mx = 0.f;
#pragma unroll
    for (int j = 0; j < 5; j++) {
        int i = tid + j * 256;
        v[j] = v[j] * rms * out_nw[i];
        mx = fmaxf(mx, fabsf(v[j]));
    }
    float g = fmaxf(block_reduce_max256(mx, red), 1e-10f);
    if (tid == 0) gy[r] = g;
    float s = 127.f / g;
#pragma unroll
    for (int j = 0; j < 5; j++) {
        int i = tid + j * 256;
        yq[(size_t)r * DIN_ + i] = fminf(fmaxf(rintf(v[j] * s), -128.f), 127.f);
    }
}

extern "C" void kernel_launch(void* const* d_in, const int* in_sizes, int n_in,
                              void* d_out, int out_size, void* d_ws, size_t ws_size,
                              hipStream_t stream) {
    (void)in_sizes; (void)n_in; (void)out_size;
    const float* x      = (const float*)d_in[0];
    const float* norm_w = (const float*)d_in[1];
    const float* in_w   = (const float*)d_in[2];
    const float* in_nw  = (const float*)d_in[3];
    const float* conv_w = (const float*)d_in[4];
    const float* conv_b = (const float*)d_in[5];
    const float* dtu_w  = (const float*)d_in[6];
    const float* dtu_nw = (const float*)d_in[7];
    const float* dtd_w  = (const float*)d_in[8];
    const float* dtd_b  = (const float*)d_in[9];
    const float* Bp_w   = (const float*)d_in[10];
    const float* Bp_nw  = (const float*)d_in[11];
    const float* Cp_w   = (const float*)d_in[12];
    const float* Cp_nw  = (const float*)d_in[13];
    const float* A_log  = (const float*)d_in[14];
    const float* Dv     = (const float*)d_in[15];
    const float* out_w  = (const float*)d_in[16];
    const float* out_nw = (const float*)d_in[17];

    float* ws = (float*)d_ws;
    float* alphas   = ws;                      // 8
    float* partials = ws + 8;                  // 5*256
    float* xq1      = ws + 8 + 5 * 256;        // 4096*640 — later reused as hloc/Pp
    float* gamma1   = xq1 + (size_t)NROWS * H_;
    float* xz       = gamma1 + NROWS;
    float* xp       = xz + (size_t)NROWS * DXZ;
    float* xpn      = xp + (size_t)NROWS * DIN_;       // later reused as y
    float* g3       = xpn + (size_t)NROWS * DIN_;
    float* dtu_out  = g3 + 3 * NROWS;
    float* Bmat     = dtu_out + (size_t)NROWS * DTR_;
    float* Cmat     = Bmat + (size_t)NROWS * DST_;
    float* dtb      = Cmat + (size_t)NROWS * DST_;     // later reused as yq
    float* gy       = dtb + (size_t)NROWS * DIN_;
    float* wq_in    = gy + NROWS;
    float* wq_dtu   = wq_in + (size_t)DXZ * H_;
    float* wq_Bp    = wq_dtu + (size_t)DTR_ * DIN_;
    float* wq_Cp    = wq_Bp + (size_t)DST_ * DIN_;
    float* wq_out   = wq_Cp + (size_t)DST_ * DIN_;
    size_t need = (size_t)((wq_out + (size_t)H_ * DIN_) - ws) * sizeof(float);
    if (ws_size < need) return;

    // scan scratch overlays dead xq1 region: hloc+Pp = 2*(2*32*20480) = 2.62M floats = |xq1|
    float* hloc = xq1;
    float* Pp   = xq1 + (size_t)2 * NCH * 20480;

    // ---- batched weight quant (3 launches instead of 15) ----
    const int n0 = DXZ * H_, n1 = DTR_ * DIN_, n2 = DST_ * DIN_, n3 = DST_ * DIN_, n4 = H_ * DIN_;
    hipLaunchKernelGGL(absmean_partial5, dim3(256, 5), dim3(256), 0, stream,
                       in_w, dtu_w, Bp_w, Cp_w, out_w, n0, n1, n2, n3, n4, partials);
    hipLaunchKernelGGL(absmean_final5, dim3(5), dim3(256), 0, stream, partials, n0, n1, n2, n3, n4, alphas);
    hipLaunchKernelGGL(quant_w5, dim3((n0 + 255) / 256, 5), dim3(256), 0, stream,
                       in_w, dtu_w, Bp_w, Cp_w, out_w, n0, n1, n2, n3, n4, alphas,
                       wq_in, wq_dtu, wq_Bp, wq_Cp, wq_out);

    hipLaunchKernelGGL(k_norm_quant_in, dim3(NROWS), dim3(256), 0, stream, x, norm_w, in_nw, xq1, gamma1);
    hipLaunchKernelGGL(k_gemm, dim3(DXZ / 64, NROWS / 64), dim3(256), 0, stream,
                       xq1, wq_in, alphas + 0, gamma1, (const float*)nullptr, xz, NROWS, DXZ, H_);
    hipLaunchKernelGGL(k_conv_silu, dim3((NROWS * DIN_) / 256), dim3(256), 0, stream, xz, conv_w, conv_b, xp);
    hipLaunchKernelGGL(k_norm_xp, dim3(NROWS), dim3(256), 0, stream, xp, dtu_nw, Bp_nw, Cp_nw, xpn, g3);
    hipLaunchKernelGGL(k_skinny, dim3(NROWS), dim3(128), 0, stream,
                       xpn, dtu_nw, Bp_nw, Cp_nw, g3, alphas, wq_dtu, wq_Bp, wq_Cp, dtu_out, Bmat, Cmat);
    hipLaunchKernelGGL(k_dtd, dim3(NROWS), dim3(256), 0, stream, dtu_out, dtd_w, dtd_b, dtb);

    // ---- chunked scan (xq1 dead by now; hloc/Pp overlay it) ----
    hipLaunchKernelGGL(k_scan_a, dim3(2 * (DIN_ / 16) * NCH), dim3(256), 0, stream,
                       dtb, xp, Bmat, A_log, hloc, Pp);
    hipLaunchKernelGGL(k_scan_b, dim3((2 * 20480) / 256), dim3(256), 0, stream, hloc, Pp);
    hipLaunchKernelGGL(k_scan_c, dim3(2 * (DIN_ / 16) * NCH), dim3(256), 0, stream,
                       dtb, xp, Bmat, Cmat, xz, A_log, Dv, hloc, xpn /*y*/);

    hipLaunchKernelGGL(k_norm_y, dim3(NROWS), dim3(256), 0, stream, xpn /*y*/, out_nw, dtb /*yq*/, gy);
    hipLaunchKernelGGL(k_gemm, dim3(H_ / 64, NROWS / 64), dim3(256), 0, stream,
                       dtb /*yq*/, wq_out, alphas + 4, gy, x /*residual*/, (float*)d_out, NROWS, H_, DIN_);
}

// Round 3
// 595.440 us; speedup vs baseline: 2.8537x; 1.8304x over previous
//
#include <hip/hip_runtime.h>
#include <hip/hip_bf16.h>
#include <cmath>

#define NROWS 4096   // B*L
#define H_    640
#define DIN_  1280
#define DXZ   2560
#define DTR_  40
#define DST_  16
#define LSEQ  2048
#define EPS_  1e-6f
#define NCH   32     // scan chunks
#define CL    64     // chunk length (NCH*CL == LSEQ)

typedef __attribute__((ext_vector_type(8))) short short8;
typedef __attribute__((ext_vector_type(4))) float f32x4;
typedef unsigned short ushort_t;

// async global->LDS, 16B per lane; LDS dest = wave-uniform base + lane*16
#define GLD16(gp, lp) __builtin_amdgcn_global_load_lds( \
    (const __attribute__((address_space(1))) unsigned int*)(unsigned long long)(gp), \
    (__attribute__((address_space(3))) unsigned int*)(unsigned int)(unsigned long long)(lp), 16, 0, 0)

// ---------------- reductions ----------------
__device__ __forceinline__ float block_reduce_sum256(float v, float* red) {
    int tid = threadIdx.x;
    red[tid] = v; __syncthreads();
    for (int o = 128; o; o >>= 1) { if (tid < o) red[tid] += red[tid + o]; __syncthreads(); }
    float r = red[0]; __syncthreads();
    return r;
}
__device__ __forceinline__ float block_reduce_max256(float v, float* red) {
    int tid = threadIdx.x;
    red[tid] = v; __syncthreads();
    for (int o = 128; o; o >>= 1) { if (tid < o) red[tid] = fmaxf(red[tid], red[tid + o]); __syncthreads(); }
    float r = red[0]; __syncthreads();
    return r;
}

// ---------------- batched alpha = max(mean|w|,1e-10) for 5 weights ----------------
__global__ __launch_bounds__(256) void absmean_partial5(const float* __restrict__ w0, const float* __restrict__ w1,
                                                        const float* __restrict__ w2, const float* __restrict__ w3,
                                                        const float* __restrict__ w4,
                                                        int n0, int n1, int n2, int n3, int n4,
                                                        float* __restrict__ partials) {
    const int wi = blockIdx.y;
    const float* w = (wi == 0) ? w0 : (wi == 1) ? w1 : (wi == 2) ? w2 : (wi == 3) ? w3 : w4;
    const int n = (wi == 0) ? n0 : (wi == 1) ? n1 : (wi == 2) ? n2 : (wi == 3) ? n3 : n4;
    __shared__ float red[256];
    float s = 0.f;
    for (int i = blockIdx.x * 256 + threadIdx.x; i < n; i += gridDim.x * 256) s += fabsf(w[i]);
    red[threadIdx.x] = s; __syncthreads();
    for (int o = 128; o; o >>= 1) { if (threadIdx.x < o) red[threadIdx.x] += red[threadIdx.x + o]; __syncthreads(); }
    if (threadIdx.x == 0) partials[wi * 256 + blockIdx.x] = red[0];
}
__global__ __launch_bounds__(256) void absmean_final5(const float* __restrict__ partials,
                                                      int n0, int n1, int n2, int n3, int n4,
                                                      float* __restrict__ alphas) {
    const int wi = blockIdx.x;
    const int n = (wi == 0) ? n0 : (wi == 1) ? n1 : (wi == 2) ? n2 : (wi == 3) ? n3 : n4;
    __shared__ double red[256];
    double s = (double)partials[wi * 256 + threadIdx.x];
    red[threadIdx.x] = s; __syncthreads();
    for (int o = 128; o; o >>= 1) { if (threadIdx.x < o) red[threadIdx.x] += red[threadIdx.x + o]; __syncthreads(); }
    if (threadIdx.x == 0) alphas[wi] = fmaxf((float)(red[0] / (double)n), 1e-10f);
}
// quantized ternary weights, stored as bf16 (exact for {-1,0,1})
__global__ __launch_bounds__(256) void quant_w5(const float* __restrict__ w0, const float* __restrict__ w1,
                                                const float* __restrict__ w2, const float* __restrict__ w3,
                                                const float* __restrict__ w4,
                                                int n0, int n1, int n2, int n3, int n4,
                                                const float* __restrict__ alphas,
                                                __hip_bfloat16* __restrict__ q0, __hip_bfloat16* __restrict__ q1,
                                                __hip_bfloat16* __restrict__ q2, __hip_bfloat16* __restrict__ q3,
                                                __hip_bfloat16* __restrict__ q4) {
    const int wi = blockIdx.y;
    const float* w = (wi == 0) ? w0 : (wi == 1) ? w1 : (wi == 2) ? w2 : (wi == 3) ? w3 : w4;
    __hip_bfloat16* q = (wi == 0) ? q0 : (wi == 1) ? q1 : (wi == 2) ? q2 : (wi == 3) ? q3 : q4;
    const int n = (wi == 0) ? n0 : (wi == 1) ? n1 : (wi == 2) ? n2 : (wi == 3) ? n3 : n4;
    float a = alphas[wi];
    for (int i = blockIdx.x * 256 + threadIdx.x; i < n; i += gridDim.x * 256)
        q[i] = __float2bfloat16(fminf(fmaxf(rintf(w[i] / a), -1.f), 1.f));
}

// ---------------- rmsnorm(x,norm_w) -> rmsnorm(.,in_nw) -> int8 quant (bf16 out) ----------------
__global__ __launch_bounds__(256) void k_norm_quant_in(const float* __restrict__ x,
                                                       const float* __restrict__ norm_w,
                                                       const float* __restrict__ in_nw,
                                                       __hip_bfloat16* __restrict__ xq, float* __restrict__ gamma) {
    const int r = blockIdx.x, tid = threadIdx.x;
    const float* xr = x + (size_t)r * H_;
    __shared__ float red[256];
    const bool has2 = (tid < H_ - 512);
    float v0 = xr[tid], v1 = xr[tid + 256], v2 = has2 ? xr[tid + 512] : 0.f;
    float ss = v0 * v0 + v1 * v1 + v2 * v2;
    float sum = block_reduce_sum256(ss, red);
    float r1 = 1.f / sqrtf(sum / H_ + EPS_);
    v0 *= r1 * norm_w[tid];
    v1 *= r1 * norm_w[tid + 256];
    if (has2) v2 *= r1 * norm_w[tid + 512];
    ss = v0 * v0 + v1 * v1 + v2 * v2;
    sum = block_reduce_sum256(ss, red);
    float r2 = 1.f / sqrtf(sum / H_ + EPS_);
    v0 *= r2 * in_nw[tid];
    v1 *= r2 * in_nw[tid + 256];
    if (has2) v2 *= r2 * in_nw[tid + 512];
    float mx = fmaxf(fmaxf(fabsf(v0), fabsf(v1)), fabsf(v2));
    float g = fmaxf(block_reduce_max256(mx, red), 1e-10f);
    if (tid == 0) gamma[r] = g;
    float s = 127.f / g;
    __hip_bfloat16* o = xq + (size_t)r * H_;
    o[tid]       = __float2bfloat16(fminf(fmaxf(rintf(v0 * s), -128.f), 127.f));
    o[tid + 256] = __float2bfloat16(fminf(fmaxf(rintf(v1 * s), -128.f), 127.f));
    if (has2) o[tid + 512] = __float2bfloat16(fminf(fmaxf(rintf(v2 * s), -128.f), 127.f));
}

// ---------------- MFMA bf16 quantized GEMM (m97 structure, 128x128 tile, BK=32) ----------------
// Aq: [M][K] bf16 (int values), Wq: [N][K] bf16 (ternary). out[r][c] = dot*alpha*gamma[r]/127 (+res)
__global__ __launch_bounds__(256) void k_gemm_mfma(const ushort_t* __restrict__ Aq,
                                                   const ushort_t* __restrict__ Wq,
                                                   const float* __restrict__ alpha_p,
                                                   const float* __restrict__ gamma,
                                                   const float* __restrict__ residual,
                                                   float* __restrict__ out,
                                                   int M, int N, int K) {
    __shared__ ushort_t As[128 * 32];   // swizzled [row][slot^(row&3)][8]
    __shared__ ushort_t Bs[128 * 32];
    const int tid = threadIdx.x;
    const int w = tid >> 6, lane = tid & 63;
    const int wm = w >> 1, wn = w & 1;
    const int row0 = blockIdx.y * 128, col0 = blockIdx.x * 128;
    f32x4 acc[4][4] = {};

    for (int k0 = 0; k0 < K; k0 += 32) {
        // stage A+B tiles: per wave 2 chunks of 64 lanes x 16B each, per tile
        #pragma unroll
        for (int q = 0; q < 2; ++q) {
            int c = w * 128 + q * 64 + lane;        // chunk id 0..511
            int row = c >> 2;
            int uslot = (c & 3) ^ (row & 3);        // inverse swizzle on global source
            const ushort_t* ga = Aq + (size_t)(row0 + row) * K + k0 + uslot * 8;
            GLD16(ga, (char*)As + (w * 2048 + q * 1024));
            const ushort_t* gb = Wq + (size_t)(col0 + row) * K + k0 + uslot * 8;
            GLD16(gb, (char*)Bs + (w * 2048 + q * 1024));
        }
        asm volatile("s_waitcnt vmcnt(0)" ::: "memory");
        __syncthreads();

        short8 a[4], b[4];
        #pragma unroll
        for (int i = 0; i < 4; ++i) {
            int row = wm * 64 + i * 16 + (lane & 15);
            int byt = row * 64 + ((((lane >> 4)) ^ (row & 3)) << 4);
            a[i] = *(const short8*)((const char*)As + byt);
        }
        #pragma unroll
        for (int j = 0; j < 4; ++j) {
            int row = wn * 64 + j * 16 + (lane & 15);
            int byt = row * 64 + ((((lane >> 4)) ^ (row & 3)) << 4);
            b[j] = *(const short8*)((const char*)Bs + byt);
        }
        #pragma unroll
        for (int i = 0; i < 4; ++i)
            #pragma unroll
            for (int j = 0; j < 4; ++j)
                acc[i][j] = __builtin_amdgcn_mfma_f32_16x16x32_bf16(a[i], b[j], acc[i][j], 0, 0, 0);
        __syncthreads();
    }

    const float alpha = alpha_p[0];
    #pragma unroll
    for (int i = 0; i < 4; ++i) {
        #pragma unroll
        for (int r = 0; r < 4; ++r) {
            int row = row0 + wm * 64 + i * 16 + (lane >> 4) * 4 + r;
            float s = alpha * gamma[row] * (1.f / 127.f);
            #pragma unroll
            for (int j = 0; j < 4; ++j) {
                int col = col0 + wn * 64 + j * 16 + (lane & 15);
                float o = acc[i][j][r] * s;
                if (residual) o += residual[(size_t)row * N + col];
                out[(size_t)row * N + col] = o;
            }
        }
    }
}

// ---------------- causal depthwise conv (k=4) + silu ----------------
__global__ __launch_bounds__(256) void k_conv_silu(const float* __restrict__ xz,
                                                   const float* __restrict__ cw, const float* __restrict__ cb,
                                                   float* __restrict__ xp) {
    size_t idx = (size_t)blockIdx.x * 256 + threadIdx.x;
    int d = (int)(idx % DIN_);
    size_t row = idx / DIN_;
    int l = (int)(row % LSEQ);
    float s = cb[d];
    const float* c = cw + (size_t)d * 4;
#pragma unroll
    for (int k = 0; k < 4; k++)
        if (l - k >= 0) s += xz[(row - (size_t)k) * DXZ + d] * c[k];
    xp[idx] = s / (1.f + expf(-s));   // silu
}

// ---------------- rmsnorm of x_path + 3 gammas ----------------
__global__ __launch_bounds__(256) void k_norm_xp(const float* __restrict__ xp,
                                                 const float* __restrict__ dtu_nw,
                                                 const float* __restrict__ Bp_nw,
                                                 const float* __restrict__ Cp_nw,
                                                 float* __restrict__ xpn, float* __restrict__ g3) {
    const int r = blockIdx.x, tid = threadIdx.x;
    const float* xr = xp + (size_t)r * DIN_;
    __shared__ float red[256];
    float v[5];
    float ss = 0.f;
#pragma unroll
    for (int j = 0; j < 5; j++) { v[j] = xr[tid + j * 256]; ss += v[j] * v[j]; }
    float sum = block_reduce_sum256(ss, red);
    float rms = 1.f / sqrtf(sum / DIN_ + EPS_);
    float m0 = 0.f, m1 = 0.f, m2 = 0.f;
#pragma unroll
    for (int j = 0; j < 5; j++) {
        int i = tid + j * 256;
        float t = v[j] * rms;
        xpn[(size_t)r * DIN_ + i] = t;
        m0 = fmaxf(m0, fabsf(t * dtu_nw[i]));
        m1 = fmaxf(m1, fabsf(t * Bp_nw[i]));
        m2 = fmaxf(m2, fabsf(t * Cp_nw[i]));
    }
    float g0 = block_reduce_max256(m0, red);
    float g1 = block_reduce_max256(m1, red);
    float g2 = block_reduce_max256(m2, red);
    if (tid == 0) {
        g3[r]             = fmaxf(g0, 1e-10f);
        g3[NROWS + r]     = fmaxf(g1, 1e-10f);
        g3[2 * NROWS + r] = fmaxf(g2, 1e-10f);
    }
}

// ---------------- fused skinny projections (bf16 ternary weights) ----------------
__global__ __launch_bounds__(128) void k_skinny(const float* __restrict__ xpn,
                                                const float* __restrict__ dtu_nw,
                                                const float* __restrict__ Bp_nw,
                                                const float* __restrict__ Cp_nw,
                                                const float* __restrict__ g3,
                                                const float* __restrict__ alphas,
                                                const __hip_bfloat16* __restrict__ wq_dtu,
                                                const __hip_bfloat16* __restrict__ wq_Bp,
                                                const __hip_bfloat16* __restrict__ wq_Cp,
                                                float* __restrict__ dtu_out,
                                                float* __restrict__ Bmat, float* __restrict__ Cmat) {
    const int r = blockIdx.x, tid = threadIdx.x;
    __shared__ float q[3][DIN_];
    float g0 = g3[r], g1 = g3[NROWS + r], g2 = g3[2 * NROWS + r];
    float s0 = 127.f / g0, s1 = 127.f / g1, s2 = 127.f / g2;
    for (int i = tid; i < DIN_; i += 128) {
        float t = xpn[(size_t)r * DIN_ + i];
        q[0][i] = fminf(fmaxf(rintf(t * dtu_nw[i] * s0), -128.f), 127.f);
        q[1][i] = fminf(fmaxf(rintf(t * Bp_nw[i]  * s1), -128.f), 127.f);
        q[2][i] = fminf(fmaxf(rintf(t * Cp_nw[i]  * s2), -128.f), 127.f);
    }
    __syncthreads();
    if (tid < 72) {
        int m, o; const __hip_bfloat16* w; float g, alpha;
        if (tid < 40)      { m = 0; o = tid;      w = wq_dtu + (size_t)o * DIN_; g = g0; alpha = alphas[1]; }
        else if (tid < 56) { m = 1; o = tid - 40; w = wq_Bp  + (size_t)o * DIN_; g = g1; alpha = alphas[2]; }
        else               { m = 2; o = tid - 56; w = wq_Cp  + (size_t)o * DIN_; g = g2; alpha = alphas[3]; }
        float s = 0.f;
        for (int k = 0; k < DIN_; k++) s += q[m][k] * __bfloat162float(w[k]);
        s *= alpha * g * (1.f / 127.f);
        if (m == 0)      dtu_out[(size_t)r * DTR_ + o] = s;
        else if (m == 1) Bmat[(size_t)r * DST_ + o] = s;
        else             Cmat[(size_t)r * DST_ + o] = s;
    }
}

// ---------------- dt = softplus(dtu_out @ dtd_w.T + dtd_b) ----------------
__global__ __launch_bounds__(256) void k_dtd(const float* __restrict__ dtu_out,
                                             const float* __restrict__ dtd_w,
                                             const float* __restrict__ dtd_b, float* __restrict__ dt) {
    const int r = blockIdx.x, tid = threadIdx.x;
    __shared__ float u[DTR_];
    if (tid < DTR_) u[tid] = dtu_out[(size_t)r * DTR_ + tid];
    __syncthreads();
    for (int d = tid; d < DIN_; d += 256) {
        const float* wr = dtd_w + (size_t)d * DTR_;
        float s = dtd_b[d];
#pragma unroll
        for (int t = 0; t < DTR_; t++) s += u[t] * wr[t];
        dt[(size_t)r * DIN_ + d] = (s > 0.f) ? (s + log1pf(expf(-s))) : log1pf(expf(s));
    }
}

// ======== chunked selective scan ========
__global__ __launch_bounds__(256) void k_scan_a(const float* __restrict__ dt, const float* __restrict__ xp,
                                                const float* __restrict__ Bm, const float* __restrict__ A_log,
                                                float* __restrict__ hloc, float* __restrict__ Pp) {
    const int blk = blockIdx.x;
    const int c = blk % NCH;
    const int dg = (blk / NCH) % (DIN_ / 16);
    const int b = blk / (NCH * (DIN_ / 16));
    const int d0 = dg * 16;
    const int tid = threadIdx.x, g = tid >> 4, n = tid & 15;
    const int d = d0 + g;
    const float A = -expf(A_log[(size_t)d * DST_ + n]);
    __shared__ float s_dt[CL][16], s_xp[CL][16], s_B[CL][16];
    const int l0 = c * CL;
    for (int i = tid; i < CL * 16; i += 256) {
        int ll = i >> 4, dd = i & 15;
        size_t row = (size_t)(b * LSEQ + l0 + ll);
        s_dt[ll][dd] = dt[row * DIN_ + d0 + dd];
        s_xp[ll][dd] = xp[row * DIN_ + d0 + dd];
        s_B[ll][dd]  = Bm[row * DST_ + dd];
    }
    __syncthreads();
    float h = 0.f, P = 1.f;
#pragma unroll 4
    for (int ll = 0; ll < CL; ++ll) {
        float dtv = s_dt[ll][g], xv = s_xp[ll][g], Bv = s_B[ll][n];
        float dA = expf(A * dtv);
        h = dA * h + dtv * Bv * xv;
        P *= dA;
    }
    size_t idx = (size_t)(b * NCH + c) * 20480 + (size_t)d0 * 16 + tid;
    hloc[idx] = h;
    Pp[idx] = P;
}

__global__ __launch_bounds__(256) void k_scan_b(float* __restrict__ hloc, const float* __restrict__ Pp) {
    int i = blockIdx.x * 256 + threadIdx.x;
    int b = i / 20480, dn = i % 20480;
    size_t base = (size_t)b * NCH * 20480 + dn;
    float H = 0.f;
    for (int c = 0; c < NCH; ++c) {
        size_t off = base + (size_t)c * 20480;
        float hl = hloc[off], p = Pp[off];
        hloc[off] = H;
        H = p * H + hl;
    }
}

__global__ __launch_bounds__(256) void k_scan_c(const float* __restrict__ dt, const float* __restrict__ xp,
                                                const float* __restrict__ Bm, const float* __restrict__ Cm,
                                                const float* __restrict__ xz, const float* __restrict__ A_log,
                                                const float* __restrict__ Dvec, const float* __restrict__ Hinit,
                                                float* __restrict__ y) {
    const int blk = blockIdx.x;
    const int c = blk % NCH;
    const int dg = (blk / NCH) % (DIN_ / 16);
    const int b = blk / (NCH * (DIN_ / 16));
    const int d0 = dg * 16;
    const int tid = threadIdx.x, g = tid >> 4, n = tid & 15;
    const int d = d0 + g;
    const float A = -expf(A_log[(size_t)d * DST_ + n]);
    const float Dd = Dvec[d];
    __shared__ float s_dt[CL][16], s_xp[CL][16], s_B[CL][16], s_C[CL][16], s_z[CL][16];
    const int l0 = c * CL;
    for (int i = tid; i < CL * 16; i += 256) {
        int ll = i >> 4, dd = i & 15;
        size_t row = (size_t)(b * LSEQ + l0 + ll);
        s_dt[ll][dd] = dt[row * DIN_ + d0 + dd];
        s_xp[ll][dd] = xp[row * DIN_ + d0 + dd];
        s_B[ll][dd]  = Bm[row * DST_ + dd];
        s_C[ll][dd]  = Cm[row * DST_ + dd];
        s_z[ll][dd]  = xz[row * DXZ + DIN_ + d0 + dd];
    }
    __syncthreads();
    float h = Hinit[(size_t)(b * NCH + c) * 20480 + (size_t)d0 * 16 + tid];
    for (int ll = 0; ll < CL; ++ll) {
        float dtv = s_dt[ll][g], xv = s_xp[ll][g];
        float Bv = s_B[ll][n], Cv = s_C[ll][n];
        float dA = expf(A * dtv);
        h = dA * h + dtv * Bv * xv;
        float contrib = h * Cv;
        contrib += __shfl_xor(contrib, 1);
        contrib += __shfl_xor(contrib, 2);
        contrib += __shfl_xor(contrib, 4);
        contrib += __shfl_xor(contrib, 8);
        if (n == 0) {
            float zv = s_z[ll][g];
            float yv = contrib + xv * Dd;
            yv *= zv / (1.f + expf(-zv));
            y[(size_t)(b * LSEQ + l0 + ll) * DIN_ + d] = yv;
        }
    }
}

// ---------------- rmsnorm(y,out_nw) + quant (bf16 out) ----------------
__global__ __launch_bounds__(256) void k_norm_y(const float* __restrict__ y,
                                                const float* __restrict__ out_nw,
                                                __hip_bfloat16* __restrict__ yq, float* __restrict__ gy) {
    const int r = blockIdx.x, tid = threadIdx.x;
    const float* yr = y + (size_t)r * DIN_;
    __shared__ float red[256];
    float v[5];
    float ss = 0.f;
#pragma unroll
    for (int j = 0; j < 5; j++) { v[j] = yr[tid + j * 256]; ss += v[j] * v[j]; }
    float sum = block_reduce_sum256(ss, red);
    float rms = 1.f / sqrtf(sum / DIN_ + EPS_);
    float mx = 0.f;
#pragma unroll
    for (int j = 0; j < 5; j++) {
        int i = tid + j * 256;
        v[j] = v[j] * rms * out_nw[i];
        mx = fmaxf(mx, fabsf(v[j]));
    }
    float g = fmaxf(block_reduce_max256(mx, red), 1e-10f);
    if (tid == 0) gy[r] = g;
    float s = 127.f / g;
#pragma unroll
    for (int j = 0; j < 5; j++) {
        int i = tid + j * 256;
        yq[(size_t)r * DIN_ + i] = __float2bfloat16(fminf(fmaxf(rintf(v[j] * s), -128.f), 127.f));
    }
}

extern "C" void kernel_launch(void* const* d_in, const int* in_sizes, int n_in,
                              void* d_out, int out_size, void* d_ws, size_t ws_size,
                              hipStream_t stream) {
    (void)in_sizes; (void)n_in; (void)out_size;
    const float* x      = (const float*)d_in[0];
    const float* norm_w = (const float*)d_in[1];
    const float* in_w   = (const float*)d_in[2];
    const float* in_nw  = (const float*)d_in[3];
    const float* conv_w = (const float*)d_in[4];
    const float* conv_b = (const float*)d_in[5];
    const float* dtu_w  = (const float*)d_in[6];
    const float* dtu_nw = (const float*)d_in[7];
    const float* dtd_w  = (const float*)d_in[8];
    const float* dtd_b  = (const float*)d_in[9];
    const float* Bp_w   = (const float*)d_in[10];
    const float* Bp_nw  = (const float*)d_in[11];
    const float* Cp_w   = (const float*)d_in[12];
    const float* Cp_nw  = (const float*)d_in[13];
    const float* A_log  = (const float*)d_in[14];
    const float* Dv     = (const float*)d_in[15];
    const float* out_w  = (const float*)d_in[16];
    const float* out_nw = (const float*)d_in[17];

    float* ws = (float*)d_ws;
    float* alphas   = ws;                      // 8
    float* partials = ws + 8;                  // 5*256
    float* xq1      = ws + 8 + 5 * 256;        // bf16 activations live here; later reused as hloc/Pp
    float* gamma1   = xq1 + (size_t)NROWS * H_;
    float* xz       = gamma1 + NROWS;
    float* xp       = xz + (size_t)NROWS * DXZ;
    float* xpn      = xp + (size_t)NROWS * DIN_;       // later reused as y
    float* g3       = xpn + (size_t)NROWS * DIN_;
    float* dtu_out  = g3 + 3 * NROWS;
    float* Bmat     = dtu_out + (size_t)NROWS * DTR_;
    float* Cmat     = Bmat + (size_t)NROWS * DST_;
    float* dtb      = Cmat + (size_t)NROWS * DST_;     // later reused as yq (bf16)
    float* gy       = dtb + (size_t)NROWS * DIN_;
    float* wq_in    = gy + NROWS;                      // bf16
    float* wq_dtu   = wq_in + (size_t)DXZ * H_;        // bf16
    float* wq_Bp    = wq_dtu + (size_t)DTR_ * DIN_;    // bf16
    float* wq_Cp    = wq_Bp + (size_t)DST_ * DIN_;     // bf16
    float* wq_out   = wq_Cp + (size_t)DST_ * DIN_;     // bf16
    size_t need = (size_t)((wq_out + (size_t)H_ * DIN_) - ws) * sizeof(float);
    if (ws_size < need) return;

    float* hloc = xq1;
    float* Pp   = xq1 + (size_t)2 * NCH * 20480;

    const int n0 = DXZ * H_, n1 = DTR_ * DIN_, n2 = DST_ * DIN_, n3 = DST_ * DIN_, n4 = H_ * DIN_;
    hipLaunchKernelGGL(absmean_partial5, dim3(256, 5), dim3(256), 0, stream,
                       in_w, dtu_w, Bp_w, Cp_w, out_w, n0, n1, n2, n3, n4, partials);
    hipLaunchKernelGGL(absmean_final5, dim3(5), dim3(256), 0, stream, partials, n0, n1, n2, n3, n4, alphas);
    hipLaunchKernelGGL(quant_w5, dim3((n0 + 255) / 256, 5), dim3(256), 0, stream,
                       in_w, dtu_w, Bp_w, Cp_w, out_w, n0, n1, n2, n3, n4, alphas,
                       (__hip_bfloat16*)wq_in, (__hip_bfloat16*)wq_dtu, (__hip_bfloat16*)wq_Bp,
                       (__hip_bfloat16*)wq_Cp, (__hip_bfloat16*)wq_out);

    hipLaunchKernelGGL(k_norm_quant_in, dim3(NROWS), dim3(256), 0, stream,
                       x, norm_w, in_nw, (__hip_bfloat16*)xq1, gamma1);
    hipLaunchKernelGGL(k_gemm_mfma, dim3(DXZ / 128, NROWS / 128), dim3(256), 0, stream,
                       (const ushort_t*)xq1, (const ushort_t*)wq_in, alphas + 0, gamma1,
                       (const float*)nullptr, xz, NROWS, DXZ, H_);
    hipLaunchKernelGGL(k_conv_silu, dim3((NROWS * DIN_) / 256), dim3(256), 0, stream, xz, conv_w, conv_b, xp);
    hipLaunchKernelGGL(k_norm_xp, dim3(NROWS), dim3(256), 0, stream, xp, dtu_nw, Bp_nw, Cp_nw, xpn, g3);
    hipLaunchKernelGGL(k_skinny, dim3(NROWS), dim3(128), 0, stream,
                       xpn, dtu_nw, Bp_nw, Cp_nw, g3, alphas,
                       (const __hip_bfloat16*)wq_dtu, (const __hip_bfloat16*)wq_Bp,
                       (const __hip_bfloat16*)wq_Cp, dtu_out, Bmat, Cmat);
    hipLaunchKernelGGL(k_dtd, dim3(NROWS), dim3(256), 0, stream, dtu_out, dtd_w, dtd_b, dtb);

    hipLaunchKernelGGL(k_scan_a, dim3(2 * (DIN_ / 16) * NCH), dim3(256), 0, stream,
                       dtb, xp, Bmat, A_log, hloc, Pp);
    hipLaunchKernelGGL(k_scan_b, dim3((2 * 20480) / 256), dim3(256), 0, stream, hloc, Pp);
    hipLaunchKernelGGL(k_scan_c, dim3(2 * (DIN_ / 16) * NCH), dim3(256), 0, stream,
                       dtb, xp, Bmat, Cmat, xz, A_log, Dv, hloc, xpn /*y*/);

    hipLaunchKernelGGL(k_norm_y, dim3(NROWS), dim3(256), 0, stream, xpn /*y*/, out_nw,
                       (__hip_bfloat16*)dtb /*yq*/, gy);
    hipLaunchKernelGGL(k_gemm_mfma, dim3(H_ / 128, NROWS / 128), dim3(256), 0, stream,
                       (const ushort_t*)dtb /*yq*/, (const ushort_t*)wq_out, alphas + 4, gy,
                       x /*residual*/, (float*)d_out, NROWS, H_, DIN_);
}

// Round 4
// 481.294 us; speedup vs baseline: 3.5305x; 1.2372x over previous
//
#include <hip/hip_runtime.h>
#include <hip/hip_bf16.h>
#include <cmath>

#define NROWS 4096   // B*L
#define H_    640
#define DIN_  1280
#define DXZ   2560
#define DTR_  40
#define DST_  16
#define LSEQ  2048
#define EPS_  1e-6f
#define NCH   32     // scan chunks
#define CL    64     // chunk length (NCH*CL == LSEQ)

typedef __attribute__((ext_vector_type(8))) short short8;
typedef __attribute__((ext_vector_type(4))) float f32x4;
typedef unsigned short ushort_t;

__device__ __forceinline__ float bf2f(short u) {
    return __uint_as_float((unsigned)(unsigned short)u << 16);
}

// async global->LDS, 16B per lane; LDS dest = wave-uniform base + lane*16
#define GLD16(gp, lp) __builtin_amdgcn_global_load_lds( \
    (const __attribute__((address_space(1))) unsigned int*)(unsigned long long)(gp), \
    (__attribute__((address_space(3))) unsigned int*)(unsigned int)(unsigned long long)(lp), 16, 0, 0)

// ---------------- reductions ----------------
__device__ __forceinline__ float block_reduce_sum256(float v, float* red) {
    int tid = threadIdx.x;
    red[tid] = v; __syncthreads();
    for (int o = 128; o; o >>= 1) { if (tid < o) red[tid] += red[tid + o]; __syncthreads(); }
    float r = red[0]; __syncthreads();
    return r;
}
__device__ __forceinline__ float block_reduce_max256(float v, float* red) {
    int tid = threadIdx.x;
    red[tid] = v; __syncthreads();
    for (int o = 128; o; o >>= 1) { if (tid < o) red[tid] = fmaxf(red[tid], red[tid + o]); __syncthreads(); }
    float r = red[0]; __syncthreads();
    return r;
}

// ---------------- batched alpha = max(mean|w|,1e-10) for 5 weights ----------------
__global__ __launch_bounds__(256) void absmean_partial5(const float* __restrict__ w0, const float* __restrict__ w1,
                                                        const float* __restrict__ w2, const float* __restrict__ w3,
                                                        const float* __restrict__ w4,
                                                        int n0, int n1, int n2, int n3, int n4,
                                                        float* __restrict__ partials) {
    const int wi = blockIdx.y;
    const float* w = (wi == 0) ? w0 : (wi == 1) ? w1 : (wi == 2) ? w2 : (wi == 3) ? w3 : w4;
    const int n = (wi == 0) ? n0 : (wi == 1) ? n1 : (wi == 2) ? n2 : (wi == 3) ? n3 : n4;
    __shared__ float red[256];
    float s = 0.f;
    for (int i = blockIdx.x * 256 + threadIdx.x; i < n; i += gridDim.x * 256) s += fabsf(w[i]);
    red[threadIdx.x] = s; __syncthreads();
    for (int o = 128; o; o >>= 1) { if (threadIdx.x < o) red[threadIdx.x] += red[threadIdx.x + o]; __syncthreads(); }
    if (threadIdx.x == 0) partials[wi * 256 + blockIdx.x] = red[0];
}
__global__ __launch_bounds__(256) void absmean_final5(const float* __restrict__ partials,
                                                      int n0, int n1, int n2, int n3, int n4,
                                                      float* __restrict__ alphas) {
    const int wi = blockIdx.x;
    const int n = (wi == 0) ? n0 : (wi == 1) ? n1 : (wi == 2) ? n2 : (wi == 3) ? n3 : n4;
    __shared__ double red[256];
    double s = (double)partials[wi * 256 + threadIdx.x];
    red[threadIdx.x] = s; __syncthreads();
    for (int o = 128; o; o >>= 1) { if (threadIdx.x < o) red[threadIdx.x] += red[threadIdx.x + o]; __syncthreads(); }
    if (threadIdx.x == 0) alphas[wi] = fmaxf((float)(red[0] / (double)n), 1e-10f);
}
// quantized ternary weights, stored as bf16 (exact for {-1,0,1})
__global__ __launch_bounds__(256) void quant_w5(const float* __restrict__ w0, const float* __restrict__ w1,
                                                const float* __restrict__ w2, const float* __restrict__ w3,
                                                const float* __restrict__ w4,
                                                int n0, int n1, int n2, int n3, int n4,
                                                const float* __restrict__ alphas,
                                                __hip_bfloat16* __restrict__ q0, __hip_bfloat16* __restrict__ q1,
                                                __hip_bfloat16* __restrict__ q2, __hip_bfloat16* __restrict__ q3,
                                                __hip_bfloat16* __restrict__ q4) {
    const int wi = blockIdx.y;
    const float* w = (wi == 0) ? w0 : (wi == 1) ? w1 : (wi == 2) ? w2 : (wi == 3) ? w3 : w4;
    __hip_bfloat16* q = (wi == 0) ? q0 : (wi == 1) ? q1 : (wi == 2) ? q2 : (wi == 3) ? q3 : q4;
    const int n = (wi == 0) ? n0 : (wi == 1) ? n1 : (wi == 2) ? n2 : (wi == 3) ? n3 : n4;
    float a = alphas[wi];
    for (int i = blockIdx.x * 256 + threadIdx.x; i < n; i += gridDim.x * 256)
        q[i] = __float2bfloat16(fminf(fmaxf(rintf(w[i] / a), -1.f), 1.f));
}

// ---------------- rmsnorm(x,norm_w) -> rmsnorm(.,in_nw) -> int8 quant (bf16 out) ----------------
__global__ __launch_bounds__(256) void k_norm_quant_in(const float* __restrict__ x,
                                                       const float* __restrict__ norm_w,
                                                       const float* __restrict__ in_nw,
                                                       __hip_bfloat16* __restrict__ xq, float* __restrict__ gamma) {
    const int r = blockIdx.x, tid = threadIdx.x;
    const float* xr = x + (size_t)r * H_;
    __shared__ float red[256];
    const bool has2 = (tid < H_ - 512);
    float v0 = xr[tid], v1 = xr[tid + 256], v2 = has2 ? xr[tid + 512] : 0.f;
    float ss = v0 * v0 + v1 * v1 + v2 * v2;
    float sum = block_reduce_sum256(ss, red);
    float r1 = 1.f / sqrtf(sum / H_ + EPS_);
    v0 *= r1 * norm_w[tid];
    v1 *= r1 * norm_w[tid + 256];
    if (has2) v2 *= r1 * norm_w[tid + 512];
    ss = v0 * v0 + v1 * v1 + v2 * v2;
    sum = block_reduce_sum256(ss, red);
    float r2 = 1.f / sqrtf(sum / H_ + EPS_);
    v0 *= r2 * in_nw[tid];
    v1 *= r2 * in_nw[tid + 256];
    if (has2) v2 *= r2 * in_nw[tid + 512];
    float mx = fmaxf(fmaxf(fabsf(v0), fabsf(v1)), fabsf(v2));
    float g = fmaxf(block_reduce_max256(mx, red), 1e-10f);
    if (tid == 0) gamma[r] = g;
    float s = 127.f / g;
    __hip_bfloat16* o = xq + (size_t)r * H_;
    o[tid]       = __float2bfloat16(fminf(fmaxf(rintf(v0 * s), -128.f), 127.f));
    o[tid + 256] = __float2bfloat16(fminf(fmaxf(rintf(v1 * s), -128.f), 127.f));
    if (has2) o[tid + 512] = __float2bfloat16(fminf(fmaxf(rintf(v2 * s), -128.f), 127.f));
}

// ---------------- MFMA bf16 quantized GEMM (m97 structure, 128x128 tile, BK=32) ----------------
__global__ __launch_bounds__(256) void k_gemm_mfma(const ushort_t* __restrict__ Aq,
                                                   const ushort_t* __restrict__ Wq,
                                                   const float* __restrict__ alpha_p,
                                                   const float* __restrict__ gamma,
                                                   const float* __restrict__ residual,
                                                   float* __restrict__ out,
                                                   int M, int N, int K) {
    __shared__ ushort_t As[128 * 32];   // swizzled [row][slot^(row&3)][8]
    __shared__ ushort_t Bs[128 * 32];
    const int tid = threadIdx.x;
    const int w = tid >> 6, lane = tid & 63;
    const int wm = w >> 1, wn = w & 1;
    const int row0 = blockIdx.y * 128, col0 = blockIdx.x * 128;
    f32x4 acc[4][4] = {};

    for (int k0 = 0; k0 < K; k0 += 32) {
        #pragma unroll
        for (int q = 0; q < 2; ++q) {
            int c = w * 128 + q * 64 + lane;        // chunk id 0..511
            int row = c >> 2;
            int uslot = (c & 3) ^ (row & 3);        // inverse swizzle on global source
            const ushort_t* ga = Aq + (size_t)(row0 + row) * K + k0 + uslot * 8;
            GLD16(ga, (char*)As + (w * 2048 + q * 1024));
            const ushort_t* gb = Wq + (size_t)(col0 + row) * K + k0 + uslot * 8;
            GLD16(gb, (char*)Bs + (w * 2048 + q * 1024));
        }
        asm volatile("s_waitcnt vmcnt(0)" ::: "memory");
        __syncthreads();

        short8 a[4], b[4];
        #pragma unroll
        for (int i = 0; i < 4; ++i) {
            int row = wm * 64 + i * 16 + (lane & 15);
            int byt = row * 64 + ((((lane >> 4)) ^ (row & 3)) << 4);
            a[i] = *(const short8*)((const char*)As + byt);
        }
        #pragma unroll
        for (int j = 0; j < 4; ++j) {
            int row = wn * 64 + j * 16 + (lane & 15);
            int byt = row * 64 + ((((lane >> 4)) ^ (row & 3)) << 4);
            b[j] = *(const short8*)((const char*)Bs + byt);
        }
        #pragma unroll
        for (int i = 0; i < 4; ++i)
            #pragma unroll
            for (int j = 0; j < 4; ++j)
                acc[i][j] = __builtin_amdgcn_mfma_f32_16x16x32_bf16(a[i], b[j], acc[i][j], 0, 0, 0);
        __syncthreads();
    }

    const float alpha = alpha_p[0];
    #pragma unroll
    for (int i = 0; i < 4; ++i) {
        #pragma unroll
        for (int r = 0; r < 4; ++r) {
            int row = row0 + wm * 64 + i * 16 + (lane >> 4) * 4 + r;
            float s = alpha * gamma[row] * (1.f / 127.f);
            #pragma unroll
            for (int j = 0; j < 4; ++j) {
                int col = col0 + wn * 64 + j * 16 + (lane & 15);
                float o = acc[i][j][r] * s;
                if (residual) o += residual[(size_t)row * N + col];
                out[(size_t)row * N + col] = o;
            }
        }
    }
}

// ---------------- causal depthwise conv (k=4) + silu ----------------
__global__ __launch_bounds__(256) void k_conv_silu(const float* __restrict__ xz,
                                                   const float* __restrict__ cw, const float* __restrict__ cb,
                                                   float* __restrict__ xp) {
    size_t idx = (size_t)blockIdx.x * 256 + threadIdx.x;
    int d = (int)(idx % DIN_);
    size_t row = idx / DIN_;
    int l = (int)(row % LSEQ);
    float s = cb[d];
    const float* c = cw + (size_t)d * 4;
#pragma unroll
    for (int k = 0; k < 4; k++)
        if (l - k >= 0) s += xz[(row - (size_t)k) * DXZ + d] * c[k];
    xp[idx] = s / (1.f + expf(-s));   // silu
}

// ---------------- rmsnorm of x_path + 3 gammas ----------------
__global__ __launch_bounds__(256) void k_norm_xp(const float* __restrict__ xp,
                                                 const float* __restrict__ dtu_nw,
                                                 const float* __restrict__ Bp_nw,
                                                 const float* __restrict__ Cp_nw,
                                                 float* __restrict__ xpn, float* __restrict__ g3) {
    const int r = blockIdx.x, tid = threadIdx.x;
    const float* xr = xp + (size_t)r * DIN_;
    __shared__ float red[256];
    float v[5];
    float ss = 0.f;
#pragma unroll
    for (int j = 0; j < 5; j++) { v[j] = xr[tid + j * 256]; ss += v[j] * v[j]; }
    float sum = block_reduce_sum256(ss, red);
    float rms = 1.f / sqrtf(sum / DIN_ + EPS_);
    float m0 = 0.f, m1 = 0.f, m2 = 0.f;
#pragma unroll
    for (int j = 0; j < 5; j++) {
        int i = tid + j * 256;
        float t = v[j] * rms;
        xpn[(size_t)r * DIN_ + i] = t;
        m0 = fmaxf(m0, fabsf(t * dtu_nw[i]));
        m1 = fmaxf(m1, fabsf(t * Bp_nw[i]));
        m2 = fmaxf(m2, fabsf(t * Cp_nw[i]));
    }
    float g0 = block_reduce_max256(m0, red);
    float g1 = block_reduce_max256(m1, red);
    float g2 = block_reduce_max256(m2, red);
    if (tid == 0) {
        g3[r]             = fmaxf(g0, 1e-10f);
        g3[NROWS + r]     = fmaxf(g1, 1e-10f);
        g3[2 * NROWS + r] = fmaxf(g2, 1e-10f);
    }
}

// ---------------- fused skinny projections (vectorized, 4 accumulators) ----------------
__global__ __launch_bounds__(128) void k_skinny(const float* __restrict__ xpn,
                                                const float* __restrict__ dtu_nw,
                                                const float* __restrict__ Bp_nw,
                                                const float* __restrict__ Cp_nw,
                                                const float* __restrict__ g3,
                                                const float* __restrict__ alphas,
                                                const __hip_bfloat16* __restrict__ wq_dtu,
                                                const __hip_bfloat16* __restrict__ wq_Bp,
                                                const __hip_bfloat16* __restrict__ wq_Cp,
                                                float* __restrict__ dtu_out,
                                                float* __restrict__ Bmat, float* __restrict__ Cmat) {
    const int r = blockIdx.x, tid = threadIdx.x;
    __shared__ float q[3][DIN_];
    float g0 = g3[r], g1 = g3[NROWS + r], g2 = g3[2 * NROWS + r];
    float s0 = 127.f / g0, s1 = 127.f / g1, s2 = 127.f / g2;
    for (int i = tid; i < DIN_; i += 128) {
        float t = xpn[(size_t)r * DIN_ + i];
        q[0][i] = fminf(fmaxf(rintf(t * dtu_nw[i] * s0), -128.f), 127.f);
        q[1][i] = fminf(fmaxf(rintf(t * Bp_nw[i]  * s1), -128.f), 127.f);
        q[2][i] = fminf(fmaxf(rintf(t * Cp_nw[i]  * s2), -128.f), 127.f);
    }
    __syncthreads();
    if (tid < 72) {
        int m, o; const __hip_bfloat16* w; float g, alpha;
        if (tid < 40)      { m = 0; o = tid;      w = wq_dtu + (size_t)o * DIN_; g = g0; alpha = alphas[1]; }
        else if (tid < 56) { m = 1; o = tid - 40; w = wq_Bp  + (size_t)o * DIN_; g = g1; alpha = alphas[2]; }
        else               { m = 2; o = tid - 56; w = wq_Cp  + (size_t)o * DIN_; g = g2; alpha = alphas[3]; }
        const ushort_t* wp = (const ushort_t*)w;
        float a0 = 0.f, a1 = 0.f, a2 = 0.f, a3 = 0.f;
        for (int k = 0; k < DIN_; k += 8) {
            short8 wv = *(const short8*)(wp + k);
            f32x4 q0v = *(const f32x4*)(&q[m][k]);
            f32x4 q1v = *(const f32x4*)(&q[m][k + 4]);
            a0 = fmaf(q0v[0], bf2f(wv[0]), a0);
            a1 = fmaf(q0v[1], bf2f(wv[1]), a1);
            a2 = fmaf(q0v[2], bf2f(wv[2]), a2);
            a3 = fmaf(q0v[3], bf2f(wv[3]), a3);
            a0 = fmaf(q1v[0], bf2f(wv[4]), a0);
            a1 = fmaf(q1v[1], bf2f(wv[5]), a1);
            a2 = fmaf(q1v[2], bf2f(wv[6]), a2);
            a3 = fmaf(q1v[3], bf2f(wv[7]), a3);
        }
        float s = ((a0 + a1) + (a2 + a3)) * alpha * g * (1.f / 127.f);
        if (m == 0)      dtu_out[(size_t)r * DTR_ + o] = s;
        else if (m == 1) Bmat[(size_t)r * DST_ + o] = s;
        else             Cmat[(size_t)r * DST_ + o] = s;
    }
}

// ---------------- dt = softplus(U @ W^T + b), LDS-tiled rank-40 GEMM ----------------
// U: [4096][40], W: [1280][40]. grid (1280/256, 4096/32), block 256.
__global__ __launch_bounds__(256) void k_dtd(const float* __restrict__ U,
                                             const float* __restrict__ W,
                                             const float* __restrict__ bias, float* __restrict__ dt) {
    const int c0 = blockIdx.x * 256;
    const int r0 = blockIdx.y * 32;
    const int tid = threadIdx.x;
    __shared__ float s_w[256 * 41];
    __shared__ float s_u[32 * 40];
    for (int i = tid; i < 256 * 40; i += 256) {
        int cc = i / 40, t = i - cc * 40;
        s_w[cc * 41 + t] = W[(size_t)c0 * 40 + i];       // coalesced
    }
    for (int i = tid; i < 32 * 40; i += 256) s_u[i] = U[(size_t)r0 * 40 + i];
    __syncthreads();
    float w[40];
#pragma unroll
    for (int t = 0; t < 40; t++) w[t] = s_w[tid * 41 + t];  // lane stride 41 -> conflict-free
    const float b = bias[c0 + tid];
    for (int r = 0; r < 32; ++r) {
        const float* ur = s_u + r * 40;
        float a0 = b, a1 = 0.f, a2 = 0.f, a3 = 0.f;
#pragma unroll
        for (int t = 0; t < 40; t += 4) {
            f32x4 uv = *(const f32x4*)(ur + t);          // broadcast b128 read
            a0 = fmaf(uv[0], w[t],     a0);
            a1 = fmaf(uv[1], w[t + 1], a1);
            a2 = fmaf(uv[2], w[t + 2], a2);
            a3 = fmaf(uv[3], w[t + 3], a3);
        }
        float s = (a0 + a1) + (a2 + a3);
        float sp = (s > 0.f) ? (s + log1pf(expf(-s))) : log1pf(expf(s));
        dt[(size_t)(r0 + r) * DIN_ + c0 + tid] = sp;     // coalesced
    }
}

// ======== chunked selective scan ========
__global__ __launch_bounds__(256) void k_scan_a(const float* __restrict__ dt, const float* __restrict__ xp,
                                                const float* __restrict__ Bm, const float* __restrict__ A_log,
                                                float* __restrict__ hloc, float* __restrict__ Pp) {
    const int blk = blockIdx.x;
    const int c = blk % NCH;
    const int dg = (blk / NCH) % (DIN_ / 16);
    const int b = blk / (NCH * (DIN_ / 16));
    const int d0 = dg * 16;
    const int tid = threadIdx.x, g = tid >> 4, n = tid & 15;
    const int d = d0 + g;
    const float A = -expf(A_log[(size_t)d * DST_ + n]);
    __shared__ float s_dt[CL][16], s_xp[CL][16], s_B[CL][16];
    const int l0 = c * CL;
    for (int i = tid; i < CL * 16; i += 256) {
        int ll = i >> 4, dd = i & 15;
        size_t row = (size_t)(b * LSEQ + l0 + ll);
        s_dt[ll][dd] = dt[row * DIN_ + d0 + dd];
        s_xp[ll][dd] = xp[row * DIN_ + d0 + dd];
        s_B[ll][dd]  = Bm[row * DST_ + dd];
    }
    __syncthreads();
    float h = 0.f, P = 1.f;
#pragma unroll 4
    for (int ll = 0; ll < CL; ++ll) {
        float dtv = s_dt[ll][g], xv = s_xp[ll][g], Bv = s_B[ll][n];
        float dA = expf(A * dtv);
        h = dA * h + dtv * Bv * xv;
        P *= dA;
    }
    size_t idx = (size_t)(b * NCH + c) * 20480 + (size_t)d0 * 16 + tid;
    hloc[idx] = h;
    Pp[idx] = P;
}

__global__ __launch_bounds__(256) void k_scan_b(float* __restrict__ hloc, const float* __restrict__ Pp) {
    int i = blockIdx.x * 256 + threadIdx.x;
    int b = i / 20480, dn = i % 20480;
    size_t base = (size_t)b * NCH * 20480 + dn;
    float H = 0.f;
    for (int c = 0; c < NCH; ++c) {
        size_t off = base + (size_t)c * 20480;
        float hl = hloc[off], p = Pp[off];
        hloc[off] = H;
        H = p * H + hl;
    }
}

__global__ __launch_bounds__(256) void k_scan_c(const float* __restrict__ dt, const float* __restrict__ xp,
                                                const float* __restrict__ Bm, const float* __restrict__ Cm,
                                                const float* __restrict__ xz, const float* __restrict__ A_log,
                                                const float* __restrict__ Dvec, const float* __restrict__ Hinit,
                                                float* __restrict__ y) {
    const int blk = blockIdx.x;
    const int c = blk % NCH;
    const int dg = (blk / NCH) % (DIN_ / 16);
    const int b = blk / (NCH * (DIN_ / 16));
    const int d0 = dg * 16;
    const int tid = threadIdx.x, g = tid >> 4, n = tid & 15;
    const int d = d0 + g;
    const float A = -expf(A_log[(size_t)d * DST_ + n]);
    const float Dd = Dvec[d];
    __shared__ float s_dt[CL][16], s_xp[CL][16], s_B[CL][16], s_C[CL][16], s_z[CL][16];
    const int l0 = c * CL;
    for (int i = tid; i < CL * 16; i += 256) {
        int ll = i >> 4, dd = i & 15;
        size_t row = (size_t)(b * LSEQ + l0 + ll);
        s_dt[ll][dd] = dt[row * DIN_ + d0 + dd];
        s_xp[ll][dd] = xp[row * DIN_ + d0 + dd];
        s_B[ll][dd]  = Bm[row * DST_ + dd];
        s_C[ll][dd]  = Cm[row * DST_ + dd];
        s_z[ll][dd]  = xz[row * DXZ + DIN_ + d0 + dd];
    }
    __syncthreads();
    float h = Hinit[(size_t)(b * NCH + c) * 20480 + (size_t)d0 * 16 + tid];
    for (int ll = 0; ll < CL; ++ll) {
        float dtv = s_dt[ll][g], xv = s_xp[ll][g];
        float Bv = s_B[ll][n], Cv = s_C[ll][n];
        float dA = expf(A * dtv);
        h = dA * h + dtv * Bv * xv;
        float contrib = h * Cv;
        contrib += __shfl_xor(contrib, 1);
        contrib += __shfl_xor(contrib, 2);
        contrib += __shfl_xor(contrib, 4);
        contrib += __shfl_xor(contrib, 8);
        if (n == 0) {
            float zv = s_z[ll][g];
            float yv = contrib + xv * Dd;
            yv *= zv / (1.f + expf(-zv));
            y[(size_t)(b * LSEQ + l0 + ll) * DIN_ + d] = yv;
        }
    }
}

// ---------------- rmsnorm(y,out_nw) + quant (bf16 out) ----------------
__global__ __launch_bounds__(256) void k_norm_y(const float* __restrict__ y,
                                                const float* __restrict__ out_nw,
                                                __hip_bfloat16* __restrict__ yq, float* __restrict__ gy) {
    const int r = blockIdx.x, tid = threadIdx.x;
    const float* yr = y + (size_t)r * DIN_;
    __shared__ float red[256];
    float v[5];
    float ss = 0.f;
#pragma unroll
    for (int j = 0; j < 5; j++) { v[j] = yr[tid + j * 256]; ss += v[j] * v[j]; }
    float sum = block_reduce_sum256(ss, red);
    float rms = 1.f / sqrtf(sum / DIN_ + EPS_);
    float mx = 0.f;
#pragma unroll
    for (int j = 0; j < 5; j++) {
        int i = tid + j * 256;
        v[j] = v[j] * rms * out_nw[i];
        mx = fmaxf(mx, fabsf(v[j]));
    }
    float g = fmaxf(block_reduce_max256(mx, red), 1e-10f);
    if (tid == 0) gy[r] = g;
    float s = 127.f / g;
#pragma unroll
    for (int j = 0; j < 5; j++) {
        int i = tid + j * 256;
        yq[(size_t)r * DIN_ + i] = __float2bfloat16(fminf(fmaxf(rintf(v[j] * s), -128.f), 127.f));
    }
}

extern "C" void kernel_launch(void* const* d_in, const int* in_sizes, int n_in,
                              void* d_out, int out_size, void* d_ws, size_t ws_size,
                              hipStream_t stream) {
    (void)in_sizes; (void)n_in; (void)out_size;
    const float* x      = (const float*)d_in[0];
    const float* norm_w = (const float*)d_in[1];
    const float* in_w   = (const float*)d_in[2];
    const float* in_nw  = (const float*)d_in[3];
    const float* conv_w = (const float*)d_in[4];
    const float* conv_b = (const float*)d_in[5];
    const float* dtu_w  = (const float*)d_in[6];
    const float* dtu_nw = (const float*)d_in[7];
    const float* dtd_w  = (const float*)d_in[8];
    const float* dtd_b  = (const float*)d_in[9];
    const float* Bp_w   = (const float*)d_in[10];
    const float* Bp_nw  = (const float*)d_in[11];
    const float* Cp_w   = (const float*)d_in[12];
    const float* Cp_nw  = (const float*)d_in[13];
    const float* A_log  = (const float*)d_in[14];
    const float* Dv     = (const float*)d_in[15];
    const float* out_w  = (const float*)d_in[16];
    const float* out_nw = (const float*)d_in[17];

    float* ws = (float*)d_ws;
    float* alphas   = ws;                      // 8
    float* partials = ws + 8;                  // 5*256
    float* xq1      = ws + 8 + 5 * 256;        // bf16 activations; later reused as hloc/Pp
    float* gamma1   = xq1 + (size_t)NROWS * H_;
    float* xz       = gamma1 + NROWS;
    float* xp       = xz + (size_t)NROWS * DXZ;
    float* xpn      = xp + (size_t)NROWS * DIN_;       // later reused as y
    float* g3       = xpn + (size_t)NROWS * DIN_;
    float* dtu_out  = g3 + 3 * NROWS;
    float* Bmat     = dtu_out + (size_t)NROWS * DTR_;
    float* Cmat     = Bmat + (size_t)NROWS * DST_;
    float* dtb      = Cmat + (size_t)NROWS * DST_;     // later reused as yq (bf16)
    float* gy       = dtb + (size_t)NROWS * DIN_;
    float* wq_in    = gy + NROWS;                      // bf16
    float* wq_dtu   = wq_in + (size_t)DXZ * H_;        // bf16
    float* wq_Bp    = wq_dtu + (size_t)DTR_ * DIN_;    // bf16
    float* wq_Cp    = wq_Bp + (size_t)DST_ * DIN_;     // bf16
    float* wq_out   = wq_Cp + (size_t)DST_ * DIN_;     // bf16
    size_t need = (size_t)((wq_out + (size_t)H_ * DIN_) - ws) * sizeof(float);
    if (ws_size < need) return;

    float* hloc = xq1;
    float* Pp   = xq1 + (size_t)2 * NCH * 20480;

    const int n0 = DXZ * H_, n1 = DTR_ * DIN_, n2 = DST_ * DIN_, n3 = DST_ * DIN_, n4 = H_ * DIN_;
    hipLaunchKernelGGL(absmean_partial5, dim3(256, 5), dim3(256), 0, stream,
                       in_w, dtu_w, Bp_w, Cp_w, out_w, n0, n1, n2, n3, n4, partials);
    hipLaunchKernelGGL(absmean_final5, dim3(5), dim3(256), 0, stream, partials, n0, n1, n2, n3, n4, alphas);
    hipLaunchKernelGGL(quant_w5, dim3((n0 + 255) / 256, 5), dim3(256), 0, stream,
                       in_w, dtu_w, Bp_w, Cp_w, out_w, n0, n1, n2, n3, n4, alphas,
                       (__hip_bfloat16*)wq_in, (__hip_bfloat16*)wq_dtu, (__hip_bfloat16*)wq_Bp,
                       (__hip_bfloat16*)wq_Cp, (__hip_bfloat16*)wq_out);

    hipLaunchKernelGGL(k_norm_quant_in, dim3(NROWS), dim3(256), 0, stream,
                       x, norm_w, in_nw, (__hip_bfloat16*)xq1, gamma1);
    hipLaunchKernelGGL(k_gemm_mfma, dim3(DXZ / 128, NROWS / 128), dim3(256), 0, stream,
                       (const ushort_t*)xq1, (const ushort_t*)wq_in, alphas + 0, gamma1,
                       (const float*)nullptr, xz, NROWS, DXZ, H_);
    hipLaunchKernelGGL(k_conv_silu, dim3((NROWS * DIN_) / 256), dim3(256), 0, stream, xz, conv_w, conv_b, xp);
    hipLaunchKernelGGL(k_norm_xp, dim3(NROWS), dim3(256), 0, stream, xp, dtu_nw, Bp_nw, Cp_nw, xpn, g3);
    hipLaunchKernelGGL(k_skinny, dim3(NROWS), dim3(128), 0, stream,
                       xpn, dtu_nw, Bp_nw, Cp_nw, g3, alphas,
                       (const __hip_bfloat16*)wq_dtu, (const __hip_bfloat16*)wq_Bp,
                       (const __hip_bfloat16*)wq_Cp, dtu_out, Bmat, Cmat);
    hipLaunchKernelGGL(k_dtd, dim3(DIN_ / 256, NROWS / 32), dim3(256), 0, stream,
                       dtu_out, dtd_w, dtd_b, dtb);

    hipLaunchKernelGGL(k_scan_a, dim3(2 * (DIN_ / 16) * NCH), dim3(256), 0, stream,
                       dtb, xp, Bmat, A_log, hloc, Pp);
    hipLaunchKernelGGL(k_scan_b, dim3((2 * 20480) / 256), dim3(256), 0, stream, hloc, Pp);
    hipLaunchKernelGGL(k_scan_c, dim3(2 * (DIN_ / 16) * NCH), dim3(256), 0, stream,
                       dtb, xp, Bmat, Cmat, xz, A_log, Dv, hloc, xpn /*y*/);

    hipLaunchKernelGGL(k_norm_y, dim3(NROWS), dim3(256), 0, stream, xpn /*y*/, out_nw,
                       (__hip_bfloat16*)dtb /*yq*/, gy);
    hipLaunchKernelGGL(k_gemm_mfma, dim3(H_ / 128, NROWS / 128), dim3(256), 0, stream,
                       (const ushort_t*)dtb /*yq*/, (const ushort_t*)wq_out, alphas + 4, gy,
                       x /*residual*/, (float*)d_out, NROWS, H_, DIN_);
}

// Round 5
// 391.844 us; speedup vs baseline: 4.3364x; 1.2283x over previous
//
#include <hip/hip_runtime.h>
#include <hip/hip_bf16.h>
#include <cmath>

#define NROWS 4096   // B*L
#define H_    640
#define DIN_  1280
#define DXZ   2560
#define DTR_  40
#define DST_  16
#define LSEQ  2048
#define EPS_  1e-6f
#define NCH   32     // scan chunks
#define CL    64     // chunk length (NCH*CL == LSEQ)
#define KSPLIT 8
#define KCH (DIN_ / KSPLIT)   // 160

typedef __attribute__((ext_vector_type(8))) short short8;
typedef __attribute__((ext_vector_type(4))) float f32x4;
typedef unsigned short ushort_t;

__device__ __forceinline__ float bf2f(short u) {
    return __uint_as_float((unsigned)(unsigned short)u << 16);
}
// exact for integer-valued floats |x| <= 256 (low mantissa bits are zero)
__device__ __forceinline__ short f2bfs(float x) { return (short)(__float_as_uint(x) >> 16); }

// async global->LDS, 16B per lane; LDS dest = wave-uniform base + lane*16
#define GLD16(gp, lp) __builtin_amdgcn_global_load_lds( \
    (const __attribute__((address_space(1))) unsigned int*)(unsigned long long)(gp), \
    (__attribute__((address_space(3))) unsigned int*)(unsigned int)(unsigned long long)(lp), 16, 0, 0)

// ---------------- reductions ----------------
__device__ __forceinline__ float block_reduce_sum256(float v, float* red) {
    int tid = threadIdx.x;
    red[tid] = v; __syncthreads();
    for (int o = 128; o; o >>= 1) { if (tid < o) red[tid] += red[tid + o]; __syncthreads(); }
    float r = red[0]; __syncthreads();
    return r;
}
__device__ __forceinline__ float block_reduce_max256(float v, float* red) {
    int tid = threadIdx.x;
    red[tid] = v; __syncthreads();
    for (int o = 128; o; o >>= 1) { if (tid < o) red[tid] = fmaxf(red[tid], red[tid + o]); __syncthreads(); }
    float r = red[0]; __syncthreads();
    return r;
}

// ---------------- batched alpha = max(mean|w|,1e-10) for 5 weights ----------------
__global__ __launch_bounds__(256) void absmean_partial5(const float* __restrict__ w0, const float* __restrict__ w1,
                                                        const float* __restrict__ w2, const float* __restrict__ w3,
                                                        const float* __restrict__ w4,
                                                        int n0, int n1, int n2, int n3, int n4,
                                                        float* __restrict__ partials) {
    const int wi = blockIdx.y;
    const float* w = (wi == 0) ? w0 : (wi == 1) ? w1 : (wi == 2) ? w2 : (wi == 3) ? w3 : w4;
    const int n = (wi == 0) ? n0 : (wi == 1) ? n1 : (wi == 2) ? n2 : (wi == 3) ? n3 : n4;
    __shared__ float red[256];
    float s = 0.f;
    for (int i = blockIdx.x * 256 + threadIdx.x; i < n; i += gridDim.x * 256) s += fabsf(w[i]);
    red[threadIdx.x] = s; __syncthreads();
    for (int o = 128; o; o >>= 1) { if (threadIdx.x < o) red[threadIdx.x] += red[threadIdx.x + o]; __syncthreads(); }
    if (threadIdx.x == 0) partials[wi * 256 + blockIdx.x] = red[0];
}
__global__ __launch_bounds__(256) void absmean_final5(const float* __restrict__ partials,
                                                      int n0, int n1, int n2, int n3, int n4,
                                                      float* __restrict__ alphas) {
    const int wi = blockIdx.x;
    const int n = (wi == 0) ? n0 : (wi == 1) ? n1 : (wi == 2) ? n2 : (wi == 3) ? n3 : n4;
    __shared__ double red[256];
    double s = (double)partials[wi * 256 + threadIdx.x];
    red[threadIdx.x] = s; __syncthreads();
    for (int o = 128; o; o >>= 1) { if (threadIdx.x < o) red[threadIdx.x] += red[threadIdx.x + o]; __syncthreads(); }
    if (threadIdx.x == 0) alphas[wi] = fmaxf((float)(red[0] / (double)n), 1e-10f);
}
// ternary quant for the two big weights (in_w -> alphas[0], out_w -> alphas[4]), bf16 out
__global__ __launch_bounds__(256) void quant_w2(const float* __restrict__ w0, const float* __restrict__ w1,
                                                int n0, int n1, const float* __restrict__ alphas,
                                                __hip_bfloat16* __restrict__ q0, __hip_bfloat16* __restrict__ q1) {
    const int wi = blockIdx.y;
    const float* w = wi ? w1 : w0;
    __hip_bfloat16* q = wi ? q1 : q0;
    const int n = wi ? n1 : n0;
    float a = alphas[wi ? 4 : 0];
    for (int i = blockIdx.x * 256 + threadIdx.x; i < n; i += gridDim.x * 256) {
        short v = f2bfs(fminf(fmaxf(rintf(w[i] / a), -1.f), 1.f));
        ((ushort_t*)q)[i] = (ushort_t)v;
    }
}

// ---------------- skinny weights -> MFMA-fragment-linear layout ----------------
// wq_sk[t][kb][lane][8] bf16; t: 0..2 dtu rows 16t.. (rows>=40 zero), 3 Bp, 4 Cp.
// lane l -> row (l&15), k = kb*32 + (l>>4)*8 + e
__global__ __launch_bounds__(256) void build_wq_sk(const float* __restrict__ dtu_w,
                                                   const float* __restrict__ Bp_w,
                                                   const float* __restrict__ Cp_w,
                                                   const float* __restrict__ alphas,
                                                   ushort_t* __restrict__ wq_sk) {
    int idx = blockIdx.x * 256 + threadIdx.x;
    if (idx >= 5 * 40 * 64) return;
    int t = idx / 2560, rem = idx % 2560, kb = rem / 64, l = rem % 64;
    int nloc = l & 15, kg = l >> 4;
    float alpha; const float* src; int row; bool valid = true;
    if (t < 3)      { alpha = alphas[1]; src = dtu_w; row = t * 16 + nloc; valid = (row < 40); }
    else if (t == 3){ alpha = alphas[2]; src = Bp_w;  row = nloc; }
    else            { alpha = alphas[3]; src = Cp_w;  row = nloc; }
    int k0 = kb * 32 + kg * 8;
    short8 outv;
#pragma unroll
    for (int e = 0; e < 8; ++e) {
        float q = valid ? fminf(fmaxf(rintf(src[(size_t)row * DIN_ + k0 + e] / alpha), -1.f), 1.f) : 0.f;
        outv[e] = f2bfs(q);
    }
    *(short8*)(wq_sk + (size_t)idx * 8) = outv;
}

// ---------------- rmsnorm(x,norm_w) -> rmsnorm(.,in_nw) -> int8 quant (bf16 out) ----------------
__global__ __launch_bounds__(256) void k_norm_quant_in(const float* __restrict__ x,
                                                       const float* __restrict__ norm_w,
                                                       const float* __restrict__ in_nw,
                                                       __hip_bfloat16* __restrict__ xq, float* __restrict__ gamma) {
    const int r = blockIdx.x, tid = threadIdx.x;
    const float* xr = x + (size_t)r * H_;
    __shared__ float red[256];
    const bool has2 = (tid < H_ - 512);
    float v0 = xr[tid], v1 = xr[tid + 256], v2 = has2 ? xr[tid + 512] : 0.f;
    float ss = v0 * v0 + v1 * v1 + v2 * v2;
    float sum = block_reduce_sum256(ss, red);
    float r1 = 1.f / sqrtf(sum / H_ + EPS_);
    v0 *= r1 * norm_w[tid];
    v1 *= r1 * norm_w[tid + 256];
    if (has2) v2 *= r1 * norm_w[tid + 512];
    ss = v0 * v0 + v1 * v1 + v2 * v2;
    sum = block_reduce_sum256(ss, red);
    float r2 = 1.f / sqrtf(sum / H_ + EPS_);
    v0 *= r2 * in_nw[tid];
    v1 *= r2 * in_nw[tid + 256];
    if (has2) v2 *= r2 * in_nw[tid + 512];
    float mx = fmaxf(fmaxf(fabsf(v0), fabsf(v1)), fabsf(v2));
    float g = fmaxf(block_reduce_max256(mx, red), 1e-10f);
    if (tid == 0) gamma[r] = g;
    float s = 127.f / g;
    __hip_bfloat16* o = xq + (size_t)r * H_;
    o[tid]       = __float2bfloat16(fminf(fmaxf(rintf(v0 * s), -128.f), 127.f));
    o[tid + 256] = __float2bfloat16(fminf(fmaxf(rintf(v1 * s), -128.f), 127.f));
    if (has2) o[tid + 512] = __float2bfloat16(fminf(fmaxf(rintf(v2 * s), -128.f), 127.f));
}

// ---------------- MFMA bf16 quantized GEMM (m97 structure, 128x128 tile, BK=32) ----------------
__global__ __launch_bounds__(256) void k_gemm_mfma(const ushort_t* __restrict__ Aq,
                                                   const ushort_t* __restrict__ Wq,
                                                   const float* __restrict__ alpha_p,
                                                   const float* __restrict__ gamma,
                                                   const float* __restrict__ residual,
                                                   float* __restrict__ out,
                                                   int M, int N, int K) {
    __shared__ ushort_t As[128 * 32];   // swizzled [row][slot^(row&3)][8]
    __shared__ ushort_t Bs[128 * 32];
    const int tid = threadIdx.x;
    const int w = tid >> 6, lane = tid & 63;
    const int wm = w >> 1, wn = w & 1;
    const int row0 = blockIdx.y * 128, col0 = blockIdx.x * 128;
    f32x4 acc[4][4] = {};

    for (int k0 = 0; k0 < K; k0 += 32) {
        #pragma unroll
        for (int q = 0; q < 2; ++q) {
            int c = w * 128 + q * 64 + lane;        // chunk id 0..511
            int row = c >> 2;
            int uslot = (c & 3) ^ (row & 3);        // inverse swizzle on global source
            const ushort_t* ga = Aq + (size_t)(row0 + row) * K + k0 + uslot * 8;
            GLD16(ga, (char*)As + (w * 2048 + q * 1024));
            const ushort_t* gb = Wq + (size_t)(col0 + row) * K + k0 + uslot * 8;
            GLD16(gb, (char*)Bs + (w * 2048 + q * 1024));
        }
        asm volatile("s_waitcnt vmcnt(0)" ::: "memory");
        __syncthreads();

        short8 a[4], b[4];
        #pragma unroll
        for (int i = 0; i < 4; ++i) {
            int row = wm * 64 + i * 16 + (lane & 15);
            int byt = row * 64 + ((((lane >> 4)) ^ (row & 3)) << 4);
            a[i] = *(const short8*)((const char*)As + byt);
        }
        #pragma unroll
        for (int j = 0; j < 4; ++j) {
            int row = wn * 64 + j * 16 + (lane & 15);
            int byt = row * 64 + ((((lane >> 4)) ^ (row & 3)) << 4);
            b[j] = *(const short8*)((const char*)Bs + byt);
        }
        #pragma unroll
        for (int i = 0; i < 4; ++i)
            #pragma unroll
            for (int j = 0; j < 4; ++j)
                acc[i][j] = __builtin_amdgcn_mfma_f32_16x16x32_bf16(a[i], b[j], acc[i][j], 0, 0, 0);
        __syncthreads();
    }

    const float alpha = alpha_p[0];
    #pragma unroll
    for (int i = 0; i < 4; ++i) {
        #pragma unroll
        for (int r = 0; r < 4; ++r) {
            int row = row0 + wm * 64 + i * 16 + (lane >> 4) * 4 + r;
            float s = alpha * gamma[row] * (1.f / 127.f);
            #pragma unroll
            for (int j = 0; j < 4; ++j) {
                int col = col0 + wn * 64 + j * 16 + (lane & 15);
                float o = acc[i][j][r] * s;
                if (residual) o += residual[(size_t)row * N + col];
                out[(size_t)row * N + col] = o;
            }
        }
    }
}

// ---------------- causal depthwise conv (k=4) + silu ----------------
__global__ __launch_bounds__(256) void k_conv_silu(const float* __restrict__ xz,
                                                   const float* __restrict__ cw, const float* __restrict__ cb,
                                                   float* __restrict__ xp) {
    size_t idx = (size_t)blockIdx.x * 256 + threadIdx.x;
    int d = (int)(idx % DIN_);
    size_t row = idx / DIN_;
    int l = (int)(row % LSEQ);
    float s = cb[d];
    const float* c = cw + (size_t)d * 4;
#pragma unroll
    for (int k = 0; k < 4; k++)
        if (l - k >= 0) s += xz[(row - (size_t)k) * DXZ + d] * c[k];
    xp[idx] = s / (1.f + expf(-s));   // silu
}

// ---------------- rmsnorm scales of x_path: rinv + 3 gammas (no xpn write) ----------------
__global__ __launch_bounds__(256) void k_norm_xp(const float* __restrict__ xp,
                                                 const float* __restrict__ dtu_nw,
                                                 const float* __restrict__ Bp_nw,
                                                 const float* __restrict__ Cp_nw,
                                                 float* __restrict__ rinv_out, float* __restrict__ g3) {
    const int r = blockIdx.x, tid = threadIdx.x;
    const float* xr = xp + (size_t)r * DIN_;
    __shared__ float red[256];
    float v[5];
    float ss = 0.f;
#pragma unroll
    for (int j = 0; j < 5; j++) { v[j] = xr[tid + j * 256]; ss += v[j] * v[j]; }
    float sum = block_reduce_sum256(ss, red);
    float rms = 1.f / sqrtf(sum / DIN_ + EPS_);
    float m0 = 0.f, m1 = 0.f, m2 = 0.f;
#pragma unroll
    for (int j = 0; j < 5; j++) {
        int i = tid + j * 256;
        float t = v[j] * rms;
        m0 = fmaxf(m0, fabsf(t * dtu_nw[i]));
        m1 = fmaxf(m1, fabsf(t * Bp_nw[i]));
        m2 = fmaxf(m2, fabsf(t * Cp_nw[i]));
    }
    float g0 = block_reduce_max256(m0, red);
    float g1 = block_reduce_max256(m1, red);
    float g2 = block_reduce_max256(m2, red);
    if (tid == 0) {
        rinv_out[r]       = rms;
        g3[r]             = fmaxf(g0, 1e-10f);
        g3[NROWS + r]     = fmaxf(g1, 1e-10f);
        g3[2 * NROWS + r] = fmaxf(g2, 1e-10f);
    }
}

// ---------------- fused quant + 3 skinny MFMA GEMMs, K-split with exact f32 atomics ----------------
// grid (NROWS/64, KSPLIT), block 256 (4 waves; wave w = rows w*16..w*16+15 of the 64-row tile)
__global__ __launch_bounds__(256) void k_skinny_mfma(const float* __restrict__ xp,
                                                     const float* __restrict__ rinv,
                                                     const float* __restrict__ dtu_nw,
                                                     const float* __restrict__ Bp_nw,
                                                     const float* __restrict__ Cp_nw,
                                                     const float* __restrict__ g3,
                                                     const ushort_t* __restrict__ wq_sk,
                                                     float* __restrict__ dtu_acc,
                                                     float* __restrict__ B_acc,
                                                     float* __restrict__ C_acc) {
    const int tid = threadIdx.x;
    const int w = tid >> 6, l = tid & 63;
    const int row0 = blockIdx.x * 64;
    const int kc0 = blockIdx.y * KCH;
    __shared__ float s_xp[64 * 36];          // +4 pad: conflict-free frag reads
    __shared__ float s_nw[3 * KCH];
    for (int i = tid; i < 3 * KCH; i += 256) {
        int m = i / KCH, j = i - m * KCH;
        const float* nw = (m == 0) ? dtu_nw : (m == 1) ? Bp_nw : Cp_nw;
        s_nw[i] = nw[kc0 + j];
    }
    const int arow = row0 + w * 16 + (l & 15);
    const float ri = rinv[arow];
    const float s0 = 127.f / g3[arow];
    const float s1 = 127.f / g3[NROWS + arow];
    const float s2 = 127.f / g3[2 * NROWS + arow];
    const int kgrp = l >> 4;
    f32x4 acc[5] = {};

    for (int ks = 0; ks < KCH / 32; ++ks) {
        const int kc = kc0 + ks * 32;
        __syncthreads();                      // also covers s_nw staging on first iter
        {
            int srow = tid >> 2, scol = (tid & 3) * 8;
            const float* gp = xp + (size_t)(row0 + srow) * DIN_ + kc + scol;
            f32x4 u0 = *(const f32x4*)gp;
            f32x4 u1 = *(const f32x4*)(gp + 4);
            *(f32x4*)(s_xp + srow * 36 + scol)     = u0;
            *(f32x4*)(s_xp + srow * 36 + scol + 4) = u1;
        }
        __syncthreads();
        const float* sp = s_xp + (w * 16 + (l & 15)) * 36 + kgrp * 8;
        f32x4 t0 = *(const f32x4*)sp;
        f32x4 t1 = *(const f32x4*)(sp + 4);
        float t[8] = { t0[0]*ri, t0[1]*ri, t0[2]*ri, t0[3]*ri,
                       t1[0]*ri, t1[1]*ri, t1[2]*ri, t1[3]*ri };
        short8 a0, a1, a2;
        #pragma unroll
        for (int e = 0; e < 8; ++e) {
            int kk = ks * 32 + kgrp * 8 + e;
            float q0 = fminf(fmaxf(rintf(t[e] * s_nw[kk]           * s0), -128.f), 127.f);
            float q1 = fminf(fmaxf(rintf(t[e] * s_nw[KCH + kk]     * s1), -128.f), 127.f);
            float q2 = fminf(fmaxf(rintf(t[e] * s_nw[2 * KCH + kk] * s2), -128.f), 127.f);
            a0[e] = f2bfs(q0); a1[e] = f2bfs(q1); a2[e] = f2bfs(q2);
        }
        const int kbg = kc >> 5;              // global 32-col block index
        short8 b0 = *(const short8*)(wq_sk + ((size_t)(0 * 40 + kbg) * 64 + l) * 8);
        short8 b1 = *(const short8*)(wq_sk + ((size_t)(1 * 40 + kbg) * 64 + l) * 8);
        short8 b2 = *(const short8*)(wq_sk + ((size_t)(2 * 40 + kbg) * 64 + l) * 8);
        short8 b3 = *(const short8*)(wq_sk + ((size_t)(3 * 40 + kbg) * 64 + l) * 8);
        short8 b4 = *(const short8*)(wq_sk + ((size_t)(4 * 40 + kbg) * 64 + l) * 8);
        acc[0] = __builtin_amdgcn_mfma_f32_16x16x32_bf16(a0, b0, acc[0], 0, 0, 0);
        acc[1] = __builtin_amdgcn_mfma_f32_16x16x32_bf16(a0, b1, acc[1], 0, 0, 0);
        acc[2] = __builtin_amdgcn_mfma_f32_16x16x32_bf16(a0, b2, acc[2], 0, 0, 0);
        acc[3] = __builtin_amdgcn_mfma_f32_16x16x32_bf16(a1, b3, acc[3], 0, 0, 0);
        acc[4] = __builtin_amdgcn_mfma_f32_16x16x32_bf16(a2, b4, acc[4], 0, 0, 0);
    }

    const int col = l & 15;
    const int rbase = row0 + w * 16 + (l >> 4) * 4;
    #pragma unroll
    for (int j = 0; j < 4; ++j) {
        int r = rbase + j;
        atomicAdd(&dtu_acc[(size_t)r * DTR_ + col],      acc[0][j]);
        atomicAdd(&dtu_acc[(size_t)r * DTR_ + 16 + col], acc[1][j]);
        if (col < 8) atomicAdd(&dtu_acc[(size_t)r * DTR_ + 32 + col], acc[2][j]);
        atomicAdd(&B_acc[(size_t)r * DST_ + col], acc[3][j]);
        atomicAdd(&C_acc[(size_t)r * DST_ + col], acc[4][j]);
    }
}

// scale B/C raw integer dots in place
__global__ __launch_bounds__(256) void k_scale_bc(float* __restrict__ Bm, float* __restrict__ Cm,
                                                  const float* __restrict__ g3, const float* __restrict__ alphas) {
    int idx = blockIdx.x * 256 + threadIdx.x;     // < NROWS*16
    int r = idx >> 4;
    float a2 = alphas[2], a3 = alphas[3];
    Bm[idx] = ((Bm[idx] * a2) * g3[NROWS + r]) * (1.f / 127.f);
    Cm[idx] = ((Cm[idx] * a3) * g3[2 * NROWS + r]) * (1.f / 127.f);
}

// ---------------- dt = softplus((raw_dot*scale) @ dtd_w.T + b), LDS-tiled rank-40 GEMM ----------------
__global__ __launch_bounds__(256) void k_dtd(const float* __restrict__ U /*raw acc*/,
                                             const float* __restrict__ W,
                                             const float* __restrict__ bias,
                                             const float* __restrict__ g3,
                                             const float* __restrict__ alphas,
                                             float* __restrict__ dt) {
    const int c0 = blockIdx.x * 256;
    const int r0 = blockIdx.y * 32;
    const int tid = threadIdx.x;
    __shared__ float s_w[256 * 41];
    __shared__ float s_u[32 * 40];
    for (int i = tid; i < 256 * 40; i += 256) {
        int cc = i / 40, t = i - cc * 40;
        s_w[cc * 41 + t] = W[(size_t)c0 * 40 + i];
    }
    const float alpha = alphas[1];
    for (int i = tid; i < 32 * 40; i += 256) {
        int rr = i / 40;
        s_u[i] = ((U[(size_t)r0 * 40 + i] * alpha) * g3[r0 + rr]) * (1.f / 127.f);
    }
    __syncthreads();
    float w[40];
#pragma unroll
    for (int t = 0; t < 40; t++) w[t] = s_w[tid * 41 + t];
    const float b = bias[c0 + tid];
    for (int r = 0; r < 32; ++r) {
        const float* ur = s_u + r * 40;
        float a0 = b, a1 = 0.f, a2 = 0.f, a3 = 0.f;
#pragma unroll
        for (int t = 0; t < 40; t += 4) {
            f32x4 uv = *(const f32x4*)(ur + t);
            a0 = fmaf(uv[0], w[t],     a0);
            a1 = fmaf(uv[1], w[t + 1], a1);
            a2 = fmaf(uv[2], w[t + 2], a2);
            a3 = fmaf(uv[3], w[t + 3], a3);
        }
        float s = (a0 + a1) + (a2 + a3);
        float sp = (s > 0.f) ? (s + log1pf(expf(-s))) : log1pf(expf(s));
        dt[(size_t)(r0 + r) * DIN_ + c0 + tid] = sp;
    }
}

// ======== chunked selective scan ========
__global__ __launch_bounds__(256) void k_scan_a(const float* __restrict__ dt, const float* __restrict__ xp,
                                                const float* __restrict__ Bm, const float* __restrict__ A_log,
                                                float* __restrict__ hloc, float* __restrict__ Pp) {
    const int blk = blockIdx.x;
    const int c = blk % NCH;
    const int dg = (blk / NCH) % (DIN_ / 16);
    const int b = blk / (NCH * (DIN_ / 16));
    const int d0 = dg * 16;
    const int tid = threadIdx.x, g = tid >> 4, n = tid & 15;
    const int d = d0 + g;
    const float A = -expf(A_log[(size_t)d * DST_ + n]);
    __shared__ float s_dt[CL][16], s_xp[CL][16], s_B[CL][16];
    const int l0 = c * CL;
    for (int i = tid; i < CL * 16; i += 256) {
        int ll = i >> 4, dd = i & 15;
        size_t row = (size_t)(b * LSEQ + l0 + ll);
        s_dt[ll][dd] = dt[row * DIN_ + d0 + dd];
        s_xp[ll][dd] = xp[row * DIN_ + d0 + dd];
        s_B[ll][dd]  = Bm[row * DST_ + dd];
    }
    __syncthreads();
    float h = 0.f, P = 1.f;
#pragma unroll 4
    for (int ll = 0; ll < CL; ++ll) {
        float dtv = s_dt[ll][g], xv = s_xp[ll][g], Bv = s_B[ll][n];
        float dA = expf(A * dtv);
        h = dA * h + dtv * Bv * xv;
        P *= dA;
    }
    size_t idx = (size_t)(b * NCH + c) * 20480 + (size_t)d0 * 16 + tid;
    hloc[idx] = h;
    Pp[idx] = P;
}

__global__ __launch_bounds__(256) void k_scan_b(float* __restrict__ hloc, const float* __restrict__ Pp) {
    int i = blockIdx.x * 256 + threadIdx.x;
    int b = i / 20480, dn = i % 20480;
    size_t base = (size_t)b * NCH * 20480 + dn;
    float H = 0.f;
    for (int c = 0; c < NCH; ++c) {
        size_t off = base + (size_t)c * 20480;
        float hl = hloc[off], p = Pp[off];
        hloc[off] = H;
        H = p * H + hl;
    }
}

__global__ __launch_bounds__(256) void k_scan_c(const float* __restrict__ dt, const float* __restrict__ xp,
                                                const float* __restrict__ Bm, const float* __restrict__ Cm,
                                                const float* __restrict__ xz, const float* __restrict__ A_log,
                                                const float* __restrict__ Dvec, const float* __restrict__ Hinit,
                                                float* __restrict__ y) {
    const int blk = blockIdx.x;
    const int c = blk % NCH;
    const int dg = (blk / NCH) % (DIN_ / 16);
    const int b = blk / (NCH * (DIN_ / 16));
    const int d0 = dg * 16;
    const int tid = threadIdx.x, g = tid >> 4, n = tid & 15;
    const int d = d0 + g;
    const float A = -expf(A_log[(size_t)d * DST_ + n]);
    const float Dd = Dvec[d];
    __shared__ float s_dt[CL][16], s_xp[CL][16], s_B[CL][16], s_C[CL][16], s_z[CL][16];
    const int l0 = c * CL;
    for (int i = tid; i < CL * 16; i += 256) {
        int ll = i >> 4, dd = i & 15;
        size_t row = (size_t)(b * LSEQ + l0 + ll);
        s_dt[ll][dd] = dt[row * DIN_ + d0 + dd];
        s_xp[ll][dd] = xp[row * DIN_ + d0 + dd];
        s_B[ll][dd]  = Bm[row * DST_ + dd];
        s_C[ll][dd]  = Cm[row * DST_ + dd];
        s_z[ll][dd]  = xz[row * DXZ + DIN_ + d0 + dd];
    }
    __syncthreads();
    float h = Hinit[(size_t)(b * NCH + c) * 20480 + (size_t)d0 * 16 + tid];
    for (int ll = 0; ll < CL; ++ll) {
        float dtv = s_dt[ll][g], xv = s_xp[ll][g];
        float Bv = s_B[ll][n], Cv = s_C[ll][n];
        float dA = expf(A * dtv);
        h = dA * h + dtv * Bv * xv;
        float contrib = h * Cv;
        contrib += __shfl_xor(contrib, 1);
        contrib += __shfl_xor(contrib, 2);
        contrib += __shfl_xor(contrib, 4);
        contrib += __shfl_xor(contrib, 8);
        if (n == 0) {
            float zv = s_z[ll][g];
            float yv = contrib + xv * Dd;
            yv *= zv / (1.f + expf(-zv));
            y[(size_t)(b * LSEQ + l0 + ll) * DIN_ + d] = yv;
        }
    }
}

// ---------------- rmsnorm(y,out_nw) + quant (bf16 out) ----------------
__global__ __launch_bounds__(256) void k_norm_y(const float* __restrict__ y,
                                                const float* __restrict__ out_nw,
                                                __hip_bfloat16* __restrict__ yq, float* __restrict__ gy) {
    const int r = blockIdx.x, tid = threadIdx.x;
    const float* yr = y + (size_t)r * DIN_;
    __shared__ float red[256];
    float v[5];
    float ss = 0.f;
#pragma unroll
    for (int j = 0; j < 5; j++) { v[j] = yr[tid + j * 256]; ss += v[j] * v[j]; }
    float sum = block_reduce_sum256(ss, red);
    float rms = 1.f / sqrtf(sum / DIN_ + EPS_);
    float mx = 0.f;
#pragma unroll
    for (int j = 0; j < 5; j++) {
        int i = tid + j * 256;
        v[j] = v[j] * rms * out_nw[i];
        mx = fmaxf(mx, fabsf(v[j]));
    }
    float g = fmaxf(block_reduce_max256(mx, red), 1e-10f);
    if (tid == 0) gy[r] = g;
    float s = 127.f / g;
#pragma unroll
    for (int j = 0; j < 5; j++) {
        int i = tid + j * 256;
        yq[(size_t)r * DIN_ + i] = __float2bfloat16(fminf(fmaxf(rintf(v[j] * s), -128.f), 127.f));
    }
}

extern "C" void kernel_launch(void* const* d_in, const int* in_sizes, int n_in,
                              void* d_out, int out_size, void* d_ws, size_t ws_size,
                              hipStream_t stream) {
    (void)in_sizes; (void)n_in; (void)out_size;
    const float* x      = (const float*)d_in[0];
    const float* norm_w = (const float*)d_in[1];
    const float* in_w   = (const float*)d_in[2];
    const float* in_nw  = (const float*)d_in[3];
    const float* conv_w = (const float*)d_in[4];
    const float* conv_b = (const float*)d_in[5];
    const float* dtu_w  = (const float*)d_in[6];
    const float* dtu_nw = (const float*)d_in[7];
    const float* dtd_w  = (const float*)d_in[8];
    const float* dtd_b  = (const float*)d_in[9];
    const float* Bp_w   = (const float*)d_in[10];
    const float* Bp_nw  = (const float*)d_in[11];
    const float* Cp_w   = (const float*)d_in[12];
    const float* Cp_nw  = (const float*)d_in[13];
    const float* A_log  = (const float*)d_in[14];
    const float* Dv     = (const float*)d_in[15];
    const float* out_w  = (const float*)d_in[16];
    const float* out_nw = (const float*)d_in[17];

    float* ws = (float*)d_ws;
    float* alphas   = ws;                      // 8
    float* partials = ws + 8;                  // 5*256
    float* xq1      = ws + 8 + 5 * 256;        // bf16 activations; later reused as hloc/Pp
    float* gamma1   = xq1 + (size_t)NROWS * H_;
    float* xz       = gamma1 + NROWS;
    float* xp       = xz + (size_t)NROWS * DXZ;
    float* xpn     = xp + (size_t)NROWS * DIN_;        // now only used as y (scan output)
    float* g3       = xpn + (size_t)NROWS * DIN_;
    float* dtu_out  = g3 + 3 * NROWS;                  // raw integer dots (memset 0 each call)
    float* Bmat     = dtu_out + (size_t)NROWS * DTR_;
    float* Cmat     = Bmat + (size_t)NROWS * DST_;
    float* dtb      = Cmat + (size_t)NROWS * DST_;     // later reused as yq (bf16)
    float* gy       = dtb + (size_t)NROWS * DIN_;
    float* wq_in    = gy + NROWS;                      // bf16
    float* wq_dtu   = wq_in + (size_t)DXZ * H_;        // (unused, kept for layout)
    float* wq_Bp    = wq_dtu + (size_t)DTR_ * DIN_;
    float* wq_Cp    = wq_Bp + (size_t)DST_ * DIN_;
    float* wq_out   = wq_Cp + (size_t)DST_ * DIN_;     // bf16
    float* rinv     = wq_out + (size_t)H_ * DIN_;      // NROWS
    float* wq_sk    = rinv + NROWS;                    // 5*40*64*8 bf16 = 51200 float slots
    size_t need = (size_t)((wq_sk + 51200) - ws) * sizeof(float);
    if (ws_size < need) return;

    float* hloc = xq1;
    float* Pp   = xq1 + (size_t)2 * NCH * 20480;

    // zero the atomic accumulators (dtu_out, Bmat, Cmat are contiguous: NROWS*72 floats)
    hipMemsetAsync(dtu_out, 0, (size_t)NROWS * 72 * sizeof(float), stream);

    const int n0 = DXZ * H_, n1 = DTR_ * DIN_, n2 = DST_ * DIN_, n3 = DST_ * DIN_, n4 = H_ * DIN_;
    hipLaunchKernelGGL(absmean_partial5, dim3(256, 5), dim3(256), 0, stream,
                       in_w, dtu_w, Bp_w, Cp_w, out_w, n0, n1, n2, n3, n4, partials);
    hipLaunchKernelGGL(absmean_final5, dim3(5), dim3(256), 0, stream, partials, n0, n1, n2, n3, n4, alphas);
    hipLaunchKernelGGL(quant_w2, dim3((n0 + 255) / 256, 2), dim3(256), 0, stream,
                       in_w, out_w, n0, n4, alphas, (__hip_bfloat16*)wq_in, (__hip_bfloat16*)wq_out);
    hipLaunchKernelGGL(build_wq_sk, dim3(50), dim3(256), 0, stream,
                       dtu_w, Bp_w, Cp_w, alphas, (ushort_t*)wq_sk);

    hipLaunchKernelGGL(k_norm_quant_in, dim3(NROWS), dim3(256), 0, stream,
                       x, norm_w, in_nw, (__hip_bfloat16*)xq1, gamma1);
    hipLaunchKernelGGL(k_gemm_mfma, dim3(DXZ / 128, NROWS / 128), dim3(256), 0, stream,
                       (const ushort_t*)xq1, (const ushort_t*)wq_in, alphas + 0, gamma1,
                       (const float*)nullptr, xz, NROWS, DXZ, H_);
    hipLaunchKernelGGL(k_conv_silu, dim3((NROWS * DIN_) / 256), dim3(256), 0, stream, xz, conv_w, conv_b, xp);
    hipLaunchKernelGGL(k_norm_xp, dim3(NROWS), dim3(256), 0, stream, xp, dtu_nw, Bp_nw, Cp_nw, rinv, g3);
    hipLaunchKernelGGL(k_skinny_mfma, dim3(NROWS / 64, KSPLIT), dim3(256), 0, stream,
                       xp, rinv, dtu_nw, Bp_nw, Cp_nw, g3, (const ushort_t*)wq_sk,
                       dtu_out, Bmat, Cmat);
    hipLaunchKernelGGL(k_scale_bc, dim3((NROWS * DST_) / 256), dim3(256), 0, stream, Bmat, Cmat, g3, alphas);
    hipLaunchKernelGGL(k_dtd, dim3(DIN_ / 256, NROWS / 32), dim3(256), 0, stream,
                       dtu_out, dtd_w, dtd_b, g3, alphas, dtb);

    hipLaunchKernelGGL(k_scan_a, dim3(2 * (DIN_ / 16) * NCH), dim3(256), 0, stream,
                       dtb, xp, Bmat, A_log, hloc, Pp);
    hipLaunchKernelGGL(k_scan_b, dim3((2 * 20480) / 256), dim3(256), 0, stream, hloc, Pp);
    hipLaunchKernelGGL(k_scan_c, dim3(2 * (DIN_ / 16) * NCH), dim3(256), 0, stream,
                       dtb, xp, Bmat, Cmat, xz, A_log, Dv, hloc, xpn /*y*/);

    hipLaunchKernelGGL(k_norm_y, dim3(NROWS), dim3(256), 0, stream, xpn /*y*/, out_nw,
                       (__hip_bfloat16*)dtb /*yq*/, gy);
    hipLaunchKernelGGL(k_gemm_mfma, dim3(H_ / 128, NROWS / 128), dim3(256), 0, stream,
                       (const ushort_t*)dtb /*yq*/, (const ushort_t*)wq_out, alphas + 4, gy,
                       x /*residual*/, (float*)d_out, NROWS, H_, DIN_);
}

// Round 6
// 312.035 us; speedup vs baseline: 5.4456x; 1.2558x over previous
//
#include <hip/hip_runtime.h>
#include <hip/hip_bf16.h>
#include <cmath>

#define NROWS 4096   // B*L
#define H_    640
#define DIN_  1280
#define DXZ   2560
#define DTR_  40
#define DST_  16
#define LSEQ  2048
#define EPS_  1e-6f
#define NCH   32     // scan chunks
#define CL    64     // chunk length (NCH*CL == LSEQ)
#define KSPLIT 8
#define KCH (DIN_ / KSPLIT)   // 160
#define LOG2E 1.4426950408889634f

typedef __attribute__((ext_vector_type(8))) short short8;
typedef __attribute__((ext_vector_type(4))) float f32x4;
typedef unsigned short ushort_t;

__device__ __forceinline__ float bf2f(short u) {
    return __uint_as_float((unsigned)(unsigned short)u << 16);
}
// exact for integer-valued floats |x| <= 256 (low mantissa bits are zero)
__device__ __forceinline__ short f2bfs(float x) { return (short)(__float_as_uint(x) >> 16); }

// async global->LDS, 16B per lane; LDS dest = wave-uniform base + lane*16
#define GLD16(gp, lp) __builtin_amdgcn_global_load_lds( \
    (const __attribute__((address_space(1))) unsigned int*)(unsigned long long)(gp), \
    (__attribute__((address_space(3))) unsigned int*)(unsigned int)(unsigned long long)(lp), 16, 0, 0)

// ---------------- reductions ----------------
__device__ __forceinline__ float block_reduce_sum256(float v, float* red) {
    int tid = threadIdx.x;
    red[tid] = v; __syncthreads();
    for (int o = 128; o; o >>= 1) { if (tid < o) red[tid] += red[tid + o]; __syncthreads(); }
    float r = red[0]; __syncthreads();
    return r;
}
__device__ __forceinline__ float block_reduce_max256(float v, float* red) {
    int tid = threadIdx.x;
    red[tid] = v; __syncthreads();
    for (int o = 128; o; o >>= 1) { if (tid < o) red[tid] = fmaxf(red[tid], red[tid + o]); __syncthreads(); }
    float r = red[0]; __syncthreads();
    return r;
}

// ---------------- batched alpha = max(mean|w|,1e-10) for 5 weights ----------------
__global__ __launch_bounds__(256) void absmean_partial5(const float* __restrict__ w0, const float* __restrict__ w1,
                                                        const float* __restrict__ w2, const float* __restrict__ w3,
                                                        const float* __restrict__ w4,
                                                        int n0, int n1, int n2, int n3, int n4,
                                                        float* __restrict__ partials) {
    const int wi = blockIdx.y;
    const float* w = (wi == 0) ? w0 : (wi == 1) ? w1 : (wi == 2) ? w2 : (wi == 3) ? w3 : w4;
    const int n = (wi == 0) ? n0 : (wi == 1) ? n1 : (wi == 2) ? n2 : (wi == 3) ? n3 : n4;
    __shared__ float red[256];
    float s = 0.f;
    for (int i = blockIdx.x * 256 + threadIdx.x; i < n; i += gridDim.x * 256) s += fabsf(w[i]);
    red[threadIdx.x] = s; __syncthreads();
    for (int o = 128; o; o >>= 1) { if (threadIdx.x < o) red[threadIdx.x] += red[threadIdx.x + o]; __syncthreads(); }
    if (threadIdx.x == 0) partials[wi * 256 + blockIdx.x] = red[0];
}
__global__ __launch_bounds__(256) void absmean_final5(const float* __restrict__ partials,
                                                      int n0, int n1, int n2, int n3, int n4,
                                                      float* __restrict__ alphas) {
    const int wi = blockIdx.x;
    const int n = (wi == 0) ? n0 : (wi == 1) ? n1 : (wi == 2) ? n2 : (wi == 3) ? n3 : n4;
    __shared__ double red[256];
    double s = (double)partials[wi * 256 + threadIdx.x];
    red[threadIdx.x] = s; __syncthreads();
    for (int o = 128; o; o >>= 1) { if (threadIdx.x < o) red[threadIdx.x] += red[threadIdx.x + o]; __syncthreads(); }
    if (threadIdx.x == 0) alphas[wi] = fmaxf((float)(red[0] / (double)n), 1e-10f);
}
// ternary quant for the two big weights (in_w -> alphas[0], out_w -> alphas[4]), bf16 out
__global__ __launch_bounds__(256) void quant_w2(const float* __restrict__ w0, const float* __restrict__ w1,
                                                int n0, int n1, const float* __restrict__ alphas,
                                                __hip_bfloat16* __restrict__ q0, __hip_bfloat16* __restrict__ q1) {
    const int wi = blockIdx.y;
    const float* w = wi ? w1 : w0;
    __hip_bfloat16* q = wi ? q1 : q0;
    const int n = wi ? n1 : n0;
    float a = alphas[wi ? 4 : 0];
    for (int i = blockIdx.x * 256 + threadIdx.x; i < n; i += gridDim.x * 256) {
        short v = f2bfs(fminf(fmaxf(rintf(w[i] / a), -1.f), 1.f));
        ((ushort_t*)q)[i] = (ushort_t)v;
    }
}

// ---------------- skinny weights -> MFMA-fragment-linear layout ----------------
__global__ __launch_bounds__(256) void build_wq_sk(const float* __restrict__ dtu_w,
                                                   const float* __restrict__ Bp_w,
                                                   const float* __restrict__ Cp_w,
                                                   const float* __restrict__ alphas,
                                                   ushort_t* __restrict__ wq_sk) {
    int idx = blockIdx.x * 256 + threadIdx.x;
    if (idx >= 5 * 40 * 64) return;
    int t = idx / 2560, rem = idx % 2560, kb = rem / 64, l = rem % 64;
    int nloc = l & 15, kg = l >> 4;
    float alpha; const float* src; int row; bool valid = true;
    if (t < 3)      { alpha = alphas[1]; src = dtu_w; row = t * 16 + nloc; valid = (row < 40); }
    else if (t == 3){ alpha = alphas[2]; src = Bp_w;  row = nloc; }
    else            { alpha = alphas[3]; src = Cp_w;  row = nloc; }
    int k0 = kb * 32 + kg * 8;
    short8 outv;
#pragma unroll
    for (int e = 0; e < 8; ++e) {
        float q = valid ? fminf(fmaxf(rintf(src[(size_t)row * DIN_ + k0 + e] / alpha), -1.f), 1.f) : 0.f;
        outv[e] = f2bfs(q);
    }
    *(short8*)(wq_sk + (size_t)idx * 8) = outv;
}

// ---------------- rmsnorm(x,norm_w) -> rmsnorm(.,in_nw) -> int8 quant (bf16 out) ----------------
__global__ __launch_bounds__(256) void k_norm_quant_in(const float* __restrict__ x,
                                                       const float* __restrict__ norm_w,
                                                       const float* __restrict__ in_nw,
                                                       __hip_bfloat16* __restrict__ xq, float* __restrict__ gamma) {
    const int r = blockIdx.x, tid = threadIdx.x;
    const float* xr = x + (size_t)r * H_;
    __shared__ float red[256];
    const bool has2 = (tid < H_ - 512);
    float v0 = xr[tid], v1 = xr[tid + 256], v2 = has2 ? xr[tid + 512] : 0.f;
    float ss = v0 * v0 + v1 * v1 + v2 * v2;
    float sum = block_reduce_sum256(ss, red);
    float r1 = 1.f / sqrtf(sum / H_ + EPS_);
    v0 *= r1 * norm_w[tid];
    v1 *= r1 * norm_w[tid + 256];
    if (has2) v2 *= r1 * norm_w[tid + 512];
    ss = v0 * v0 + v1 * v1 + v2 * v2;
    sum = block_reduce_sum256(ss, red);
    float r2 = 1.f / sqrtf(sum / H_ + EPS_);
    v0 *= r2 * in_nw[tid];
    v1 *= r2 * in_nw[tid + 256];
    if (has2) v2 *= r2 * in_nw[tid + 512];
    float mx = fmaxf(fmaxf(fabsf(v0), fabsf(v1)), fabsf(v2));
    float g = fmaxf(block_reduce_max256(mx, red), 1e-10f);
    if (tid == 0) gamma[r] = g;
    float s = 127.f / g;
    __hip_bfloat16* o = xq + (size_t)r * H_;
    o[tid]       = __float2bfloat16(fminf(fmaxf(rintf(v0 * s), -128.f), 127.f));
    o[tid + 256] = __float2bfloat16(fminf(fmaxf(rintf(v1 * s), -128.f), 127.f));
    if (has2) o[tid + 512] = __float2bfloat16(fminf(fmaxf(rintf(v2 * s), -128.f), 127.f));
}

// ---------------- MFMA bf16 quantized GEMM (m97 structure, 128x128 tile, BK=32) ----------------
__global__ __launch_bounds__(256) void k_gemm_mfma(const ushort_t* __restrict__ Aq,
                                                   const ushort_t* __restrict__ Wq,
                                                   const float* __restrict__ alpha_p,
                                                   const float* __restrict__ gamma,
                                                   const float* __restrict__ residual,
                                                   float* __restrict__ out,
                                                   int M, int N, int K) {
    __shared__ ushort_t As[128 * 32];   // swizzled [row][slot^(row&3)][8]
    __shared__ ushort_t Bs[128 * 32];
    const int tid = threadIdx.x;
    const int w = tid >> 6, lane = tid & 63;
    const int wm = w >> 1, wn = w & 1;
    const int row0 = blockIdx.y * 128, col0 = blockIdx.x * 128;
    f32x4 acc[4][4] = {};

    for (int k0 = 0; k0 < K; k0 += 32) {
        #pragma unroll
        for (int q = 0; q < 2; ++q) {
            int c = w * 128 + q * 64 + lane;        // chunk id 0..511
            int row = c >> 2;
            int uslot = (c & 3) ^ (row & 3);        // inverse swizzle on global source
            const ushort_t* ga = Aq + (size_t)(row0 + row) * K + k0 + uslot * 8;
            GLD16(ga, (char*)As + (w * 2048 + q * 1024));
            const ushort_t* gb = Wq + (size_t)(col0 + row) * K + k0 + uslot * 8;
            GLD16(gb, (char*)Bs + (w * 2048 + q * 1024));
        }
        asm volatile("s_waitcnt vmcnt(0)" ::: "memory");
        __syncthreads();

        short8 a[4], b[4];
        #pragma unroll
        for (int i = 0; i < 4; ++i) {
            int row = wm * 64 + i * 16 + (lane & 15);
            int byt = row * 64 + ((((lane >> 4)) ^ (row & 3)) << 4);
            a[i] = *(const short8*)((const char*)As + byt);
        }
        #pragma unroll
        for (int j = 0; j < 4; ++j) {
            int row = wn * 64 + j * 16 + (lane & 15);
            int byt = row * 64 + ((((lane >> 4)) ^ (row & 3)) << 4);
            b[j] = *(const short8*)((const char*)Bs + byt);
        }
        #pragma unroll
        for (int i = 0; i < 4; ++i)
            #pragma unroll
            for (int j = 0; j < 4; ++j)
                acc[i][j] = __builtin_amdgcn_mfma_f32_16x16x32_bf16(a[i], b[j], acc[i][j], 0, 0, 0);
        __syncthreads();
    }

    const float alpha = alpha_p[0];
    #pragma unroll
    for (int i = 0; i < 4; ++i) {
        #pragma unroll
        for (int r = 0; r < 4; ++r) {
            int row = row0 + wm * 64 + i * 16 + (lane >> 4) * 4 + r;
            float s = alpha * gamma[row] * (1.f / 127.f);
            #pragma unroll
            for (int j = 0; j < 4; ++j) {
                int col = col0 + wn * 64 + j * 16 + (lane & 15);
                float o = acc[i][j][r] * s;
                if (residual) o += residual[(size_t)row * N + col];
                out[(size_t)row * N + col] = o;
            }
        }
    }
}

// ---------------- causal depthwise conv (k=4) + silu ----------------
__global__ __launch_bounds__(256) void k_conv_silu(const float* __restrict__ xz,
                                                   const float* __restrict__ cw, const float* __restrict__ cb,
                                                   float* __restrict__ xp) {
    size_t idx = (size_t)blockIdx.x * 256 + threadIdx.x;
    int d = (int)(idx % DIN_);
    size_t row = idx / DIN_;
    int l = (int)(row % LSEQ);
    float s = cb[d];
    const float* c = cw + (size_t)d * 4;
#pragma unroll
    for (int k = 0; k < 4; k++)
        if (l - k >= 0) s += xz[(row - (size_t)k) * DXZ + d] * c[k];
    xp[idx] = s / (1.f + expf(-s));   // silu
}

// ---------------- rmsnorm scales of x_path: rinv + 3 gammas (no xpn write) ----------------
__global__ __launch_bounds__(256) void k_norm_xp(const float* __restrict__ xp,
                                                 const float* __restrict__ dtu_nw,
                                                 const float* __restrict__ Bp_nw,
                                                 const float* __restrict__ Cp_nw,
                                                 float* __restrict__ rinv_out, float* __restrict__ g3) {
    const int r = blockIdx.x, tid = threadIdx.x;
    const float* xr = xp + (size_t)r * DIN_;
    __shared__ float red[256];
    float v[5];
    float ss = 0.f;
#pragma unroll
    for (int j = 0; j < 5; j++) { v[j] = xr[tid + j * 256]; ss += v[j] * v[j]; }
    float sum = block_reduce_sum256(ss, red);
    float rms = 1.f / sqrtf(sum / DIN_ + EPS_);
    float m0 = 0.f, m1 = 0.f, m2 = 0.f;
#pragma unroll
    for (int j = 0; j < 5; j++) {
        int i = tid + j * 256;
        float t = v[j] * rms;
        m0 = fmaxf(m0, fabsf(t * dtu_nw[i]));
        m1 = fmaxf(m1, fabsf(t * Bp_nw[i]));
        m2 = fmaxf(m2, fabsf(t * Cp_nw[i]));
    }
    float g0 = block_reduce_max256(m0, red);
    float g1 = block_reduce_max256(m1, red);
    float g2 = block_reduce_max256(m2, red);
    if (tid == 0) {
        rinv_out[r]       = rms;
        g3[r]             = fmaxf(g0, 1e-10f);
        g3[NROWS + r]     = fmaxf(g1, 1e-10f);
        g3[2 * NROWS + r] = fmaxf(g2, 1e-10f);
    }
}

// ---------------- fused quant + 3 skinny MFMA GEMMs, K-split with exact f32 atomics ----------------
__global__ __launch_bounds__(256) void k_skinny_mfma(const float* __restrict__ xp,
                                                     const float* __restrict__ rinv,
                                                     const float* __restrict__ dtu_nw,
                                                     const float* __restrict__ Bp_nw,
                                                     const float* __restrict__ Cp_nw,
                                                     const float* __restrict__ g3,
                                                     const ushort_t* __restrict__ wq_sk,
                                                     float* __restrict__ dtu_acc,
                                                     float* __restrict__ B_acc,
                                                     float* __restrict__ C_acc) {
    const int tid = threadIdx.x;
    const int w = tid >> 6, l = tid & 63;
    const int row0 = blockIdx.x * 64;
    const int kc0 = blockIdx.y * KCH;
    __shared__ float s_xp[64 * 36];          // +4 pad: conflict-free frag reads
    __shared__ float s_nw[3 * KCH];
    for (int i = tid; i < 3 * KCH; i += 256) {
        int m = i / KCH, j = i - m * KCH;
        const float* nw = (m == 0) ? dtu_nw : (m == 1) ? Bp_nw : Cp_nw;
        s_nw[i] = nw[kc0 + j];
    }
    const int arow = row0 + w * 16 + (l & 15);
    const float ri = rinv[arow];
    const float s0 = 127.f / g3[arow];
    const float s1 = 127.f / g3[NROWS + arow];
    const float s2 = 127.f / g3[2 * NROWS + arow];
    const int kgrp = l >> 4;
    f32x4 acc[5] = {};

    for (int ks = 0; ks < KCH / 32; ++ks) {
        const int kc = kc0 + ks * 32;
        __syncthreads();
        {
            int srow = tid >> 2, scol = (tid & 3) * 8;
            const float* gp = xp + (size_t)(row0 + srow) * DIN_ + kc + scol;
            f32x4 u0 = *(const f32x4*)gp;
            f32x4 u1 = *(const f32x4*)(gp + 4);
            *(f32x4*)(s_xp + srow * 36 + scol)     = u0;
            *(f32x4*)(s_xp + srow * 36 + scol + 4) = u1;
        }
        __syncthreads();
        const float* sp = s_xp + (w * 16 + (l & 15)) * 36 + kgrp * 8;
        f32x4 t0 = *(const f32x4*)sp;
        f32x4 t1 = *(const f32x4*)(sp + 4);
        float t[8] = { t0[0]*ri, t0[1]*ri, t0[2]*ri, t0[3]*ri,
                       t1[0]*ri, t1[1]*ri, t1[2]*ri, t1[3]*ri };
        short8 a0, a1, a2;
        #pragma unroll
        for (int e = 0; e < 8; ++e) {
            int kk = ks * 32 + kgrp * 8 + e;
            float q0 = fminf(fmaxf(rintf(t[e] * s_nw[kk]           * s0), -128.f), 127.f);
            float q1 = fminf(fmaxf(rintf(t[e] * s_nw[KCH + kk]     * s1), -128.f), 127.f);
            float q2 = fminf(fmaxf(rintf(t[e] * s_nw[2 * KCH + kk] * s2), -128.f), 127.f);
            a0[e] = f2bfs(q0); a1[e] = f2bfs(q1); a2[e] = f2bfs(q2);
        }
        const int kbg = kc >> 5;
        short8 b0 = *(const short8*)(wq_sk + ((size_t)(0 * 40 + kbg) * 64 + l) * 8);
        short8 b1 = *(const short8*)(wq_sk + ((size_t)(1 * 40 + kbg) * 64 + l) * 8);
        short8 b2 = *(const short8*)(wq_sk + ((size_t)(2 * 40 + kbg) * 64 + l) * 8);
        short8 b3 = *(const short8*)(wq_sk + ((size_t)(3 * 40 + kbg) * 64 + l) * 8);
        short8 b4 = *(const short8*)(wq_sk + ((size_t)(4 * 40 + kbg) * 64 + l) * 8);
        acc[0] = __builtin_amdgcn_mfma_f32_16x16x32_bf16(a0, b0, acc[0], 0, 0, 0);
        acc[1] = __builtin_amdgcn_mfma_f32_16x16x32_bf16(a0, b1, acc[1], 0, 0, 0);
        acc[2] = __builtin_amdgcn_mfma_f32_16x16x32_bf16(a0, b2, acc[2], 0, 0, 0);
        acc[3] = __builtin_amdgcn_mfma_f32_16x16x32_bf16(a1, b3, acc[3], 0, 0, 0);
        acc[4] = __builtin_amdgcn_mfma_f32_16x16x32_bf16(a2, b4, acc[4], 0, 0, 0);
    }

    const int col = l & 15;
    const int rbase = row0 + w * 16 + (l >> 4) * 4;
    #pragma unroll
    for (int j = 0; j < 4; ++j) {
        int r = rbase + j;
        atomicAdd(&dtu_acc[(size_t)r * DTR_ + col],      acc[0][j]);
        atomicAdd(&dtu_acc[(size_t)r * DTR_ + 16 + col], acc[1][j]);
        if (col < 8) atomicAdd(&dtu_acc[(size_t)r * DTR_ + 32 + col], acc[2][j]);
        atomicAdd(&B_acc[(size_t)r * DST_ + col], acc[3][j]);
        atomicAdd(&C_acc[(size_t)r * DST_ + col], acc[4][j]);
    }
}

// scale B/C raw integer dots in place
__global__ __launch_bounds__(256) void k_scale_bc(float* __restrict__ Bm, float* __restrict__ Cm,
                                                  const float* __restrict__ g3, const float* __restrict__ alphas) {
    int idx = blockIdx.x * 256 + threadIdx.x;     // < NROWS*16
    int r = idx >> 4;
    float a2 = alphas[2], a3 = alphas[3];
    Bm[idx] = ((Bm[idx] * a2) * g3[NROWS + r]) * (1.f / 127.f);
    Cm[idx] = ((Cm[idx] * a3) * g3[2 * NROWS + r]) * (1.f / 127.f);
}

// ---------------- dt = softplus((raw_dot*scale) @ dtd_w.T + b), LDS-tiled rank-40 GEMM ----------------
__global__ __launch_bounds__(256) void k_dtd(const float* __restrict__ U /*raw acc*/,
                                             const float* __restrict__ W,
                                             const float* __restrict__ bias,
                                             const float* __restrict__ g3,
                                             const float* __restrict__ alphas,
                                             float* __restrict__ dt) {
    const int c0 = blockIdx.x * 256;
    const int r0 = blockIdx.y * 32;
    const int tid = threadIdx.x;
    __shared__ float s_w[256 * 41];
    __shared__ float s_u[32 * 40];
    for (int i = tid; i < 256 * 40; i += 256) {
        int cc = i / 40, t = i - cc * 40;
        s_w[cc * 41 + t] = W[(size_t)c0 * 40 + i];
    }
    const float alpha = alphas[1];
    for (int i = tid; i < 32 * 40; i += 256) {
        int rr = i / 40;
        s_u[i] = ((U[(size_t)r0 * 40 + i] * alpha) * g3[r0 + rr]) * (1.f / 127.f);
    }
    __syncthreads();
    float w[40];
#pragma unroll
    for (int t = 0; t < 40; t++) w[t] = s_w[tid * 41 + t];
    const float b = bias[c0 + tid];
    for (int r = 0; r < 32; ++r) {
        const float* ur = s_u + r * 40;
        float a0 = b, a1 = 0.f, a2 = 0.f, a3 = 0.f;
#pragma unroll
        for (int t = 0; t < 40; t += 4) {
            f32x4 uv = *(const f32x4*)(ur + t);
            a0 = fmaf(uv[0], w[t],     a0);
            a1 = fmaf(uv[1], w[t + 1], a1);
            a2 = fmaf(uv[2], w[t + 2], a2);
            a3 = fmaf(uv[3], w[t + 3], a3);
        }
        float s = (a0 + a1) + (a2 + a3);
        float sp = (s > 0.f) ? (s + log1pf(expf(-s))) : log1pf(expf(s));
        dt[(size_t)(r0 + r) * DIN_ + c0 + tid] = sp;
    }
}

// ======== chunked selective scan: 4 lanes x 4 states per channel ========
// grid (DIN/64, NCH, B), block 256. thread: q = tid&3 (states q*4..q*4+3), d = d0 + (tid>>2).
__global__ __launch_bounds__(256) void k_scan_a(const float* __restrict__ dt, const float* __restrict__ xp,
                                                const float* __restrict__ Bm, const float* __restrict__ A_log,
                                                float* __restrict__ hloc, float* __restrict__ Pp) {
    const int tid = threadIdx.x;
    const int q = tid & 3, dloc = tid >> 2;
    const int d0 = blockIdx.x * 64, c = blockIdx.y, b = blockIdx.z;
    const int d = d0 + dloc;
    const int l0 = c * CL;
    __shared__ float s_B[CL * 16];
    *(f32x4*)(s_B + tid * 4) = *(const f32x4*)(Bm + (size_t)(b * LSEQ + l0) * DST_ + tid * 4);
    f32x4 Av = *(const f32x4*)(A_log + (size_t)d * DST_ + q * 4);
    float A2[4];
#pragma unroll
    for (int j = 0; j < 4; ++j) A2[j] = -expf(Av[j]) * LOG2E;
    __syncthreads();
    const float* dtp = dt + (size_t)(b * LSEQ + l0) * DIN_ + d;
    const float* xpp = xp + (size_t)(b * LSEQ + l0) * DIN_ + d;
    float h[4] = {}, P[4] = {1.f, 1.f, 1.f, 1.f};
    float dtv = *dtp, xv = *xpp;
    for (int l = 0; l < CL; ++l) {
        float ndt = 0.f, nx = 0.f;
        if (l + 1 < CL) { ndt = dtp[(size_t)(l + 1) * DIN_]; nx = xpp[(size_t)(l + 1) * DIN_]; }
        f32x4 Bv = *(const f32x4*)(s_B + l * 16 + q * 4);
        float dtx = dtv * xv;
#pragma unroll
        for (int j = 0; j < 4; ++j) {
            float dA = __builtin_amdgcn_exp2f(A2[j] * dtv);
            h[j] = fmaf(dA, h[j], Bv[j] * dtx);
            P[j] *= dA;
        }
        dtv = ndt; xv = nx;
    }
    size_t base = (size_t)(b * NCH + c) * 20480 + (size_t)d * 16 + q * 4;
    *(f32x4*)(hloc + base) = (f32x4){h[0], h[1], h[2], h[3]};
    *(f32x4*)(Pp + base)   = (f32x4){P[0], P[1], P[2], P[3]};
}

__global__ __launch_bounds__(256) void k_scan_b(float* __restrict__ hloc, const float* __restrict__ Pp) {
    int i = blockIdx.x * 256 + threadIdx.x;
    int b = i / 20480, dn = i % 20480;
    size_t base = (size_t)b * NCH * 20480 + dn;
    float H = 0.f;
    for (int c = 0; c < NCH; ++c) {
        size_t off = base + (size_t)c * 20480;
        float hl = hloc[off], p = Pp[off];
        hloc[off] = H;
        H = p * H + hl;
    }
}

__global__ __launch_bounds__(256) void k_scan_c(const float* __restrict__ dt, const float* __restrict__ xp,
                                                const float* __restrict__ Bm, const float* __restrict__ Cm,
                                                const float* __restrict__ xz, const float* __restrict__ A_log,
                                                const float* __restrict__ Dvec, const float* __restrict__ Hinit,
                                                float* __restrict__ y) {
    const int tid = threadIdx.x;
    const int q = tid & 3, dloc = tid >> 2;
    const int d0 = blockIdx.x * 64, c = blockIdx.y, b = blockIdx.z;
    const int d = d0 + dloc;
    const int l0 = c * CL;
    __shared__ float s_B[CL * 16], s_C[CL * 16];
    *(f32x4*)(s_B + tid * 4) = *(const f32x4*)(Bm + (size_t)(b * LSEQ + l0) * DST_ + tid * 4);
    *(f32x4*)(s_C + tid * 4) = *(const f32x4*)(Cm + (size_t)(b * LSEQ + l0) * DST_ + tid * 4);
    f32x4 Av = *(const f32x4*)(A_log + (size_t)d * DST_ + q * 4);
    float A2[4];
#pragma unroll
    for (int j = 0; j < 4; ++j) A2[j] = -expf(Av[j]) * LOG2E;
    const float Dd = Dvec[d];
    __syncthreads();
    const float* dtp = dt + (size_t)(b * LSEQ + l0) * DIN_ + d;
    const float* xpp = xp + (size_t)(b * LSEQ + l0) * DIN_ + d;
    const float* zp  = xz + (size_t)(b * LSEQ + l0) * DXZ + DIN_ + d;
    float* yp = y + (size_t)(b * LSEQ + l0) * DIN_ + d;
    size_t base = (size_t)(b * NCH + c) * 20480 + (size_t)d * 16 + q * 4;
    f32x4 hv = *(const f32x4*)(Hinit + base);
    float h[4] = {hv[0], hv[1], hv[2], hv[3]};
    float dtv = *dtp, xv = *xpp, zv = *zp;
    for (int l = 0; l < CL; ++l) {
        float ndt = 0.f, nx = 0.f, nz = 0.f;
        if (l + 1 < CL) {
            ndt = dtp[(size_t)(l + 1) * DIN_];
            nx  = xpp[(size_t)(l + 1) * DIN_];
            nz  = zp[(size_t)(l + 1) * DXZ];
        }
        f32x4 Bv = *(const f32x4*)(s_B + l * 16 + q * 4);
        f32x4 Cv = *(const f32x4*)(s_C + l * 16 + q * 4);
        float dtx = dtv * xv;
        float yv = 0.f;
#pragma unroll
        for (int j = 0; j < 4; ++j) {
            float dA = __builtin_amdgcn_exp2f(A2[j] * dtv);
            h[j] = fmaf(dA, h[j], Bv[j] * dtx);
            yv = fmaf(h[j], Cv[j], yv);
        }
        yv += __shfl_xor(yv, 1);
        yv += __shfl_xor(yv, 2);
        if (q == 0) {
            float sig = 1.f / (1.f + __builtin_amdgcn_exp2f(-zv * LOG2E));
            yp[(size_t)l * DIN_] = (yv + xv * Dd) * (zv * sig);
        }
        dtv = ndt; xv = nx; zv = nz;
    }
}

// ---------------- rmsnorm(y,out_nw) + quant (bf16 out) ----------------
__global__ __launch_bounds__(256) void k_norm_y(const float* __restrict__ y,
                                                const float* __restrict__ out_nw,
                                                __hip_bfloat16* __restrict__ yq, float* __restrict__ gy) {
    const int r = blockIdx.x, tid = threadIdx.x;
    const float* yr = y + (size_t)r * DIN_;
    __shared__ float red[256];
    float v[5];
    float ss = 0.f;
#pragma unroll
    for (int j = 0; j < 5; j++) { v[j] = yr[tid + j * 256]; ss += v[j] * v[j]; }
    float sum = block_reduce_sum256(ss, red);
    float rms = 1.f / sqrtf(sum / DIN_ + EPS_);
    float mx = 0.f;
#pragma unroll
    for (int j = 0; j < 5; j++) {
        int i = tid + j * 256;
        v[j] = v[j] * rms * out_nw[i];
        mx = fmaxf(mx, fabsf(v[j]));
    }
    float g = fmaxf(block_reduce_max256(mx, red), 1e-10f);
    if (tid == 0) gy[r] = g;
    float s = 127.f / g;
#pragma unroll
    for (int j = 0; j < 5; j++) {
        int i = tid + j * 256;
        yq[(size_t)r * DIN_ + i] = __float2bfloat16(fminf(fmaxf(rintf(v[j] * s), -128.f), 127.f));
    }
}

extern "C" void kernel_launch(void* const* d_in, const int* in_sizes, int n_in,
                              void* d_out, int out_size, void* d_ws, size_t ws_size,
                              hipStream_t stream) {
    (void)in_sizes; (void)n_in; (void)out_size;
    const float* x      = (const float*)d_in[0];
    const float* norm_w = (const float*)d_in[1];
    const float* in_w   = (const float*)d_in[2];
    const float* in_nw  = (const float*)d_in[3];
    const float* conv_w = (const float*)d_in[4];
    const float* conv_b = (const float*)d_in[5];
    const float* dtu_w  = (const float*)d_in[6];
    const float* dtu_nw = (const float*)d_in[7];
    const float* dtd_w  = (const float*)d_in[8];
    const float* dtd_b  = (const float*)d_in[9];
    const float* Bp_w   = (const float*)d_in[10];
    const float* Bp_nw  = (const float*)d_in[11];
    const float* Cp_w   = (const float*)d_in[12];
    const float* Cp_nw  = (const float*)d_in[13];
    const float* A_log  = (const float*)d_in[14];
    const float* Dv     = (const float*)d_in[15];
    const float* out_w  = (const float*)d_in[16];
    const float* out_nw = (const float*)d_in[17];

    float* ws = (float*)d_ws;
    float* alphas   = ws;                      // 8
    float* partials = ws + 8;                  // 5*256
    float* xq1      = ws + 8 + 5 * 256;        // bf16 activations; later reused as hloc/Pp
    float* gamma1   = xq1 + (size_t)NROWS * H_;
    float* xz       = gamma1 + NROWS;
    float* xp       = xz + (size_t)NROWS * DXZ;
    float* xpn     = xp + (size_t)NROWS * DIN_;        // y (scan output)
    float* g3       = xpn + (size_t)NROWS * DIN_;
    float* dtu_out  = g3 + 3 * NROWS;                  // raw integer dots (memset 0 each call)
    float* Bmat     = dtu_out + (size_t)NROWS * DTR_;
    float* Cmat     = Bmat + (size_t)NROWS * DST_;
    float* dtb      = Cmat + (size_t)NROWS * DST_;     // later reused as yq (bf16)
    float* gy       = dtb + (size_t)NROWS * DIN_;
    float* wq_in    = gy + NROWS;                      // bf16
    float* wq_dtu   = wq_in + (size_t)DXZ * H_;        // (unused, kept for layout)
    float* wq_Bp    = wq_dtu + (size_t)DTR_ * DIN_;
    float* wq_Cp    = wq_Bp + (size_t)DST_ * DIN_;
    float* wq_out   = wq_Cp + (size_t)DST_ * DIN_;     // bf16
    float* rinv     = wq_out + (size_t)H_ * DIN_;      // NROWS
    float* wq_sk    = rinv + NROWS;                    // 5*40*64*8 bf16 = 51200 float slots
    size_t need = (size_t)((wq_sk + 51200) - ws) * sizeof(float);
    if (ws_size < need) return;

    float* hloc = xq1;
    float* Pp   = xq1 + (size_t)2 * NCH * 20480;

    hipMemsetAsync(dtu_out, 0, (size_t)NROWS * 72 * sizeof(float), stream);

    const int n0 = DXZ * H_, n1 = DTR_ * DIN_, n2 = DST_ * DIN_, n3 = DST_ * DIN_, n4 = H_ * DIN_;
    hipLaunchKernelGGL(absmean_partial5, dim3(256, 5), dim3(256), 0, stream,
                       in_w, dtu_w, Bp_w, Cp_w, out_w, n0, n1, n2, n3, n4, partials);
    hipLaunchKernelGGL(absmean_final5, dim3(5), dim3(256), 0, stream, partials, n0, n1, n2, n3, n4, alphas);
    hipLaunchKernelGGL(quant_w2, dim3((n0 + 255) / 256, 2), dim3(256), 0, stream,
                       in_w, out_w, n0, n4, alphas, (__hip_bfloat16*)wq_in, (__hip_bfloat16*)wq_out);
    hipLaunchKernelGGL(build_wq_sk, dim3(50), dim3(256), 0, stream,
                       dtu_w, Bp_w, Cp_w, alphas, (ushort_t*)wq_sk);

    hipLaunchKernelGGL(k_norm_quant_in, dim3(NROWS), dim3(256), 0, stream,
                       x, norm_w, in_nw, (__hip_bfloat16*)xq1, gamma1);
    hipLaunchKernelGGL(k_gemm_mfma, dim3(DXZ / 128, NROWS / 128), dim3(256), 0, stream,
                       (const ushort_t*)xq1, (const ushort_t*)wq_in, alphas + 0, gamma1,
                       (const float*)nullptr, xz, NROWS, DXZ, H_);
    hipLaunchKernelGGL(k_conv_silu, dim3((NROWS * DIN_) / 256), dim3(256), 0, stream, xz, conv_w, conv_b, xp);
    hipLaunchKernelGGL(k_norm_xp, dim3(NROWS), dim3(256), 0, stream, xp, dtu_nw, Bp_nw, Cp_nw, rinv, g3);
    hipLaunchKernelGGL(k_skinny_mfma, dim3(NROWS / 64, KSPLIT), dim3(256), 0, stream,
                       xp, rinv, dtu_nw, Bp_nw, Cp_nw, g3, (const ushort_t*)wq_sk,
                       dtu_out, Bmat, Cmat);
    hipLaunchKernelGGL(k_scale_bc, dim3((NROWS * DST_) / 256), dim3(256), 0, stream, Bmat, Cmat, g3, alphas);
    hipLaunchKernelGGL(k_dtd, dim3(DIN_ / 256, NROWS / 32), dim3(256), 0, stream,
                       dtu_out, dtd_w, dtd_b, g3, alphas, dtb);

    hipLaunchKernelGGL(k_scan_a, dim3(DIN_ / 64, NCH, 2), dim3(256), 0, stream,
                       dtb, xp, Bmat, A_log, hloc, Pp);
    hipLaunchKernelGGL(k_scan_b, dim3((2 * 20480) / 256), dim3(256), 0, stream, hloc, Pp);
    hipLaunchKernelGGL(k_scan_c, dim3(DIN_ / 64, NCH, 2), dim3(256), 0, stream,
                       dtb, xp, Bmat, Cmat, xz, A_log, Dv, hloc, xpn /*y*/);

    hipLaunchKernelGGL(k_norm_y, dim3(NROWS), dim3(256), 0, stream, xpn /*y*/, out_nw,
                       (__hip_bfloat16*)dtb /*yq*/, gy);
    hipLaunchKernelGGL(k_gemm_mfma, dim3(H_ / 128, NROWS / 128), dim3(256), 0, stream,
                       (const ushort_t*)dtb /*yq*/, (const ushort_t*)wq_out, alphas + 4, gy,
                       x /*residual*/, (float*)d_out, NROWS, H_, DIN_);
}

// Round 7
// 267.895 us; speedup vs baseline: 6.3428x; 1.1648x over previous
//
#include <hip/hip_runtime.h>
#include <hip/hip_bf16.h>
#include <cmath>

#define NROWS 4096   // B*L
#define H_    640
#define DIN_  1280
#define DXZ   2560
#define DTR_  40
#define DST_  16
#define LSEQ  2048
#define EPS_  1e-6f
#define NCH   32     // scan chunks
#define CL    64     // chunk length (NCH*CL == LSEQ)
#define KSPLIT 8
#define KCH (DIN_ / KSPLIT)   // 160
#define LOG2E 1.4426950408889634f
#define RLOG2E 0.6931471805599453f

typedef __attribute__((ext_vector_type(8))) short short8;
typedef __attribute__((ext_vector_type(4))) float f32x4;
typedef unsigned short ushort_t;

__device__ __forceinline__ float bf2f(short u) {
    return __uint_as_float((unsigned)(unsigned short)u << 16);
}
// exact for integer-valued floats |x| <= 256 (low mantissa bits are zero)
__device__ __forceinline__ short f2bfs(float x) { return (short)(__float_as_uint(x) >> 16); }

// async global->LDS, 16B per lane; LDS dest = wave-uniform base + lane*16
#define GLD16(gp, lp) __builtin_amdgcn_global_load_lds( \
    (const __attribute__((address_space(1))) unsigned int*)(unsigned long long)(gp), \
    (__attribute__((address_space(3))) unsigned int*)(unsigned int)(unsigned long long)(lp), 16, 0, 0)

// ---------------- fast reductions: wave shfl + 4-slot LDS combine ----------------
__device__ __forceinline__ float wave_sum64(float v) {
    v += __shfl_xor(v, 1);  v += __shfl_xor(v, 2);  v += __shfl_xor(v, 4);
    v += __shfl_xor(v, 8);  v += __shfl_xor(v, 16); v += __shfl_xor(v, 32);
    return v;
}
__device__ __forceinline__ float wave_max64(float v) {
    v = fmaxf(v, __shfl_xor(v, 1));  v = fmaxf(v, __shfl_xor(v, 2));
    v = fmaxf(v, __shfl_xor(v, 4));  v = fmaxf(v, __shfl_xor(v, 8));
    v = fmaxf(v, __shfl_xor(v, 16)); v = fmaxf(v, __shfl_xor(v, 32));
    return v;
}
// 256-thread block sum/max; red4 = 4-float scratch unique to this call site
__device__ __forceinline__ float block_sum4(float v, float* red4) {
    v = wave_sum64(v);
    if ((threadIdx.x & 63) == 0) red4[threadIdx.x >> 6] = v;
    __syncthreads();
    return (red4[0] + red4[1]) + (red4[2] + red4[3]);
}
__device__ __forceinline__ float block_max4(float v, float* red4) {
    v = wave_max64(v);
    if ((threadIdx.x & 63) == 0) red4[threadIdx.x >> 6] = v;
    __syncthreads();
    return fmaxf(fmaxf(red4[0], red4[1]), fmaxf(red4[2], red4[3]));
}
// legacy tree reduce (used by absmean only — not hot)
__device__ __forceinline__ float block_reduce_sum256(float v, float* red) {
    int tid = threadIdx.x;
    red[tid] = v; __syncthreads();
    for (int o = 128; o; o >>= 1) { if (tid < o) red[tid] += red[tid + o]; __syncthreads(); }
    float r = red[0]; __syncthreads();
    return r;
}

// ---------------- batched alpha = max(mean|w|,1e-10) for 5 weights ----------------
__global__ __launch_bounds__(256) void absmean_partial5(const float* __restrict__ w0, const float* __restrict__ w1,
                                                        const float* __restrict__ w2, const float* __restrict__ w3,
                                                        const float* __restrict__ w4,
                                                        int n0, int n1, int n2, int n3, int n4,
                                                        float* __restrict__ partials) {
    const int wi = blockIdx.y;
    const float* w = (wi == 0) ? w0 : (wi == 1) ? w1 : (wi == 2) ? w2 : (wi == 3) ? w3 : w4;
    const int n = (wi == 0) ? n0 : (wi == 1) ? n1 : (wi == 2) ? n2 : (wi == 3) ? n3 : n4;
    __shared__ float red[256];
    float s = 0.f;
    for (int i = blockIdx.x * 256 + threadIdx.x; i < n; i += gridDim.x * 256) s += fabsf(w[i]);
    float t = block_reduce_sum256(s, red);
    if (threadIdx.x == 0) partials[wi * 256 + blockIdx.x] = t;
}
__global__ __launch_bounds__(256) void absmean_final5(const float* __restrict__ partials,
                                                      int n0, int n1, int n2, int n3, int n4,
                                                      float* __restrict__ alphas) {
    const int wi = blockIdx.x;
    const int n = (wi == 0) ? n0 : (wi == 1) ? n1 : (wi == 2) ? n2 : (wi == 3) ? n3 : n4;
    __shared__ double red[256];
    double s = (double)partials[wi * 256 + threadIdx.x];
    red[threadIdx.x] = s; __syncthreads();
    for (int o = 128; o; o >>= 1) { if (threadIdx.x < o) red[threadIdx.x] += red[threadIdx.x + o]; __syncthreads(); }
    if (threadIdx.x == 0) alphas[wi] = fmaxf((float)(red[0] / (double)n), 1e-10f);
}
// ternary quant for the two big weights (in_w -> alphas[0], out_w -> alphas[4]), bf16 out
__global__ __launch_bounds__(256) void quant_w2(const float* __restrict__ w0, const float* __restrict__ w1,
                                                int n0, int n1, const float* __restrict__ alphas,
                                                __hip_bfloat16* __restrict__ q0, __hip_bfloat16* __restrict__ q1) {
    const int wi = blockIdx.y;
    const float* w = wi ? w1 : w0;
    __hip_bfloat16* q = wi ? q1 : q0;
    const int n = wi ? n1 : n0;
    float a = alphas[wi ? 4 : 0];
    for (int i = blockIdx.x * 256 + threadIdx.x; i < n; i += gridDim.x * 256) {
        short v = f2bfs(fminf(fmaxf(rintf(w[i] / a), -1.f), 1.f));
        ((ushort_t*)q)[i] = (ushort_t)v;
    }
}

// ---------------- skinny weights -> MFMA-fragment-linear layout ----------------
__global__ __launch_bounds__(256) void build_wq_sk(const float* __restrict__ dtu_w,
                                                   const float* __restrict__ Bp_w,
                                                   const float* __restrict__ Cp_w,
                                                   const float* __restrict__ alphas,
                                                   ushort_t* __restrict__ wq_sk) {
    int idx = blockIdx.x * 256 + threadIdx.x;
    if (idx >= 5 * 40 * 64) return;
    int t = idx / 2560, rem = idx % 2560, kb = rem / 64, l = rem % 64;
    int nloc = l & 15, kg = l >> 4;
    float alpha; const float* src; int row; bool valid = true;
    if (t < 3)      { alpha = alphas[1]; src = dtu_w; row = t * 16 + nloc; valid = (row < 40); }
    else if (t == 3){ alpha = alphas[2]; src = Bp_w;  row = nloc; }
    else            { alpha = alphas[3]; src = Cp_w;  row = nloc; }
    int k0 = kb * 32 + kg * 8;
    short8 outv;
#pragma unroll
    for (int e = 0; e < 8; ++e) {
        float q = valid ? fminf(fmaxf(rintf(src[(size_t)row * DIN_ + k0 + e] / alpha), -1.f), 1.f) : 0.f;
        outv[e] = f2bfs(q);
    }
    *(short8*)(wq_sk + (size_t)idx * 8) = outv;
}

// ---------------- rmsnorm(x,norm_w) -> rmsnorm(.,in_nw) -> int8 quant (bf16 out) ----------------
__global__ __launch_bounds__(256) void k_norm_quant_in(const float* __restrict__ x,
                                                       const float* __restrict__ norm_w,
                                                       const float* __restrict__ in_nw,
                                                       __hip_bfloat16* __restrict__ xq, float* __restrict__ gamma) {
    const int r = blockIdx.x, tid = threadIdx.x;
    const float* xr = x + (size_t)r * H_;
    __shared__ float red4[12];
    const bool has2 = (tid < H_ - 512);
    float v0 = xr[tid], v1 = xr[tid + 256], v2 = has2 ? xr[tid + 512] : 0.f;
    float sum = block_sum4(v0 * v0 + v1 * v1 + v2 * v2, red4);
    float r1 = 1.f / sqrtf(sum / H_ + EPS_);
    v0 *= r1 * norm_w[tid];
    v1 *= r1 * norm_w[tid + 256];
    if (has2) v2 *= r1 * norm_w[tid + 512];
    sum = block_sum4(v0 * v0 + v1 * v1 + v2 * v2, red4 + 4);
    float r2 = 1.f / sqrtf(sum / H_ + EPS_);
    v0 *= r2 * in_nw[tid];
    v1 *= r2 * in_nw[tid + 256];
    if (has2) v2 *= r2 * in_nw[tid + 512];
    float mx = fmaxf(fmaxf(fabsf(v0), fabsf(v1)), fabsf(v2));
    float g = fmaxf(block_max4(mx, red4 + 8), 1e-10f);
    if (tid == 0) gamma[r] = g;
    float s = 127.f / g;
    __hip_bfloat16* o = xq + (size_t)r * H_;
    o[tid]       = __float2bfloat16(fminf(fmaxf(rintf(v0 * s), -128.f), 127.f));
    o[tid + 256] = __float2bfloat16(fminf(fmaxf(rintf(v1 * s), -128.f), 127.f));
    if (has2) o[tid + 512] = __float2bfloat16(fminf(fmaxf(rintf(v2 * s), -128.f), 127.f));
}

// ---------------- MFMA bf16 quantized GEMM (m97 structure, 128x128 tile, BK=32) ----------------
__global__ __launch_bounds__(256) void k_gemm_mfma(const ushort_t* __restrict__ Aq,
                                                   const ushort_t* __restrict__ Wq,
                                                   const float* __restrict__ alpha_p,
                                                   const float* __restrict__ gamma,
                                                   const float* __restrict__ residual,
                                                   float* __restrict__ out,
                                                   int M, int N, int K) {
    __shared__ ushort_t As[128 * 32];   // swizzled [row][slot^(row&3)][8]
    __shared__ ushort_t Bs[128 * 32];
    const int tid = threadIdx.x;
    const int w = tid >> 6, lane = tid & 63;
    const int wm = w >> 1, wn = w & 1;
    const int row0 = blockIdx.y * 128, col0 = blockIdx.x * 128;
    f32x4 acc[4][4] = {};

    for (int k0 = 0; k0 < K; k0 += 32) {
        #pragma unroll
        for (int q = 0; q < 2; ++q) {
            int c = w * 128 + q * 64 + lane;        // chunk id 0..511
            int row = c >> 2;
            int uslot = (c & 3) ^ (row & 3);        // inverse swizzle on global source
            const ushort_t* ga = Aq + (size_t)(row0 + row) * K + k0 + uslot * 8;
            GLD16(ga, (char*)As + (w * 2048 + q * 1024));
            const ushort_t* gb = Wq + (size_t)(col0 + row) * K + k0 + uslot * 8;
            GLD16(gb, (char*)Bs + (w * 2048 + q * 1024));
        }
        asm volatile("s_waitcnt vmcnt(0)" ::: "memory");
        __syncthreads();

        short8 a[4], b[4];
        #pragma unroll
        for (int i = 0; i < 4; ++i) {
            int row = wm * 64 + i * 16 + (lane & 15);
            int byt = row * 64 + ((((lane >> 4)) ^ (row & 3)) << 4);
            a[i] = *(const short8*)((const char*)As + byt);
        }
        #pragma unroll
        for (int j = 0; j < 4; ++j) {
            int row = wn * 64 + j * 16 + (lane & 15);
            int byt = row * 64 + ((((lane >> 4)) ^ (row & 3)) << 4);
            b[j] = *(const short8*)((const char*)Bs + byt);
        }
        #pragma unroll
        for (int i = 0; i < 4; ++i)
            #pragma unroll
            for (int j = 0; j < 4; ++j)
                acc[i][j] = __builtin_amdgcn_mfma_f32_16x16x32_bf16(a[i], b[j], acc[i][j], 0, 0, 0);
        __syncthreads();
    }

    const float alpha = alpha_p[0];
    #pragma unroll
    for (int i = 0; i < 4; ++i) {
        #pragma unroll
        for (int r = 0; r < 4; ++r) {
            int row = row0 + wm * 64 + i * 16 + (lane >> 4) * 4 + r;
            float s = alpha * gamma[row] * (1.f / 127.f);
            #pragma unroll
            for (int j = 0; j < 4; ++j) {
                int col = col0 + wn * 64 + j * 16 + (lane & 15);
                float o = acc[i][j][r] * s;
                if (residual) o += residual[(size_t)row * N + col];
                out[(size_t)row * N + col] = o;
            }
        }
    }
}

// ---------------- causal depthwise conv (k=4) + silu ----------------
__global__ __launch_bounds__(256) void k_conv_silu(const float* __restrict__ xz,
                                                   const float* __restrict__ cw, const float* __restrict__ cb,
                                                   float* __restrict__ xp) {
    size_t idx = (size_t)blockIdx.x * 256 + threadIdx.x;
    int d = (int)(idx % DIN_);
    size_t row = idx / DIN_;
    int l = (int)(row % LSEQ);
    float s = cb[d];
    const float* c = cw + (size_t)d * 4;
#pragma unroll
    for (int k = 0; k < 4; k++)
        if (l - k >= 0) s += xz[(row - (size_t)k) * DXZ + d] * c[k];
    xp[idx] = s / (1.f + __builtin_amdgcn_exp2f(-s * LOG2E));   // silu
}

// ---------------- rmsnorm scales of x_path: rinv + 3 gammas ----------------
__global__ __launch_bounds__(256) void k_norm_xp(const float* __restrict__ xp,
                                                 const float* __restrict__ dtu_nw,
                                                 const float* __restrict__ Bp_nw,
                                                 const float* __restrict__ Cp_nw,
                                                 float* __restrict__ rinv_out, float* __restrict__ g3) {
    const int r = blockIdx.x, tid = threadIdx.x;
    const float* xr = xp + (size_t)r * DIN_;
    __shared__ float red4[16];
    float v[5];
    float ss = 0.f;
#pragma unroll
    for (int j = 0; j < 5; j++) { v[j] = xr[tid + j * 256]; ss += v[j] * v[j]; }
    float sum = block_sum4(ss, red4);
    float rms = 1.f / sqrtf(sum / DIN_ + EPS_);
    float m0 = 0.f, m1 = 0.f, m2 = 0.f;
#pragma unroll
    for (int j = 0; j < 5; j++) {
        int i = tid + j * 256;
        float t = v[j] * rms;
        m0 = fmaxf(m0, fabsf(t * dtu_nw[i]));
        m1 = fmaxf(m1, fabsf(t * Bp_nw[i]));
        m2 = fmaxf(m2, fabsf(t * Cp_nw[i]));
    }
    float g0 = block_max4(m0, red4 + 4);
    float g1 = block_max4(m1, red4 + 8);
    float g2 = block_max4(m2, red4 + 12);
    if (tid == 0) {
        rinv_out[r]       = rms;
        g3[r]             = fmaxf(g0, 1e-10f);
        g3[NROWS + r]     = fmaxf(g1, 1e-10f);
        g3[2 * NROWS + r] = fmaxf(g2, 1e-10f);
    }
}

// ---------------- fused quant + 3 skinny MFMA GEMMs, K-split with exact f32 atomics ----------------
__global__ __launch_bounds__(256) void k_skinny_mfma(const float* __restrict__ xp,
                                                     const float* __restrict__ rinv,
                                                     const float* __restrict__ dtu_nw,
                                                     const float* __restrict__ Bp_nw,
                                                     const float* __restrict__ Cp_nw,
                                                     const float* __restrict__ g3,
                                                     const ushort_t* __restrict__ wq_sk,
                                                     float* __restrict__ dtu_acc,
                                                     float* __restrict__ B_acc,
                                                     float* __restrict__ C_acc) {
    const int tid = threadIdx.x;
    const int w = tid >> 6, l = tid & 63;
    const int row0 = blockIdx.x * 64;
    const int kc0 = blockIdx.y * KCH;
    __shared__ float s_xp[64 * 36];          // +4 pad: conflict-free frag reads
    __shared__ float s_nw[3 * KCH];
    for (int i = tid; i < 3 * KCH; i += 256) {
        int m = i / KCH, j = i - m * KCH;
        const float* nw = (m == 0) ? dtu_nw : (m == 1) ? Bp_nw : Cp_nw;
        s_nw[i] = nw[kc0 + j];
    }
    const int arow = row0 + w * 16 + (l & 15);
    const float ri = rinv[arow];
    const float s0 = 127.f / g3[arow];
    const float s1 = 127.f / g3[NROWS + arow];
    const float s2 = 127.f / g3[2 * NROWS + arow];
    const int kgrp = l >> 4;
    f32x4 acc[5] = {};

    for (int ks = 0; ks < KCH / 32; ++ks) {
        const int kc = kc0 + ks * 32;
        __syncthreads();
        {
            int srow = tid >> 2, scol = (tid & 3) * 8;
            const float* gp = xp + (size_t)(row0 + srow) * DIN_ + kc + scol;
            f32x4 u0 = *(const f32x4*)gp;
            f32x4 u1 = *(const f32x4*)(gp + 4);
            *(f32x4*)(s_xp + srow * 36 + scol)     = u0;
            *(f32x4*)(s_xp + srow * 36 + scol + 4) = u1;
        }
        __syncthreads();
        const float* sp = s_xp + (w * 16 + (l & 15)) * 36 + kgrp * 8;
        f32x4 t0 = *(const f32x4*)sp;
        f32x4 t1 = *(const f32x4*)(sp + 4);
        float t[8] = { t0[0]*ri, t0[1]*ri, t0[2]*ri, t0[3]*ri,
                       t1[0]*ri, t1[1]*ri, t1[2]*ri, t1[3]*ri };
        short8 a0, a1, a2;
        #pragma unroll
        for (int e = 0; e < 8; ++e) {
            int kk = ks * 32 + kgrp * 8 + e;
            float q0 = fminf(fmaxf(rintf(t[e] * s_nw[kk]           * s0), -128.f), 127.f);
            float q1 = fminf(fmaxf(rintf(t[e] * s_nw[KCH + kk]     * s1), -128.f), 127.f);
            float q2 = fminf(fmaxf(rintf(t[e] * s_nw[2 * KCH + kk] * s2), -128.f), 127.f);
            a0[e] = f2bfs(q0); a1[e] = f2bfs(q1); a2[e] = f2bfs(q2);
        }
        const int kbg = kc >> 5;
        short8 b0 = *(const short8*)(wq_sk + ((size_t)(0 * 40 + kbg) * 64 + l) * 8);
        short8 b1 = *(const short8*)(wq_sk + ((size_t)(1 * 40 + kbg) * 64 + l) * 8);
        short8 b2 = *(const short8*)(wq_sk + ((size_t)(2 * 40 + kbg) * 64 + l) * 8);
        short8 b3 = *(const short8*)(wq_sk + ((size_t)(3 * 40 + kbg) * 64 + l) * 8);
        short8 b4 = *(const short8*)(wq_sk + ((size_t)(4 * 40 + kbg) * 64 + l) * 8);
        acc[0] = __builtin_amdgcn_mfma_f32_16x16x32_bf16(a0, b0, acc[0], 0, 0, 0);
        acc[1] = __builtin_amdgcn_mfma_f32_16x16x32_bf16(a0, b1, acc[1], 0, 0, 0);
        acc[2] = __builtin_amdgcn_mfma_f32_16x16x32_bf16(a0, b2, acc[2], 0, 0, 0);
        acc[3] = __builtin_amdgcn_mfma_f32_16x16x32_bf16(a1, b3, acc[3], 0, 0, 0);
        acc[4] = __builtin_amdgcn_mfma_f32_16x16x32_bf16(a2, b4, acc[4], 0, 0, 0);
    }

    const int col = l & 15;
    const int rbase = row0 + w * 16 + (l >> 4) * 4;
    #pragma unroll
    for (int j = 0; j < 4; ++j) {
        int r = rbase + j;
        atomicAdd(&dtu_acc[(size_t)r * DTR_ + col],      acc[0][j]);
        atomicAdd(&dtu_acc[(size_t)r * DTR_ + 16 + col], acc[1][j]);
        if (col < 8) atomicAdd(&dtu_acc[(size_t)r * DTR_ + 32 + col], acc[2][j]);
        atomicAdd(&B_acc[(size_t)r * DST_ + col], acc[3][j]);
        atomicAdd(&C_acc[(size_t)r * DST_ + col], acc[4][j]);
    }
}

// scale B/C raw integer dots in place
__global__ __launch_bounds__(256) void k_scale_bc(float* __restrict__ Bm, float* __restrict__ Cm,
                                                  const float* __restrict__ g3, const float* __restrict__ alphas) {
    int idx = blockIdx.x * 256 + threadIdx.x;     // < NROWS*16
    int r = idx >> 4;
    float a2 = alphas[2], a3 = alphas[3];
    Bm[idx] = ((Bm[idx] * a2) * g3[NROWS + r]) * (1.f / 127.f);
    Cm[idx] = ((Cm[idx] * a3) * g3[2 * NROWS + r]) * (1.f / 127.f);
}

// ---------------- dt = softplus((raw_dot*scale) @ dtd_w.T + b) ----------------
// 128 cols x 32 rows per block, 256 threads (tid&127 = col, tid>>7 = row half).
__global__ __launch_bounds__(256) void k_dtd(const float* __restrict__ U /*raw acc*/,
                                             const float* __restrict__ W,
                                             const float* __restrict__ bias,
                                             const float* __restrict__ g3,
                                             const float* __restrict__ alphas,
                                             float* __restrict__ dt) {
    const int c0 = blockIdx.x * 128;
    const int r0 = blockIdx.y * 32;
    const int tid = threadIdx.x;
    const int col = tid & 127, rh = tid >> 7;
    __shared__ float s_w[128 * 41];
    __shared__ float s_u[32 * 40];
    for (int i = tid; i < 128 * 40; i += 256) {
        int cc = i / 40, t = i - cc * 40;
        s_w[cc * 41 + t] = W[(size_t)c0 * 40 + i];
    }
    const float alpha = alphas[1];
    for (int i = tid; i < 32 * 40; i += 256) {
        int rr = i / 40;
        s_u[i] = ((U[(size_t)r0 * 40 + i] * alpha) * g3[r0 + rr]) * (1.f / 127.f);
    }
    __syncthreads();
    float w[40];
#pragma unroll
    for (int t = 0; t < 40; t++) w[t] = s_w[col * 41 + t];
    const float b = bias[c0 + col];
    for (int r = 0; r < 16; ++r) {
        const int row = rh * 16 + r;
        const float* ur = s_u + row * 40;
        float a0 = b, a1 = 0.f, a2 = 0.f, a3 = 0.f;
#pragma unroll
        for (int t = 0; t < 40; t += 4) {
            f32x4 uv = *(const f32x4*)(ur + t);
            a0 = fmaf(uv[0], w[t],     a0);
            a1 = fmaf(uv[1], w[t + 1], a1);
            a2 = fmaf(uv[2], w[t + 2], a2);
            a3 = fmaf(uv[3], w[t + 3], a3);
        }
        float s = (a0 + a1) + (a2 + a3);
        // softplus via HW exp2/log2: max(s,0) + ln(1+exp(-|s|))
        float e = __builtin_amdgcn_exp2f(-fabsf(s) * LOG2E);
        float sp = fmaxf(s, 0.f) + __builtin_amdgcn_logf(1.f + e) * RLOG2E;
        dt[(size_t)(r0 + row) * DIN_ + c0 + col] = sp;
    }
}

// ======== chunked selective scan: 4 lanes x 4 states per channel ========
__global__ __launch_bounds__(256) void k_scan_a(const float* __restrict__ dt, const float* __restrict__ xp,
                                                const float* __restrict__ Bm, const float* __restrict__ A_log,
                                                float* __restrict__ hloc, float* __restrict__ Pp) {
    const int tid = threadIdx.x;
    const int q = tid & 3, dloc = tid >> 2;
    const int d0 = blockIdx.x * 64, c = blockIdx.y, b = blockIdx.z;
    const int d = d0 + dloc;
    const int l0 = c * CL;
    __shared__ float s_B[CL * 16];
    *(f32x4*)(s_B + tid * 4) = *(const f32x4*)(Bm + (size_t)(b * LSEQ + l0) * DST_ + tid * 4);
    f32x4 Av = *(const f32x4*)(A_log + (size_t)d * DST_ + q * 4);
    float A2[4];
#pragma unroll
    for (int j = 0; j < 4; ++j) A2[j] = -expf(Av[j]) * LOG2E;
    __syncthreads();
    const float* dtp = dt + (size_t)(b * LSEQ + l0) * DIN_ + d;
    const float* xpp = xp + (size_t)(b * LSEQ + l0) * DIN_ + d;
    float h[4] = {}, P[4] = {1.f, 1.f, 1.f, 1.f};
    float dtv = *dtp, xv = *xpp;
    for (int l = 0; l < CL; ++l) {
        float ndt = 0.f, nx = 0.f;
        if (l + 1 < CL) { ndt = dtp[(size_t)(l + 1) * DIN_]; nx = xpp[(size_t)(l + 1) * DIN_]; }
        f32x4 Bv = *(const f32x4*)(s_B + l * 16 + q * 4);
        float dtx = dtv * xv;
#pragma unroll
        for (int j = 0; j < 4; ++j) {
            float dA = __builtin_amdgcn_exp2f(A2[j] * dtv);
            h[j] = fmaf(dA, h[j], Bv[j] * dtx);
            P[j] *= dA;
        }
        dtv = ndt; xv = nx;
    }
    size_t base = (size_t)(b * NCH + c) * 20480 + (size_t)d * 16 + q * 4;
    *(f32x4*)(hloc + base) = (f32x4){h[0], h[1], h[2], h[3]};
    *(f32x4*)(Pp + base)   = (f32x4){P[0], P[1], P[2], P[3]};
}

__global__ __launch_bounds__(256) void k_scan_b(float* __restrict__ hloc, const float* __restrict__ Pp) {
    int i = blockIdx.x * 256 + threadIdx.x;
    int b = i / 20480, dn = i % 20480;
    size_t base = (size_t)b * NCH * 20480 + dn;
    float H = 0.f;
    for (int c = 0; c < NCH; ++c) {
        size_t off = base + (size_t)c * 20480;
        float hl = hloc[off], p = Pp[off];
        hloc[off] = H;
        H = p * H + hl;
    }
}

__global__ __launch_bounds__(256) void k_scan_c(const float* __restrict__ dt, const float* __restrict__ xp,
                                                const float* __restrict__ Bm, const float* __restrict__ Cm,
                                                const float* __restrict__ xz, const float* __restrict__ A_log,
                                                const float* __restrict__ Dvec, const float* __restrict__ Hinit,
                                                float* __restrict__ y) {
    const int tid = threadIdx.x;
    const int q = tid & 3, dloc = tid >> 2;
    const int d0 = blockIdx.x * 64, c = blockIdx.y, b = blockIdx.z;
    const int d = d0 + dloc;
    const int l0 = c * CL;
    __shared__ float s_B[CL * 16], s_C[CL * 16];
    *(f32x4*)(s_B + tid * 4) = *(const f32x4*)(Bm + (size_t)(b * LSEQ + l0) * DST_ + tid * 4);
    *(f32x4*)(s_C + tid * 4) = *(const f32x4*)(Cm + (size_t)(b * LSEQ + l0) * DST_ + tid * 4);
    f32x4 Av = *(const f32x4*)(A_log + (size_t)d * DST_ + q * 4);
    float A2[4];
#pragma unroll
    for (int j = 0; j < 4; ++j) A2[j] = -expf(Av[j]) * LOG2E;
    const float Dd = Dvec[d];
    __syncthreads();
    const float* dtp = dt + (size_t)(b * LSEQ + l0) * DIN_ + d;
    const float* xpp = xp + (size_t)(b * LSEQ + l0) * DIN_ + d;
    const float* zp  = xz + (size_t)(b * LSEQ + l0) * DXZ + DIN_ + d;
    float* yp = y + (size_t)(b * LSEQ + l0) * DIN_ + d;
    size_t base = (size_t)(b * NCH + c) * 20480 + (size_t)d * 16 + q * 4;
    f32x4 hv = *(const f32x4*)(Hinit + base);
    float h[4] = {hv[0], hv[1], hv[2], hv[3]};
    float dtv = *dtp, xv = *xpp, zv = *zp;
    for (int l = 0; l < CL; ++l) {
        float ndt = 0.f, nx = 0.f, nz = 0.f;
        if (l + 1 < CL) {
            ndt = dtp[(size_t)(l + 1) * DIN_];
            nx  = xpp[(size_t)(l + 1) * DIN_];
            nz  = zp[(size_t)(l + 1) * DXZ];
        }
        f32x4 Bv = *(const f32x4*)(s_B + l * 16 + q * 4);
        f32x4 Cv = *(const f32x4*)(s_C + l * 16 + q * 4);
        float dtx = dtv * xv;
        float yv = 0.f;
#pragma unroll
        for (int j = 0; j < 4; ++j) {
            float dA = __builtin_amdgcn_exp2f(A2[j] * dtv);
            h[j] = fmaf(dA, h[j], Bv[j] * dtx);
            yv = fmaf(h[j], Cv[j], yv);
        }
        yv += __shfl_xor(yv, 1);
        yv += __shfl_xor(yv, 2);
        if (q == 0) {
            float sig = 1.f / (1.f + __builtin_amdgcn_exp2f(-zv * LOG2E));
            yp[(size_t)l * DIN_] = (yv + xv * Dd) * (zv * sig);
        }
        dtv = ndt; xv = nx; zv = nz;
    }
}

// ---------------- rmsnorm(y,out_nw) + quant (bf16 out) ----------------
__global__ __launch_bounds__(256) void k_norm_y(const float* __restrict__ y,
                                                const float* __restrict__ out_nw,
                                                __hip_bfloat16* __restrict__ yq, float* __restrict__ gy) {
    const int r = blockIdx.x, tid = threadIdx.x;
    const float* yr = y + (size_t)r * DIN_;
    __shared__ float red4[8];
    float v[5];
    float ss = 0.f;
#pragma unroll
    for (int j = 0; j < 5; j++) { v[j] = yr[tid + j * 256]; ss += v[j] * v[j]; }
    float sum = block_sum4(ss, red4);
    float rms = 1.f / sqrtf(sum / DIN_ + EPS_);
    float mx = 0.f;
#pragma unroll
    for (int j = 0; j < 5; j++) {
        int i = tid + j * 256;
        v[j] = v[j] * rms * out_nw[i];
        mx = fmaxf(mx, fabsf(v[j]));
    }
    float g = fmaxf(block_max4(mx, red4 + 4), 1e-10f);
    if (tid == 0) gy[r] = g;
    float s = 127.f / g;
#pragma unroll
    for (int j = 0; j < 5; j++) {
        int i = tid + j * 256;
        yq[(size_t)r * DIN_ + i] = __float2bfloat16(fminf(fmaxf(rintf(v[j] * s), -128.f), 127.f));
    }
}

extern "C" void kernel_launch(void* const* d_in, const int* in_sizes, int n_in,
                              void* d_out, int out_size, void* d_ws, size_t ws_size,
                              hipStream_t stream) {
    (void)in_sizes; (void)n_in; (void)out_size;
    const float* x      = (const float*)d_in[0];
    const float* norm_w = (const float*)d_in[1];
    const float* in_w   = (const float*)d_in[2];
    const float* in_nw  = (const float*)d_in[3];
    const float* conv_w = (const float*)d_in[4];
    const float* conv_b = (const float*)d_in[5];
    const float* dtu_w  = (const float*)d_in[6];
    const float* dtu_nw = (const float*)d_in[7];
    const float* dtd_w  = (const float*)d_in[8];
    const float* dtd_b  = (const float*)d_in[9];
    const float* Bp_w   = (const float*)d_in[10];
    const float* Bp_nw  = (const float*)d_in[11];
    const float* Cp_w   = (const float*)d_in[12];
    const float* Cp_nw  = (const float*)d_in[13];
    const float* A_log  = (const float*)d_in[14];
    const float* Dv     = (const float*)d_in[15];
    const float* out_w  = (const float*)d_in[16];
    const float* out_nw = (const float*)d_in[17];

    float* ws = (float*)d_ws;
    float* alphas   = ws;                      // 8
    float* partials = ws + 8;                  // 5*256
    float* xq1      = ws + 8 + 5 * 256;        // bf16 activations; later reused as hloc/Pp
    float* gamma1   = xq1 + (size_t)NROWS * H_;
    float* xz       = gamma1 + NROWS;
    float* xp       = xz + (size_t)NROWS * DXZ;
    float* xpn     = xp + (size_t)NROWS * DIN_;        // y (scan output)
    float* g3       = xpn + (size_t)NROWS * DIN_;
    float* dtu_out  = g3 + 3 * NROWS;                  // raw integer dots (memset 0 each call)
    float* Bmat     = dtu_out + (size_t)NROWS * DTR_;
    float* Cmat     = Bmat + (size_t)NROWS * DST_;
    float* dtb      = Cmat + (size_t)NROWS * DST_;     // later reused as yq (bf16)
    float* gy       = dtb + (size_t)NROWS * DIN_;
    float* wq_in    = gy + NROWS;                      // bf16
    float* wq_dtu   = wq_in + (size_t)DXZ * H_;        // (unused, kept for layout)
    float* wq_Bp    = wq_dtu + (size_t)DTR_ * DIN_;
    float* wq_Cp    = wq_Bp + (size_t)DST_ * DIN_;
    float* wq_out   = wq_Cp + (size_t)DST_ * DIN_;     // bf16
    float* rinv     = wq_out + (size_t)H_ * DIN_;      // NROWS
    float* wq_sk    = rinv + NROWS;                    // 5*40*64*8 bf16 = 51200 float slots
    size_t need = (size_t)((wq_sk + 51200) - ws) * sizeof(float);
    if (ws_size < need) return;

    float* hloc = xq1;
    float* Pp   = xq1 + (size_t)2 * NCH * 20480;

    hipMemsetAsync(dtu_out, 0, (size_t)NROWS * 72 * sizeof(float), stream);

    const int n0 = DXZ * H_, n1 = DTR_ * DIN_, n2 = DST_ * DIN_, n3 = DST_ * DIN_, n4 = H_ * DIN_;
    hipLaunchKernelGGL(absmean_partial5, dim3(256, 5), dim3(256), 0, stream,
                       in_w, dtu_w, Bp_w, Cp_w, out_w, n0, n1, n2, n3, n4, partials);
    hipLaunchKernelGGL(absmean_final5, dim3(5), dim3(256), 0, stream, partials, n0, n1, n2, n3, n4, alphas);
    hipLaunchKernelGGL(quant_w2, dim3((n0 + 255) / 256, 2), dim3(256), 0, stream,
                       in_w, out_w, n0, n4, alphas, (__hip_bfloat16*)wq_in, (__hip_bfloat16*)wq_out);
    hipLaunchKernelGGL(build_wq_sk, dim3(50), dim3(256), 0, stream,
                       dtu_w, Bp_w, Cp_w, alphas, (ushort_t*)wq_sk);

    hipLaunchKernelGGL(k_norm_quant_in, dim3(NROWS), dim3(256), 0, stream,
                       x, norm_w, in_nw, (__hip_bfloat16*)xq1, gamma1);
    hipLaunchKernelGGL(k_gemm_mfma, dim3(DXZ / 128, NROWS / 128), dim3(256), 0, stream,
                       (const ushort_t*)xq1, (const ushort_t*)wq_in, alphas + 0, gamma1,
                       (const float*)nullptr, xz, NROWS, DXZ, H_);
    hipLaunchKernelGGL(k_conv_silu, dim3((NROWS * DIN_) / 256), dim3(256), 0, stream, xz, conv_w, conv_b, xp);
    hipLaunchKernelGGL(k_norm_xp, dim3(NROWS), dim3(256), 0, stream, xp, dtu_nw, Bp_nw, Cp_nw, rinv, g3);
    hipLaunchKernelGGL(k_skinny_mfma, dim3(NROWS / 64, KSPLIT), dim3(256), 0, stream,
                       xp, rinv, dtu_nw, Bp_nw, Cp_nw, g3, (const ushort_t*)wq_sk,
                       dtu_out, Bmat, Cmat);
    hipLaunchKernelGGL(k_scale_bc, dim3((NROWS * DST_) / 256), dim3(256), 0, stream, Bmat, Cmat, g3, alphas);
    hipLaunchKernelGGL(k_dtd, dim3(DIN_ / 128, NROWS / 32), dim3(256), 0, stream,
                       dtu_out, dtd_w, dtd_b, g3, alphas, dtb);

    hipLaunchKernelGGL(k_scan_a, dim3(DIN_ / 64, NCH, 2), dim3(256), 0, stream,
                       dtb, xp, Bmat, A_log, hloc, Pp);
    hipLaunchKernelGGL(k_scan_b, dim3((2 * 20480) / 256), dim3(256), 0, stream, hloc, Pp);
    hipLaunchKernelGGL(k_scan_c, dim3(DIN_ / 64, NCH, 2), dim3(256), 0, stream,
                       dtb, xp, Bmat, Cmat, xz, A_log, Dv, hloc, xpn /*y*/);

    hipLaunchKernelGGL(k_norm_y, dim3(NROWS), dim3(256), 0, stream, xpn /*y*/, out_nw,
                       (__hip_bfloat16*)dtb /*yq*/, gy);
    hipLaunchKernelGGL(k_gemm_mfma, dim3(H_ / 128, NROWS / 128), dim3(256), 0, stream,
                       (const ushort_t*)dtb /*yq*/, (const ushort_t*)wq_out, alphas + 4, gy,
                       x /*residual*/, (float*)d_out, NROWS, H_, DIN_);
}

// Round 8
// 240.775 us; speedup vs baseline: 7.0572x; 1.1126x over previous
//
#include <hip/hip_runtime.h>
#include <hip/hip_bf16.h>
#include <cmath>

#define NROWS 4096   // B*L
#define H_    640
#define DIN_  1280
#define DXZ   2560
#define DTR_  40
#define DST_  16
#define LSEQ  2048
#define EPS_  1e-6f
#define NCH   32     // scan chunks
#define CL    64     // chunk length (NCH*CL == LSEQ)
#define KSPLIT 8
#define KCH (DIN_ / KSPLIT)   // 160
#define LOG2E 1.4426950408889634f
#define RLOG2E 0.6931471805599453f

typedef __attribute__((ext_vector_type(8))) short short8;
typedef __attribute__((ext_vector_type(4))) float f32x4;
typedef unsigned short ushort_t;

__device__ __forceinline__ float bf2f(short u) {
    return __uint_as_float((unsigned)(unsigned short)u << 16);
}
// exact for integer-valued floats |x| <= 256 (low mantissa bits are zero)
__device__ __forceinline__ short f2bfs(float x) { return (short)(__float_as_uint(x) >> 16); }

// async global->LDS, 16B per lane; LDS dest = wave-uniform base + lane*16
#define GLD16(gp, lp) __builtin_amdgcn_global_load_lds( \
    (const __attribute__((address_space(1))) unsigned int*)(unsigned long long)(gp), \
    (__attribute__((address_space(3))) unsigned int*)(unsigned int)(unsigned long long)(lp), 16, 0, 0)

// ---------------- fast reductions: wave shfl + 4-slot LDS combine ----------------
__device__ __forceinline__ float wave_sum64(float v) {
    v += __shfl_xor(v, 1);  v += __shfl_xor(v, 2);  v += __shfl_xor(v, 4);
    v += __shfl_xor(v, 8);  v += __shfl_xor(v, 16); v += __shfl_xor(v, 32);
    return v;
}
__device__ __forceinline__ float wave_max64(float v) {
    v = fmaxf(v, __shfl_xor(v, 1));  v = fmaxf(v, __shfl_xor(v, 2));
    v = fmaxf(v, __shfl_xor(v, 4));  v = fmaxf(v, __shfl_xor(v, 8));
    v = fmaxf(v, __shfl_xor(v, 16)); v = fmaxf(v, __shfl_xor(v, 32));
    return v;
}
__device__ __forceinline__ float block_sum4(float v, float* red4) {
    v = wave_sum64(v);
    if ((threadIdx.x & 63) == 0) red4[threadIdx.x >> 6] = v;
    __syncthreads();
    return (red4[0] + red4[1]) + (red4[2] + red4[3]);
}
__device__ __forceinline__ float block_max4(float v, float* red4) {
    v = wave_max64(v);
    if ((threadIdx.x & 63) == 0) red4[threadIdx.x >> 6] = v;
    __syncthreads();
    return fmaxf(fmaxf(red4[0], red4[1]), fmaxf(red4[2], red4[3]));
}
__device__ __forceinline__ float block_reduce_sum256(float v, float* red) {
    int tid = threadIdx.x;
    red[tid] = v; __syncthreads();
    for (int o = 128; o; o >>= 1) { if (tid < o) red[tid] += red[tid + o]; __syncthreads(); }
    float r = red[0]; __syncthreads();
    return r;
}

// ---------------- batched alpha = max(mean|w|,1e-10) for 5 weights ----------------
__global__ __launch_bounds__(256) void absmean_partial5(const float* __restrict__ w0, const float* __restrict__ w1,
                                                        const float* __restrict__ w2, const float* __restrict__ w3,
                                                        const float* __restrict__ w4,
                                                        int n0, int n1, int n2, int n3, int n4,
                                                        float* __restrict__ partials) {
    const int wi = blockIdx.y;
    const float* w = (wi == 0) ? w0 : (wi == 1) ? w1 : (wi == 2) ? w2 : (wi == 3) ? w3 : w4;
    const int n = (wi == 0) ? n0 : (wi == 1) ? n1 : (wi == 2) ? n2 : (wi == 3) ? n3 : n4;
    __shared__ float red[256];
    float s = 0.f;
    for (int i = blockIdx.x * 256 + threadIdx.x; i < n; i += gridDim.x * 256) s += fabsf(w[i]);
    float t = block_reduce_sum256(s, red);
    if (threadIdx.x == 0) partials[wi * 256 + blockIdx.x] = t;
}
__global__ __launch_bounds__(256) void absmean_final5(const float* __restrict__ partials,
                                                      int n0, int n1, int n2, int n3, int n4,
                                                      float* __restrict__ alphas) {
    const int wi = blockIdx.x;
    const int n = (wi == 0) ? n0 : (wi == 1) ? n1 : (wi == 2) ? n2 : (wi == 3) ? n3 : n4;
    __shared__ double red[256];
    double s = (double)partials[wi * 256 + threadIdx.x];
    red[threadIdx.x] = s; __syncthreads();
    for (int o = 128; o; o >>= 1) { if (threadIdx.x < o) red[threadIdx.x] += red[threadIdx.x + o]; __syncthreads(); }
    if (threadIdx.x == 0) alphas[wi] = fmaxf((float)(red[0] / (double)n), 1e-10f);
}
__global__ __launch_bounds__(256) void quant_w2(const float* __restrict__ w0, const float* __restrict__ w1,
                                                int n0, int n1, const float* __restrict__ alphas,
                                                __hip_bfloat16* __restrict__ q0, __hip_bfloat16* __restrict__ q1) {
    const int wi = blockIdx.y;
    const float* w = wi ? w1 : w0;
    __hip_bfloat16* q = wi ? q1 : q0;
    const int n = wi ? n1 : n0;
    float a = alphas[wi ? 4 : 0];
    for (int i = blockIdx.x * 256 + threadIdx.x; i < n; i += gridDim.x * 256) {
        short v = f2bfs(fminf(fmaxf(rintf(w[i] / a), -1.f), 1.f));
        ((ushort_t*)q)[i] = (ushort_t)v;
    }
}

// ---------------- skinny weights -> MFMA-fragment-linear layout ----------------
__global__ __launch_bounds__(256) void build_wq_sk(const float* __restrict__ dtu_w,
                                                   const float* __restrict__ Bp_w,
                                                   const float* __restrict__ Cp_w,
                                                   const float* __restrict__ alphas,
                                                   ushort_t* __restrict__ wq_sk) {
    int idx = blockIdx.x * 256 + threadIdx.x;
    if (idx >= 5 * 40 * 64) return;
    int t = idx / 2560, rem = idx % 2560, kb = rem / 64, l = rem % 64;
    int nloc = l & 15, kg = l >> 4;
    float alpha; const float* src; int row; bool valid = true;
    if (t < 3)      { alpha = alphas[1]; src = dtu_w; row = t * 16 + nloc; valid = (row < 40); }
    else if (t == 3){ alpha = alphas[2]; src = Bp_w;  row = nloc; }
    else            { alpha = alphas[3]; src = Cp_w;  row = nloc; }
    int k0 = kb * 32 + kg * 8;
    short8 outv;
#pragma unroll
    for (int e = 0; e < 8; ++e) {
        float q = valid ? fminf(fmaxf(rintf(src[(size_t)row * DIN_ + k0 + e] / alpha), -1.f), 1.f) : 0.f;
        outv[e] = f2bfs(q);
    }
    *(short8*)(wq_sk + (size_t)idx * 8) = outv;
}

// ---------------- rmsnorm(x,norm_w) -> rmsnorm(.,in_nw) -> int8 quant (bf16 out) ----------------
__global__ __launch_bounds__(256) void k_norm_quant_in(const float* __restrict__ x,
                                                       const float* __restrict__ norm_w,
                                                       const float* __restrict__ in_nw,
                                                       __hip_bfloat16* __restrict__ xq, float* __restrict__ gamma) {
    const int r = blockIdx.x, tid = threadIdx.x;
    const float* xr = x + (size_t)r * H_;
    __shared__ float red4[12];
    const bool has2 = (tid < H_ - 512);
    float v0 = xr[tid], v1 = xr[tid + 256], v2 = has2 ? xr[tid + 512] : 0.f;
    float sum = block_sum4(v0 * v0 + v1 * v1 + v2 * v2, red4);
    float r1 = 1.f / sqrtf(sum / H_ + EPS_);
    v0 *= r1 * norm_w[tid];
    v1 *= r1 * norm_w[tid + 256];
    if (has2) v2 *= r1 * norm_w[tid + 512];
    sum = block_sum4(v0 * v0 + v1 * v1 + v2 * v2, red4 + 4);
    float r2 = 1.f / sqrtf(sum / H_ + EPS_);
    v0 *= r2 * in_nw[tid];
    v1 *= r2 * in_nw[tid + 256];
    if (has2) v2 *= r2 * in_nw[tid + 512];
    float mx = fmaxf(fmaxf(fabsf(v0), fabsf(v1)), fabsf(v2));
    float g = fmaxf(block_max4(mx, red4 + 8), 1e-10f);
    if (tid == 0) gamma[r] = g;
    float s = 127.f / g;
    __hip_bfloat16* o = xq + (size_t)r * H_;
    o[tid]       = __float2bfloat16(fminf(fmaxf(rintf(v0 * s), -128.f), 127.f));
    o[tid + 256] = __float2bfloat16(fminf(fmaxf(rintf(v1 * s), -128.f), 127.f));
    if (has2) o[tid + 512] = __float2bfloat16(fminf(fmaxf(rintf(v2 * s), -128.f), 127.f));
}

// ---------------- MFMA bf16 quantized GEMM: double-buffered, counted-vmcnt pipeline ----------------
// BMxBN tile, 4 waves (2x2), XCD-swizzled grid. NL = (BM+BN)/64 gload_lds per wave per stage.
template<int BM, int BN>
__global__ __launch_bounds__(256) void k_gemm_mfma(const ushort_t* __restrict__ Aq,
                                                   const ushort_t* __restrict__ Wq,
                                                   const float* __restrict__ alpha_p,
                                                   const float* __restrict__ gamma,
                                                   const float* __restrict__ residual,
                                                   float* __restrict__ out,
                                                   int M, int N, int K) {
    constexpr int FM = BM / 32, FN = BN / 32;
    constexpr int NL = (BM + BN) / 64;
    __shared__ ushort_t As[2][BM * 32];   // swizzled [row][slot^(row&3)][8]
    __shared__ ushort_t Bs[2][BN * 32];
    const int tid = threadIdx.x;
    const int w = tid >> 6, lane = tid & 63;
    const int wm = w >> 1, wn = w & 1;
    // bijective XCD swizzle (nwg % 8 == 0 for all our launches)
    const int nwg = gridDim.x * gridDim.y;
    const int hw = blockIdx.y * gridDim.x + blockIdx.x;
    const int work = (nwg % 8 == 0) ? ((hw & 7) * (nwg >> 3) + (hw >> 3)) : hw;
    const int row0 = (work / gridDim.x) * BM;
    const int col0 = (work % gridDim.x) * BN;
    f32x4 acc[FM][FN] = {};

    auto stage = [&](int buf, int k0) {
        #pragma unroll
        for (int q = 0; q < BM / 64; ++q) {
            int c = w * BM + q * 64 + lane;         // chunk 0..4*BM-1 across 4 waves
            int row = c >> 2;
            int uslot = (c & 3) ^ (row & 3);        // inverse swizzle on global source
            GLD16(Aq + (size_t)(row0 + row) * K + k0 + uslot * 8,
                  (char*)As[buf] + (w * BM + q * 64) * 16);
        }
        #pragma unroll
        for (int q = 0; q < BN / 64; ++q) {
            int c = w * BN + q * 64 + lane;
            int row = c >> 2;
            int uslot = (c & 3) ^ (row & 3);
            GLD16(Wq + (size_t)(col0 + row) * K + k0 + uslot * 8,
                  (char*)Bs[buf] + (w * BN + q * 64) * 16);
        }
    };

    stage(0, 0);
    const int NT = K >> 5;
    for (int t = 0; t < NT; ++t) {
        const int cur = t & 1;
        if (t + 1 < NT) {
            stage(cur ^ 1, (t + 1) << 5);           // prefetch stays in flight across barrier
            if constexpr (NL == 2)      asm volatile("s_waitcnt vmcnt(2)" ::: "memory");
            else if constexpr (NL == 3) asm volatile("s_waitcnt vmcnt(3)" ::: "memory");
            else                        asm volatile("s_waitcnt vmcnt(4)" ::: "memory");
        } else {
            asm volatile("s_waitcnt vmcnt(0)" ::: "memory");
        }
        __builtin_amdgcn_s_barrier();               // buf[cur] ready for all waves

        short8 a[FM], b[FN];
        #pragma unroll
        for (int i = 0; i < FM; ++i) {
            int row = wm * (BM / 2) + i * 16 + (lane & 15);
            int byt = row * 64 + (((lane >> 4) ^ (row & 3)) << 4);
            a[i] = *(const short8*)((const char*)As[cur] + byt);
        }
        #pragma unroll
        for (int j = 0; j < FN; ++j) {
            int row = wn * (BN / 2) + j * 16 + (lane & 15);
            int byt = row * 64 + (((lane >> 4) ^ (row & 3)) << 4);
            b[j] = *(const short8*)((const char*)Bs[cur] + byt);
        }
        #pragma unroll
        for (int i = 0; i < FM; ++i)
            #pragma unroll
            for (int j = 0; j < FN; ++j)
                acc[i][j] = __builtin_amdgcn_mfma_f32_16x16x32_bf16(a[i], b[j], acc[i][j], 0, 0, 0);
        asm volatile("" ::: "memory");              // pin LDS reads above the barrier
        __builtin_amdgcn_s_barrier();               // all waves done reading buf[cur]
    }

    const float alpha = alpha_p[0];
    #pragma unroll
    for (int i = 0; i < FM; ++i) {
        #pragma unroll
        for (int r = 0; r < 4; ++r) {
            int row = row0 + wm * (BM / 2) + i * 16 + (lane >> 4) * 4 + r;
            float s = alpha * gamma[row] * (1.f / 127.f);
            #pragma unroll
            for (int j = 0; j < FN; ++j) {
                int col = col0 + wn * (BN / 2) + j * 16 + (lane & 15);
                float o = acc[i][j][r] * s;
                if (residual) o += residual[(size_t)row * N + col];
                out[(size_t)row * N + col] = o;
            }
        }
    }
}

// ---------------- causal depthwise conv (k=4) + silu ----------------
__global__ __launch_bounds__(256) void k_conv_silu(const float* __restrict__ xz,
                                                   const float* __restrict__ cw, const float* __restrict__ cb,
                                                   float* __restrict__ xp) {
    size_t idx = (size_t)blockIdx.x * 256 + threadIdx.x;
    int d = (int)(idx % DIN_);
    size_t row = idx / DIN_;
    int l = (int)(row % LSEQ);
    float s = cb[d];
    const float* c = cw + (size_t)d * 4;
#pragma unroll
    for (int k = 0; k < 4; k++)
        if (l - k >= 0) s += xz[(row - (size_t)k) * DXZ + d] * c[k];
    xp[idx] = s / (1.f + __builtin_amdgcn_exp2f(-s * LOG2E));   // silu
}

// ---------------- rmsnorm scales of x_path: rinv + 3 gammas ----------------
__global__ __launch_bounds__(256) void k_norm_xp(const float* __restrict__ xp,
                                                 const float* __restrict__ dtu_nw,
                                                 const float* __restrict__ Bp_nw,
                                                 const float* __restrict__ Cp_nw,
                                                 float* __restrict__ rinv_out, float* __restrict__ g3) {
    const int r = blockIdx.x, tid = threadIdx.x;
    const float* xr = xp + (size_t)r * DIN_;
    __shared__ float red4[16];
    float v[5];
    float ss = 0.f;
#pragma unroll
    for (int j = 0; j < 5; j++) { v[j] = xr[tid + j * 256]; ss += v[j] * v[j]; }
    float sum = block_sum4(ss, red4);
    float rms = 1.f / sqrtf(sum / DIN_ + EPS_);
    float m0 = 0.f, m1 = 0.f, m2 = 0.f;
#pragma unroll
    for (int j = 0; j < 5; j++) {
        int i = tid + j * 256;
        float t = v[j] * rms;
        m0 = fmaxf(m0, fabsf(t * dtu_nw[i]));
        m1 = fmaxf(m1, fabsf(t * Bp_nw[i]));
        m2 = fmaxf(m2, fabsf(t * Cp_nw[i]));
    }
    float g0 = block_max4(m0, red4 + 4);
    float g1 = block_max4(m1, red4 + 8);
    float g2 = block_max4(m2, red4 + 12);
    if (tid == 0) {
        rinv_out[r]       = rms;
        g3[r]             = fmaxf(g0, 1e-10f);
        g3[NROWS + r]     = fmaxf(g1, 1e-10f);
        g3[2 * NROWS + r] = fmaxf(g2, 1e-10f);
    }
}

// ---------------- fused quant + 3 skinny MFMA GEMMs, K-split with exact f32 atomics ----------------
__global__ __launch_bounds__(256) void k_skinny_mfma(const float* __restrict__ xp,
                                                     const float* __restrict__ rinv,
                                                     const float* __restrict__ dtu_nw,
                                                     const float* __restrict__ Bp_nw,
                                                     const float* __restrict__ Cp_nw,
                                                     const float* __restrict__ g3,
                                                     const ushort_t* __restrict__ wq_sk,
                                                     float* __restrict__ dtu_acc,
                                                     float* __restrict__ B_acc,
                                                     float* __restrict__ C_acc) {
    const int tid = threadIdx.x;
    const int w = tid >> 6, l = tid & 63;
    const int row0 = blockIdx.x * 64;
    const int kc0 = blockIdx.y * KCH;
    __shared__ float s_xp[64 * 36];          // +4 pad: conflict-free frag reads
    __shared__ float s_nw[3 * KCH];
    for (int i = tid; i < 3 * KCH; i += 256) {
        int m = i / KCH, j = i - m * KCH;
        const float* nw = (m == 0) ? dtu_nw : (m == 1) ? Bp_nw : Cp_nw;
        s_nw[i] = nw[kc0 + j];
    }
    const int arow = row0 + w * 16 + (l & 15);
    const float ri = rinv[arow];
    const float s0 = 127.f / g3[arow];
    const float s1 = 127.f / g3[NROWS + arow];
    const float s2 = 127.f / g3[2 * NROWS + arow];
    const int kgrp = l >> 4;
    f32x4 acc[5] = {};

    for (int ks = 0; ks < KCH / 32; ++ks) {
        const int kc = kc0 + ks * 32;
        __syncthreads();
        {
            int srow = tid >> 2, scol = (tid & 3) * 8;
            const float* gp = xp + (size_t)(row0 + srow) * DIN_ + kc + scol;
            f32x4 u0 = *(const f32x4*)gp;
            f32x4 u1 = *(const f32x4*)(gp + 4);
            *(f32x4*)(s_xp + srow * 36 + scol)     = u0;
            *(f32x4*)(s_xp + srow * 36 + scol + 4) = u1;
        }
        __syncthreads();
        const float* sp = s_xp + (w * 16 + (l & 15)) * 36 + kgrp * 8;
        f32x4 t0 = *(const f32x4*)sp;
        f32x4 t1 = *(const f32x4*)(sp + 4);
        float t[8] = { t0[0]*ri, t0[1]*ri, t0[2]*ri, t0[3]*ri,
                       t1[0]*ri, t1[1]*ri, t1[2]*ri, t1[3]*ri };
        short8 a0, a1, a2;
        #pragma unroll
        for (int e = 0; e < 8; ++e) {
            int kk = ks * 32 + kgrp * 8 + e;
            float q0 = fminf(fmaxf(rintf(t[e] * s_nw[kk]           * s0), -128.f), 127.f);
            float q1 = fminf(fmaxf(rintf(t[e] * s_nw[KCH + kk]     * s1), -128.f), 127.f);
            float q2 = fminf(fmaxf(rintf(t[e] * s_nw[2 * KCH + kk] * s2), -128.f), 127.f);
            a0[e] = f2bfs(q0); a1[e] = f2bfs(q1); a2[e] = f2bfs(q2);
        }
        const int kbg = kc >> 5;
        short8 b0 = *(const short8*)(wq_sk + ((size_t)(0 * 40 + kbg) * 64 + l) * 8);
        short8 b1 = *(const short8*)(wq_sk + ((size_t)(1 * 40 + kbg) * 64 + l) * 8);
        short8 b2 = *(const short8*)(wq_sk + ((size_t)(2 * 40 + kbg) * 64 + l) * 8);
        short8 b3 = *(const short8*)(wq_sk + ((size_t)(3 * 40 + kbg) * 64 + l) * 8);
        short8 b4 = *(const short8*)(wq_sk + ((size_t)(4 * 40 + kbg) * 64 + l) * 8);
        acc[0] = __builtin_amdgcn_mfma_f32_16x16x32_bf16(a0, b0, acc[0], 0, 0, 0);
        acc[1] = __builtin_amdgcn_mfma_f32_16x16x32_bf16(a0, b1, acc[1], 0, 0, 0);
        acc[2] = __builtin_amdgcn_mfma_f32_16x16x32_bf16(a0, b2, acc[2], 0, 0, 0);
        acc[3] = __builtin_amdgcn_mfma_f32_16x16x32_bf16(a1, b3, acc[3], 0, 0, 0);
        acc[4] = __builtin_amdgcn_mfma_f32_16x16x32_bf16(a2, b4, acc[4], 0, 0, 0);
    }

    const int col = l & 15;
    const int rbase = row0 + w * 16 + (l >> 4) * 4;
    #pragma unroll
    for (int j = 0; j < 4; ++j) {
        int r = rbase + j;
        atomicAdd(&dtu_acc[(size_t)r * DTR_ + col],      acc[0][j]);
        atomicAdd(&dtu_acc[(size_t)r * DTR_ + 16 + col], acc[1][j]);
        if (col < 8) atomicAdd(&dtu_acc[(size_t)r * DTR_ + 32 + col], acc[2][j]);
        atomicAdd(&B_acc[(size_t)r * DST_ + col], acc[3][j]);
        atomicAdd(&C_acc[(size_t)r * DST_ + col], acc[4][j]);
    }
}

// scale B/C raw integer dots in place
__global__ __launch_bounds__(256) void k_scale_bc(float* __restrict__ Bm, float* __restrict__ Cm,
                                                  const float* __restrict__ g3, const float* __restrict__ alphas) {
    int idx = blockIdx.x * 256 + threadIdx.x;     // < NROWS*16
    int r = idx >> 4;
    float a2 = alphas[2], a3 = alphas[3];
    Bm[idx] = ((Bm[idx] * a2) * g3[NROWS + r]) * (1.f / 127.f);
    Cm[idx] = ((Cm[idx] * a3) * g3[2 * NROWS + r]) * (1.f / 127.f);
}

// ---------------- dt = softplus((raw_dot*scale) @ dtd_w.T + b) ----------------
__global__ __launch_bounds__(256) void k_dtd(const float* __restrict__ U /*raw acc*/,
                                             const float* __restrict__ W,
                                             const float* __restrict__ bias,
                                             const float* __restrict__ g3,
                                             const float* __restrict__ alphas,
                                             float* __restrict__ dt) {
    const int c0 = blockIdx.x * 128;
    const int r0 = blockIdx.y * 32;
    const int tid = threadIdx.x;
    const int col = tid & 127, rh = tid >> 7;
    __shared__ float s_w[128 * 41];
    __shared__ float s_u[32 * 40];
    for (int i = tid; i < 128 * 40; i += 256) {
        int cc = i / 40, t = i - cc * 40;
        s_w[cc * 41 + t] = W[(size_t)c0 * 40 + i];
    }
    const float alpha = alphas[1];
    for (int i = tid; i < 32 * 40; i += 256) {
        int rr = i / 40;
        s_u[i] = ((U[(size_t)r0 * 40 + i] * alpha) * g3[r0 + rr]) * (1.f / 127.f);
    }
    __syncthreads();
    float w[40];
#pragma unroll
    for (int t = 0; t < 40; t++) w[t] = s_w[col * 41 + t];
    const float b = bias[c0 + col];
    for (int r = 0; r < 16; ++r) {
        const int row = rh * 16 + r;
        const float* ur = s_u + row * 40;
        float a0 = b, a1 = 0.f, a2 = 0.f, a3 = 0.f;
#pragma unroll
        for (int t = 0; t < 40; t += 4) {
            f32x4 uv = *(const f32x4*)(ur + t);
            a0 = fmaf(uv[0], w[t],     a0);
            a1 = fmaf(uv[1], w[t + 1], a1);
            a2 = fmaf(uv[2], w[t + 2], a2);
            a3 = fmaf(uv[3], w[t + 3], a3);
        }
        float s = (a0 + a1) + (a2 + a3);
        float e = __builtin_amdgcn_exp2f(-fabsf(s) * LOG2E);
        float sp = fmaxf(s, 0.f) + __builtin_amdgcn_logf(1.f + e) * RLOG2E;
        dt[(size_t)(r0 + row) * DIN_ + c0 + col] = sp;
    }
}

// ======== chunked selective scan: 4 lanes x 4 states per channel ========
__global__ __launch_bounds__(256) void k_scan_a(const float* __restrict__ dt, const float* __restrict__ xp,
                                                const float* __restrict__ Bm, const float* __restrict__ A_log,
                                                float* __restrict__ hloc, float* __restrict__ Pp) {
    const int tid = threadIdx.x;
    const int q = tid & 3, dloc = tid >> 2;
    const int d0 = blockIdx.x * 64, c = blockIdx.y, b = blockIdx.z;
    const int d = d0 + dloc;
    const int l0 = c * CL;
    __shared__ float s_B[CL * 16];
    *(f32x4*)(s_B + tid * 4) = *(const f32x4*)(Bm + (size_t)(b * LSEQ + l0) * DST_ + tid * 4);
    f32x4 Av = *(const f32x4*)(A_log + (size_t)d * DST_ + q * 4);
    float A2[4];
#pragma unroll
    for (int j = 0; j < 4; ++j) A2[j] = -expf(Av[j]) * LOG2E;
    __syncthreads();
    const float* dtp = dt + (size_t)(b * LSEQ + l0) * DIN_ + d;
    const float* xpp = xp + (size_t)(b * LSEQ + l0) * DIN_ + d;
    float h[4] = {}, P[4] = {1.f, 1.f, 1.f, 1.f};
    float dtv = *dtp, xv = *xpp;
    for (int l = 0; l < CL; ++l) {
        float ndt = 0.f, nx = 0.f;
        if (l + 1 < CL) { ndt = dtp[(size_t)(l + 1) * DIN_]; nx = xpp[(size_t)(l + 1) * DIN_]; }
        f32x4 Bv = *(const f32x4*)(s_B + l * 16 + q * 4);
        float dtx = dtv * xv;
#pragma unroll
        for (int j = 0; j < 4; ++j) {
            float dA = __builtin_amdgcn_exp2f(A2[j] * dtv);
            h[j] = fmaf(dA, h[j], Bv[j] * dtx);
            P[j] *= dA;
        }
        dtv = ndt; xv = nx;
    }
    size_t base = (size_t)(b * NCH + c) * 20480 + (size_t)d * 16 + q * 4;
    *(f32x4*)(hloc + base) = (f32x4){h[0], h[1], h[2], h[3]};
    *(f32x4*)(Pp + base)   = (f32x4){P[0], P[1], P[2], P[3]};
}

__global__ __launch_bounds__(256) void k_scan_b(float* __restrict__ hloc, const float* __restrict__ Pp) {
    int i = blockIdx.x * 256 + threadIdx.x;
    int b = i / 20480, dn = i % 20480;
    size_t base = (size_t)b * NCH * 20480 + dn;
    float H = 0.f;
    for (int c = 0; c < NCH; ++c) {
        size_t off = base + (size_t)c * 20480;
        float hl = hloc[off], p = Pp[off];
        hloc[off] = H;
        H = p * H + hl;
    }
}

__global__ __launch_bounds__(256) void k_scan_c(const float* __restrict__ dt, const float* __restrict__ xp,
                                                const float* __restrict__ Bm, const float* __restrict__ Cm,
                                                const float* __restrict__ xz, const float* __restrict__ A_log,
                                                const float* __restrict__ Dvec, const float* __restrict__ Hinit,
                                                float* __restrict__ y) {
    const int tid = threadIdx.x;
    const int q = tid & 3, dloc = tid >> 2;
    const int d0 = blockIdx.x * 64, c = blockIdx.y, b = blockIdx.z;
    const int d = d0 + dloc;
    const int l0 = c * CL;
    __shared__ float s_B[CL * 16], s_C[CL * 16];
    *(f32x4*)(s_B + tid * 4) = *(const f32x4*)(Bm + (size_t)(b * LSEQ + l0) * DST_ + tid * 4);
    *(f32x4*)(s_C + tid * 4) = *(const f32x4*)(Cm + (size_t)(b * LSEQ + l0) * DST_ + tid * 4);
    f32x4 Av = *(const f32x4*)(A_log + (size_t)d * DST_ + q * 4);
    float A2[4];
#pragma unroll
    for (int j = 0; j < 4; ++j) A2[j] = -expf(Av[j]) * LOG2E;
    const float Dd = Dvec[d];
    __syncthreads();
    const float* dtp = dt + (size_t)(b * LSEQ + l0) * DIN_ + d;
    const float* xpp = xp + (size_t)(b * LSEQ + l0) * DIN_ + d;
    const float* zp  = xz + (size_t)(b * LSEQ + l0) * DXZ + DIN_ + d;
    float* yp = y + (size_t)(b * LSEQ + l0) * DIN_ + d;
    size_t base = (size_t)(b * NCH + c) * 20480 + (size_t)d * 16 + q * 4;
    f32x4 hv = *(const f32x4*)(Hinit + base);
    float h[4] = {hv[0], hv[1], hv[2], hv[3]};
    float dtv = *dtp, xv = *xpp, zv = *zp;
    for (int l = 0; l < CL; ++l) {
        float ndt = 0.f, nx = 0.f, nz = 0.f;
        if (l + 1 < CL) {
            ndt = dtp[(size_t)(l + 1) * DIN_];
            nx  = xpp[(size_t)(l + 1) * DIN_];
            nz  = zp[(size_t)(l + 1) * DXZ];
        }
        f32x4 Bv = *(const f32x4*)(s_B + l * 16 + q * 4);
        f32x4 Cv = *(const f32x4*)(s_C + l * 16 + q * 4);
        float dtx = dtv * xv;
        float yv = 0.f;
#pragma unroll
        for (int j = 0; j < 4; ++j) {
            float dA = __builtin_amdgcn_exp2f(A2[j] * dtv);
            h[j] = fmaf(dA, h[j], Bv[j] * dtx);
            yv = fmaf(h[j], Cv[j], yv);
        }
        yv += __shfl_xor(yv, 1);
        yv += __shfl_xor(yv, 2);
        if (q == 0) {
            float sig = 1.f / (1.f + __builtin_amdgcn_exp2f(-zv * LOG2E));
            yp[(size_t)l * DIN_] = (yv + xv * Dd) * (zv * sig);
        }
        dtv = ndt; xv = nx; zv = nz;
    }
}

// ---------------- rmsnorm(y,out_nw) + quant (bf16 out) ----------------
__global__ __launch_bounds__(256) void k_norm_y(const float* __restrict__ y,
                                                const float* __restrict__ out_nw,
                                                __hip_bfloat16* __restrict__ yq, float* __restrict__ gy) {
    const int r = blockIdx.x, tid = threadIdx.x;
    const float* yr = y + (size_t)r * DIN_;
    __shared__ float red4[8];
    float v[5];
    float ss = 0.f;
#pragma unroll
    for (int j = 0; j < 5; j++) { v[j] = yr[tid + j * 256]; ss += v[j] * v[j]; }
    float sum = block_sum4(ss, red4);
    float rms = 1.f / sqrtf(sum / DIN_ + EPS_);
    float mx = 0.f;
#pragma unroll
    for (int j = 0; j < 5; j++) {
        int i = tid + j * 256;
        v[j] = v[j] * rms * out_nw[i];
        mx = fmaxf(mx, fabsf(v[j]));
    }
    float g = fmaxf(block_max4(mx, red4 + 4), 1e-10f);
    if (tid == 0) gy[r] = g;
    float s = 127.f / g;
#pragma unroll
    for (int j = 0; j < 5; j++) {
        int i = tid + j * 256;
        yq[(size_t)r * DIN_ + i] = __float2bfloat16(fminf(fmaxf(rintf(v[j] * s), -128.f), 127.f));
    }
}

extern "C" void kernel_launch(void* const* d_in, const int* in_sizes, int n_in,
                              void* d_out, int out_size, void* d_ws, size_t ws_size,
                              hipStream_t stream) {
    (void)in_sizes; (void)n_in; (void)out_size;
    const float* x      = (const float*)d_in[0];
    const float* norm_w = (const float*)d_in[1];
    const float* in_w   = (const float*)d_in[2];
    const float* in_nw  = (const float*)d_in[3];
    const float* conv_w = (const float*)d_in[4];
    const float* conv_b = (const float*)d_in[5];
    const float* dtu_w  = (const float*)d_in[6];
    const float* dtu_nw = (const float*)d_in[7];
    const float* dtd_w  = (const float*)d_in[8];
    const float* dtd_b  = (const float*)d_in[9];
    const float* Bp_w   = (const float*)d_in[10];
    const float* Bp_nw  = (const float*)d_in[11];
    const float* Cp_w   = (const float*)d_in[12];
    const float* Cp_nw  = (const float*)d_in[13];
    const float* A_log  = (const float*)d_in[14];
    const float* Dv     = (const float*)d_in[15];
    const float* out_w  = (const float*)d_in[16];
    const float* out_nw = (const float*)d_in[17];

    float* ws = (float*)d_ws;
    float* alphas   = ws;                      // 8
    float* partials = ws + 8;                  // 5*256
    float* xq1      = ws + 8 + 5 * 256;        // bf16 activations; later reused as hloc/Pp
    float* gamma1   = xq1 + (size_t)NROWS * H_;
    float* xz       = gamma1 + NROWS;
    float* xp       = xz + (size_t)NROWS * DXZ;
    float* xpn     = xp + (size_t)NROWS * DIN_;        // y (scan output)
    float* g3       = xpn + (size_t)NROWS * DIN_;
    float* dtu_out  = g3 + 3 * NROWS;                  // raw integer dots (memset 0 each call)
    float* Bmat     = dtu_out + (size_t)NROWS * DTR_;
    float* Cmat     = Bmat + (size_t)NROWS * DST_;
    float* dtb      = Cmat + (size_t)NROWS * DST_;     // later reused as yq (bf16)
    float* gy       = dtb + (size_t)NROWS * DIN_;
    float* wq_in    = gy + NROWS;                      // bf16
    float* wq_dtu   = wq_in + (size_t)DXZ * H_;        // (unused, kept for layout)
    float* wq_Bp    = wq_dtu + (size_t)DTR_ * DIN_;
    float* wq_Cp    = wq_Bp + (size_t)DST_ * DIN_;
    float* wq_out   = wq_Cp + (size_t)DST_ * DIN_;     // bf16
    float* rinv     = wq_out + (size_t)H_ * DIN_;      // NROWS
    float* wq_sk    = rinv + NROWS;                    // 5*40*64*8 bf16 = 51200 float slots
    size_t need = (size_t)((wq_sk + 51200) - ws) * sizeof(float);
    if (ws_size < need) return;

    float* hloc = xq1;
    float* Pp   = xq1 + (size_t)2 * NCH * 20480;

    hipMemsetAsync(dtu_out, 0, (size_t)NROWS * 72 * sizeof(float), stream);

    const int n0 = DXZ * H_, n1 = DTR_ * DIN_, n2 = DST_ * DIN_, n3 = DST_ * DIN_, n4 = H_ * DIN_;
    hipLaunchKernelGGL(absmean_partial5, dim3(256, 5), dim3(256), 0, stream,
                       in_w, dtu_w, Bp_w, Cp_w, out_w, n0, n1, n2, n3, n4, partials);
    hipLaunchKernelGGL(absmean_final5, dim3(5), dim3(256), 0, stream, partials, n0, n1, n2, n3, n4, alphas);
    hipLaunchKernelGGL(quant_w2, dim3((n0 + 255) / 256, 2), dim3(256), 0, stream,
                       in_w, out_w, n0, n4, alphas, (__hip_bfloat16*)wq_in, (__hip_bfloat16*)wq_out);
    hipLaunchKernelGGL(build_wq_sk, dim3(50), dim3(256), 0, stream,
                       dtu_w, Bp_w, Cp_w, alphas, (ushort_t*)wq_sk);

    hipLaunchKernelGGL(k_norm_quant_in, dim3(NROWS), dim3(256), 0, stream,
                       x, norm_w, in_nw, (__hip_bfloat16*)xq1, gamma1);
    hipLaunchKernelGGL((k_gemm_mfma<128, 128>), dim3(DXZ / 128, NROWS / 128), dim3(256), 0, stream,
                       (const ushort_t*)xq1, (const ushort_t*)wq_in, alphas + 0, gamma1,
                       (const float*)nullptr, xz, NROWS, DXZ, H_);
    hipLaunchKernelGGL(k_conv_silu, dim3((NROWS * DIN_) / 256), dim3(256), 0, stream, xz, conv_w, conv_b, xp);
    hipLaunchKernelGGL(k_norm_xp, dim3(NROWS), dim3(256), 0, stream, xp, dtu_nw, Bp_nw, Cp_nw, rinv, g3);
    hipLaunchKernelGGL(k_skinny_mfma, dim3(NROWS / 64, KSPLIT), dim3(256), 0, stream,
                       xp, rinv, dtu_nw, Bp_nw, Cp_nw, g3, (const ushort_t*)wq_sk,
                       dtu_out, Bmat, Cmat);
    hipLaunchKernelGGL(k_scale_bc, dim3((NROWS * DST_) / 256), dim3(256), 0, stream, Bmat, Cmat, g3, alphas);
    hipLaunchKernelGGL(k_dtd, dim3(DIN_ / 128, NROWS / 32), dim3(256), 0, stream,
                       dtu_out, dtd_w, dtd_b, g3, alphas, dtb);

    hipLaunchKernelGGL(k_scan_a, dim3(DIN_ / 64, NCH, 2), dim3(256), 0, stream,
                       dtb, xp, Bmat, A_log, hloc, Pp);
    hipLaunchKernelGGL(k_scan_b, dim3((2 * 20480) / 256), dim3(256), 0, stream, hloc, Pp);
    hipLaunchKernelGGL(k_scan_c, dim3(DIN_ / 64, NCH, 2), dim3(256), 0, stream,
                       dtb, xp, Bmat, Cmat, xz, A_log, Dv, hloc, xpn /*y*/);

    hipLaunchKernelGGL(k_norm_y, dim3(NROWS), dim3(256), 0, stream, xpn /*y*/, out_nw,
                       (__hip_bfloat16*)dtb /*yq*/, gy);
    hipLaunchKernelGGL((k_gemm_mfma<64, 64>), dim3(H_ / 64, NROWS / 64), dim3(256), 0, stream,
                       (const ushort_t*)dtb /*yq*/, (const ushort_t*)wq_out, alphas + 4, gy,
                       x /*residual*/, (float*)d_out, NROWS, H_, DIN_);
}

// Round 9
// 228.611 us; speedup vs baseline: 7.4327x; 1.0532x over previous
//
#include <hip/hip_runtime.h>
#include <hip/hip_bf16.h>
#include <cmath>

#define NROWS 4096   // B*L
#define H_    640
#define DIN_  1280
#define DXZ   2560
#define DTR_  40
#define DST_  16
#define LSEQ  2048
#define EPS_  1e-6f
#define NCH   64     // scan chunks
#define CL    32     // chunk length (NCH*CL == LSEQ)
#define KSPLIT 8
#define KCH (DIN_ / KSPLIT)   // 160
#define LOG2E 1.4426950408889634f
#define RLOG2E 0.6931471805599453f

typedef __attribute__((ext_vector_type(8))) short short8;
typedef __attribute__((ext_vector_type(4))) float f32x4;
typedef unsigned short ushort_t;

__device__ __forceinline__ float bf2f(short u) {
    return __uint_as_float((unsigned)(unsigned short)u << 16);
}
// exact for integer-valued floats |x| <= 256 (low mantissa bits are zero)
__device__ __forceinline__ short f2bfs(float x) { return (short)(__float_as_uint(x) >> 16); }

// async global->LDS, 16B per lane; LDS dest = wave-uniform base + lane*16
#define GLD16(gp, lp) __builtin_amdgcn_global_load_lds( \
    (const __attribute__((address_space(1))) unsigned int*)(unsigned long long)(gp), \
    (__attribute__((address_space(3))) unsigned int*)(unsigned int)(unsigned long long)(lp), 16, 0, 0)

// ---------------- fast reductions: wave shfl + 4-slot LDS combine ----------------
__device__ __forceinline__ float wave_sum64(float v) {
    v += __shfl_xor(v, 1);  v += __shfl_xor(v, 2);  v += __shfl_xor(v, 4);
    v += __shfl_xor(v, 8);  v += __shfl_xor(v, 16); v += __shfl_xor(v, 32);
    return v;
}
__device__ __forceinline__ float wave_max64(float v) {
    v = fmaxf(v, __shfl_xor(v, 1));  v = fmaxf(v, __shfl_xor(v, 2));
    v = fmaxf(v, __shfl_xor(v, 4));  v = fmaxf(v, __shfl_xor(v, 8));
    v = fmaxf(v, __shfl_xor(v, 16)); v = fmaxf(v, __shfl_xor(v, 32));
    return v;
}
__device__ __forceinline__ float block_sum4(float v, float* red4) {
    v = wave_sum64(v);
    if ((threadIdx.x & 63) == 0) red4[threadIdx.x >> 6] = v;
    __syncthreads();
    return (red4[0] + red4[1]) + (red4[2] + red4[3]);
}
__device__ __forceinline__ float block_max4(float v, float* red4) {
    v = wave_max64(v);
    if ((threadIdx.x & 63) == 0) red4[threadIdx.x >> 6] = v;
    __syncthreads();
    return fmaxf(fmaxf(red4[0], red4[1]), fmaxf(red4[2], red4[3]));
}
__device__ __forceinline__ float block_reduce_sum256(float v, float* red) {
    int tid = threadIdx.x;
    red[tid] = v; __syncthreads();
    for (int o = 128; o; o >>= 1) { if (tid < o) red[tid] += red[tid + o]; __syncthreads(); }
    float r = red[0]; __syncthreads();
    return r;
}

// ---------------- batched alpha = max(mean|w|,1e-10) for 5 weights ----------------
__global__ __launch_bounds__(256) void absmean_partial5(const float* __restrict__ w0, const float* __restrict__ w1,
                                                        const float* __restrict__ w2, const float* __restrict__ w3,
                                                        const float* __restrict__ w4,
                                                        int n0, int n1, int n2, int n3, int n4,
                                                        float* __restrict__ partials) {
    const int wi = blockIdx.y;
    const float* w = (wi == 0) ? w0 : (wi == 1) ? w1 : (wi == 2) ? w2 : (wi == 3) ? w3 : w4;
    const int n = (wi == 0) ? n0 : (wi == 1) ? n1 : (wi == 2) ? n2 : (wi == 3) ? n3 : n4;
    __shared__ float red[256];
    float s = 0.f;
    for (int i = blockIdx.x * 256 + threadIdx.x; i < n; i += gridDim.x * 256) s += fabsf(w[i]);
    float t = block_reduce_sum256(s, red);
    if (threadIdx.x == 0) partials[wi * 256 + blockIdx.x] = t;
}
__global__ __launch_bounds__(256) void absmean_final5(const float* __restrict__ partials,
                                                      int n0, int n1, int n2, int n3, int n4,
                                                      float* __restrict__ alphas) {
    const int wi = blockIdx.x;
    const int n = (wi == 0) ? n0 : (wi == 1) ? n1 : (wi == 2) ? n2 : (wi == 3) ? n3 : n4;
    __shared__ double red[256];
    double s = (double)partials[wi * 256 + threadIdx.x];
    red[threadIdx.x] = s; __syncthreads();
    for (int o = 128; o; o >>= 1) { if (threadIdx.x < o) red[threadIdx.x] += red[threadIdx.x + o]; __syncthreads(); }
    if (threadIdx.x == 0) alphas[wi] = fmaxf((float)(red[0] / (double)n), 1e-10f);
}
__global__ __launch_bounds__(256) void quant_w2(const float* __restrict__ w0, const float* __restrict__ w1,
                                                int n0, int n1, const float* __restrict__ alphas,
                                                __hip_bfloat16* __restrict__ q0, __hip_bfloat16* __restrict__ q1) {
    const int wi = blockIdx.y;
    const float* w = wi ? w1 : w0;
    __hip_bfloat16* q = wi ? q1 : q0;
    const int n = wi ? n1 : n0;
    float a = alphas[wi ? 4 : 0];
    for (int i = blockIdx.x * 256 + threadIdx.x; i < n; i += gridDim.x * 256) {
        short v = f2bfs(fminf(fmaxf(rintf(w[i] / a), -1.f), 1.f));
        ((ushort_t*)q)[i] = (ushort_t)v;
    }
}

// ---------------- skinny weights -> MFMA-fragment-linear layout ----------------
__global__ __launch_bounds__(256) void build_wq_sk(const float* __restrict__ dtu_w,
                                                   const float* __restrict__ Bp_w,
                                                   const float* __restrict__ Cp_w,
                                                   const float* __restrict__ alphas,
                                                   ushort_t* __restrict__ wq_sk) {
    int idx = blockIdx.x * 256 + threadIdx.x;
    if (idx >= 5 * 40 * 64) return;
    int t = idx / 2560, rem = idx % 2560, kb = rem / 64, l = rem % 64;
    int nloc = l & 15, kg = l >> 4;
    float alpha; const float* src; int row; bool valid = true;
    if (t < 3)      { alpha = alphas[1]; src = dtu_w; row = t * 16 + nloc; valid = (row < 40); }
    else if (t == 3){ alpha = alphas[2]; src = Bp_w;  row = nloc; }
    else            { alpha = alphas[3]; src = Cp_w;  row = nloc; }
    int k0 = kb * 32 + kg * 8;
    short8 outv;
#pragma unroll
    for (int e = 0; e < 8; ++e) {
        float q = valid ? fminf(fmaxf(rintf(src[(size_t)row * DIN_ + k0 + e] / alpha), -1.f), 1.f) : 0.f;
        outv[e] = f2bfs(q);
    }
    *(short8*)(wq_sk + (size_t)idx * 8) = outv;
}

// ---------------- rmsnorm(x,norm_w) -> rmsnorm(.,in_nw) -> int8 quant (bf16 out) ----------------
__global__ __launch_bounds__(256) void k_norm_quant_in(const float* __restrict__ x,
                                                       const float* __restrict__ norm_w,
                                                       const float* __restrict__ in_nw,
                                                       __hip_bfloat16* __restrict__ xq, float* __restrict__ gamma) {
    const int r = blockIdx.x, tid = threadIdx.x;
    const float* xr = x + (size_t)r * H_;
    __shared__ float red4[12];
    const bool has2 = (tid < H_ - 512);
    float v0 = xr[tid], v1 = xr[tid + 256], v2 = has2 ? xr[tid + 512] : 0.f;
    float sum = block_sum4(v0 * v0 + v1 * v1 + v2 * v2, red4);
    float r1 = 1.f / sqrtf(sum / H_ + EPS_);
    v0 *= r1 * norm_w[tid];
    v1 *= r1 * norm_w[tid + 256];
    if (has2) v2 *= r1 * norm_w[tid + 512];
    sum = block_sum4(v0 * v0 + v1 * v1 + v2 * v2, red4 + 4);
    float r2 = 1.f / sqrtf(sum / H_ + EPS_);
    v0 *= r2 * in_nw[tid];
    v1 *= r2 * in_nw[tid + 256];
    if (has2) v2 *= r2 * in_nw[tid + 512];
    float mx = fmaxf(fmaxf(fabsf(v0), fabsf(v1)), fabsf(v2));
    float g = fmaxf(block_max4(mx, red4 + 8), 1e-10f);
    if (tid == 0) gamma[r] = g;
    float s = 127.f / g;
    __hip_bfloat16* o = xq + (size_t)r * H_;
    o[tid]       = __float2bfloat16(fminf(fmaxf(rintf(v0 * s), -128.f), 127.f));
    o[tid + 256] = __float2bfloat16(fminf(fmaxf(rintf(v1 * s), -128.f), 127.f));
    if (has2) o[tid + 512] = __float2bfloat16(fminf(fmaxf(rintf(v2 * s), -128.f), 127.f));
}

// ---------------- MFMA bf16 quantized GEMM: double-buffered, counted-vmcnt pipeline ----------------
template<int BM, int BN>
__global__ __launch_bounds__(256) void k_gemm_mfma(const ushort_t* __restrict__ Aq,
                                                   const ushort_t* __restrict__ Wq,
                                                   const float* __restrict__ alpha_p,
                                                   const float* __restrict__ gamma,
                                                   const float* __restrict__ residual,
                                                   float* __restrict__ out,
                                                   int M, int N, int K) {
    constexpr int FM = BM / 32, FN = BN / 32;
    constexpr int NL = (BM + BN) / 64;
    __shared__ ushort_t As[2][BM * 32];   // swizzled [row][slot^(row&3)][8]
    __shared__ ushort_t Bs[2][BN * 32];
    const int tid = threadIdx.x;
    const int w = tid >> 6, lane = tid & 63;
    const int wm = w >> 1, wn = w & 1;
    const int nwg = gridDim.x * gridDim.y;
    const int hw = blockIdx.y * gridDim.x + blockIdx.x;
    const int work = (nwg % 8 == 0) ? ((hw & 7) * (nwg >> 3) + (hw >> 3)) : hw;
    const int row0 = (work / gridDim.x) * BM;
    const int col0 = (work % gridDim.x) * BN;
    f32x4 acc[FM][FN] = {};

    auto stage = [&](int buf, int k0) {
        #pragma unroll
        for (int q = 0; q < BM / 64; ++q) {
            int c = w * BM + q * 64 + lane;
            int row = c >> 2;
            int uslot = (c & 3) ^ (row & 3);
            GLD16(Aq + (size_t)(row0 + row) * K + k0 + uslot * 8,
                  (char*)As[buf] + (w * BM + q * 64) * 16);
        }
        #pragma unroll
        for (int q = 0; q < BN / 64; ++q) {
            int c = w * BN + q * 64 + lane;
            int row = c >> 2;
            int uslot = (c & 3) ^ (row & 3);
            GLD16(Wq + (size_t)(col0 + row) * K + k0 + uslot * 8,
                  (char*)Bs[buf] + (w * BN + q * 64) * 16);
        }
    };

    stage(0, 0);
    const int NT = K >> 5;
    for (int t = 0; t < NT; ++t) {
        const int cur = t & 1;
        if (t + 1 < NT) {
            stage(cur ^ 1, (t + 1) << 5);
            if constexpr (NL == 2)      asm volatile("s_waitcnt vmcnt(2)" ::: "memory");
            else if constexpr (NL == 3) asm volatile("s_waitcnt vmcnt(3)" ::: "memory");
            else                        asm volatile("s_waitcnt vmcnt(4)" ::: "memory");
        } else {
            asm volatile("s_waitcnt vmcnt(0)" ::: "memory");
        }
        __builtin_amdgcn_s_barrier();

        short8 a[FM], b[FN];
        #pragma unroll
        for (int i = 0; i < FM; ++i) {
            int row = wm * (BM / 2) + i * 16 + (lane & 15);
            int byt = row * 64 + (((lane >> 4) ^ (row & 3)) << 4);
            a[i] = *(const short8*)((const char*)As[cur] + byt);
        }
        #pragma unroll
        for (int j = 0; j < FN; ++j) {
            int row = wn * (BN / 2) + j * 16 + (lane & 15);
            int byt = row * 64 + (((lane >> 4) ^ (row & 3)) << 4);
            b[j] = *(const short8*)((const char*)Bs[cur] + byt);
        }
        #pragma unroll
        for (int i = 0; i < FM; ++i)
            #pragma unroll
            for (int j = 0; j < FN; ++j)
                acc[i][j] = __builtin_amdgcn_mfma_f32_16x16x32_bf16(a[i], b[j], acc[i][j], 0, 0, 0);
        asm volatile("" ::: "memory");
        __builtin_amdgcn_s_barrier();
    }

    const float alpha = alpha_p[0];
    #pragma unroll
    for (int i = 0; i < FM; ++i) {
        #pragma unroll
        for (int r = 0; r < 4; ++r) {
            int row = row0 + wm * (BM / 2) + i * 16 + (lane >> 4) * 4 + r;
            float s = alpha * gamma[row] * (1.f / 127.f);
            #pragma unroll
            for (int j = 0; j < FN; ++j) {
                int col = col0 + wn * (BN / 2) + j * 16 + (lane & 15);
                float o = acc[i][j][r] * s;
                if (residual) o += residual[(size_t)row * N + col];
                out[(size_t)row * N + col] = o;
            }
        }
    }
}

// ---------------- fused causal conv(k=4)+silu + rmsnorm scales (one block per row) ----------------
__global__ __launch_bounds__(256) void k_conv_norm(const float* __restrict__ xz,
                                                   const float* __restrict__ cw, const float* __restrict__ cb,
                                                   const float* __restrict__ dtu_nw,
                                                   const float* __restrict__ Bp_nw,
                                                   const float* __restrict__ Cp_nw,
                                                   float* __restrict__ xp,
                                                   float* __restrict__ rinv_out, float* __restrict__ g3) {
    const int row = blockIdx.x, tid = threadIdx.x;
    const int l = row & (LSEQ - 1);
    __shared__ float red4[16];
    float vv[5];
    float ss = 0.f;
#pragma unroll
    for (int j = 0; j < 5; ++j) {
        int d = tid + j * 256;
        f32x4 c4 = *(const f32x4*)(cw + (size_t)d * 4);
        const float* base = xz + (size_t)row * DXZ + d;
        float s = cb[d] + base[0] * c4[0];
        if (l >= 1) s += base[-(ptrdiff_t)DXZ] * c4[1];
        if (l >= 2) s += base[-(ptrdiff_t)(2 * DXZ)] * c4[2];
        if (l >= 3) s += base[-(ptrdiff_t)(3 * DXZ)] * c4[3];
        float v = s / (1.f + __builtin_amdgcn_exp2f(-s * LOG2E));
        vv[j] = v;
        ss += v * v;
        xp[(size_t)row * DIN_ + d] = v;
    }
    float sum = block_sum4(ss, red4);
    float rms = 1.f / sqrtf(sum / DIN_ + EPS_);
    float m0 = 0.f, m1 = 0.f, m2 = 0.f;
#pragma unroll
    for (int j = 0; j < 5; ++j) {
        int d = tid + j * 256;
        float t = vv[j] * rms;
        m0 = fmaxf(m0, fabsf(t * dtu_nw[d]));
        m1 = fmaxf(m1, fabsf(t * Bp_nw[d]));
        m2 = fmaxf(m2, fabsf(t * Cp_nw[d]));
    }
    float g0 = block_max4(m0, red4 + 4);
    float g1 = block_max4(m1, red4 + 8);
    float g2 = block_max4(m2, red4 + 12);
    if (tid == 0) {
        rinv_out[row]       = rms;
        g3[row]             = fmaxf(g0, 1e-10f);
        g3[NROWS + row]     = fmaxf(g1, 1e-10f);
        g3[2 * NROWS + row] = fmaxf(g2, 1e-10f);
    }
}

// ---------------- fused quant + 3 skinny MFMA GEMMs, K-split with exact f32 atomics ----------------
__global__ __launch_bounds__(256) void k_skinny_mfma(const float* __restrict__ xp,
                                                     const float* __restrict__ rinv,
                                                     const float* __restrict__ dtu_nw,
                                                     const float* __restrict__ Bp_nw,
                                                     const float* __restrict__ Cp_nw,
                                                     const float* __restrict__ g3,
                                                     const ushort_t* __restrict__ wq_sk,
                                                     float* __restrict__ dtu_acc,
                                                     float* __restrict__ B_acc,
                                                     float* __restrict__ C_acc) {
    const int tid = threadIdx.x;
    const int w = tid >> 6, l = tid & 63;
    const int row0 = blockIdx.x * 64;
    const int kc0 = blockIdx.y * KCH;
    __shared__ float s_xp[64 * 36];
    __shared__ float s_nw[3 * KCH];
    for (int i = tid; i < 3 * KCH; i += 256) {
        int m = i / KCH, j = i - m * KCH;
        const float* nw = (m == 0) ? dtu_nw : (m == 1) ? Bp_nw : Cp_nw;
        s_nw[i] = nw[kc0 + j];
    }
    const int arow = row0 + w * 16 + (l & 15);
    const float ri = rinv[arow];
    const float s0 = 127.f / g3[arow];
    const float s1 = 127.f / g3[NROWS + arow];
    const float s2 = 127.f / g3[2 * NROWS + arow];
    const int kgrp = l >> 4;
    f32x4 acc[5] = {};

    for (int ks = 0; ks < KCH / 32; ++ks) {
        const int kc = kc0 + ks * 32;
        __syncthreads();
        {
            int srow = tid >> 2, scol = (tid & 3) * 8;
            const float* gp = xp + (size_t)(row0 + srow) * DIN_ + kc + scol;
            f32x4 u0 = *(const f32x4*)gp;
            f32x4 u1 = *(const f32x4*)(gp + 4);
            *(f32x4*)(s_xp + srow * 36 + scol)     = u0;
            *(f32x4*)(s_xp + srow * 36 + scol + 4) = u1;
        }
        __syncthreads();
        const float* sp = s_xp + (w * 16 + (l & 15)) * 36 + kgrp * 8;
        f32x4 t0 = *(const f32x4*)sp;
        f32x4 t1 = *(const f32x4*)(sp + 4);
        float t[8] = { t0[0]*ri, t0[1]*ri, t0[2]*ri, t0[3]*ri,
                       t1[0]*ri, t1[1]*ri, t1[2]*ri, t1[3]*ri };
        short8 a0, a1, a2;
        #pragma unroll
        for (int e = 0; e < 8; ++e) {
            int kk = ks * 32 + kgrp * 8 + e;
            float q0 = fminf(fmaxf(rintf(t[e] * s_nw[kk]           * s0), -128.f), 127.f);
            float q1 = fminf(fmaxf(rintf(t[e] * s_nw[KCH + kk]     * s1), -128.f), 127.f);
            float q2 = fminf(fmaxf(rintf(t[e] * s_nw[2 * KCH + kk] * s2), -128.f), 127.f);
            a0[e] = f2bfs(q0); a1[e] = f2bfs(q1); a2[e] = f2bfs(q2);
        }
        const int kbg = kc >> 5;
        short8 b0 = *(const short8*)(wq_sk + ((size_t)(0 * 40 + kbg) * 64 + l) * 8);
        short8 b1 = *(const short8*)(wq_sk + ((size_t)(1 * 40 + kbg) * 64 + l) * 8);
        short8 b2 = *(const short8*)(wq_sk + ((size_t)(2 * 40 + kbg) * 64 + l) * 8);
        short8 b3 = *(const short8*)(wq_sk + ((size_t)(3 * 40 + kbg) * 64 + l) * 8);
        short8 b4 = *(const short8*)(wq_sk + ((size_t)(4 * 40 + kbg) * 64 + l) * 8);
        acc[0] = __builtin_amdgcn_mfma_f32_16x16x32_bf16(a0, b0, acc[0], 0, 0, 0);
        acc[1] = __builtin_amdgcn_mfma_f32_16x16x32_bf16(a0, b1, acc[1], 0, 0, 0);
        acc[2] = __builtin_amdgcn_mfma_f32_16x16x32_bf16(a0, b2, acc[2], 0, 0, 0);
        acc[3] = __builtin_amdgcn_mfma_f32_16x16x32_bf16(a1, b3, acc[3], 0, 0, 0);
        acc[4] = __builtin_amdgcn_mfma_f32_16x16x32_bf16(a2, b4, acc[4], 0, 0, 0);
    }

    const int col = l & 15;
    const int rbase = row0 + w * 16 + (l >> 4) * 4;
    #pragma unroll
    for (int j = 0; j < 4; ++j) {
        int r = rbase + j;
        atomicAdd(&dtu_acc[(size_t)r * DTR_ + col],      acc[0][j]);
        atomicAdd(&dtu_acc[(size_t)r * DTR_ + 16 + col], acc[1][j]);
        if (col < 8) atomicAdd(&dtu_acc[(size_t)r * DTR_ + 32 + col], acc[2][j]);
        atomicAdd(&B_acc[(size_t)r * DST_ + col], acc[3][j]);
        atomicAdd(&C_acc[(size_t)r * DST_ + col], acc[4][j]);
    }
}

// scale B/C raw integer dots in place
__global__ __launch_bounds__(256) void k_scale_bc(float* __restrict__ Bm, float* __restrict__ Cm,
                                                  const float* __restrict__ g3, const float* __restrict__ alphas) {
    int idx = blockIdx.x * 256 + threadIdx.x;
    int r = idx >> 4;
    float a2 = alphas[2], a3 = alphas[3];
    Bm[idx] = ((Bm[idx] * a2) * g3[NROWS + r]) * (1.f / 127.f);
    Cm[idx] = ((Cm[idx] * a3) * g3[2 * NROWS + r]) * (1.f / 127.f);
}

// ---------------- dt = softplus((raw_dot*scale) @ dtd_w.T + b) ----------------
__global__ __launch_bounds__(256) void k_dtd(const float* __restrict__ U,
                                             const float* __restrict__ W,
                                             const float* __restrict__ bias,
                                             const float* __restrict__ g3,
                                             const float* __restrict__ alphas,
                                             float* __restrict__ dt) {
    const int c0 = blockIdx.x * 128;
    const int r0 = blockIdx.y * 32;
    const int tid = threadIdx.x;
    const int col = tid & 127, rh = tid >> 7;
    __shared__ float s_w[128 * 41];
    __shared__ float s_u[32 * 40];
    for (int i = tid; i < 128 * 40; i += 256) {
        int cc = i / 40, t = i - cc * 40;
        s_w[cc * 41 + t] = W[(size_t)c0 * 40 + i];
    }
    const float alpha = alphas[1];
    for (int i = tid; i < 32 * 40; i += 256) {
        int rr = i / 40;
        s_u[i] = ((U[(size_t)r0 * 40 + i] * alpha) * g3[r0 + rr]) * (1.f / 127.f);
    }
    __syncthreads();
    float w[40];
#pragma unroll
    for (int t = 0; t < 40; t++) w[t] = s_w[col * 41 + t];
    const float b = bias[c0 + col];
    for (int r = 0; r < 16; ++r) {
        const int row = rh * 16 + r;
        const float* ur = s_u + row * 40;
        float a0 = b, a1 = 0.f, a2 = 0.f, a3 = 0.f;
#pragma unroll
        for (int t = 0; t < 40; t += 4) {
            f32x4 uv = *(const f32x4*)(ur + t);
            a0 = fmaf(uv[0], w[t],     a0);
            a1 = fmaf(uv[1], w[t + 1], a1);
            a2 = fmaf(uv[2], w[t + 2], a2);
            a3 = fmaf(uv[3], w[t + 3], a3);
        }
        float s = (a0 + a1) + (a2 + a3);
        float e = __builtin_amdgcn_exp2f(-fabsf(s) * LOG2E);
        float sp = fmaxf(s, 0.f) + __builtin_amdgcn_logf(1.f + e) * RLOG2E;
        dt[(size_t)(r0 + row) * DIN_ + c0 + col] = sp;
    }
}

// ======== chunked selective scan: 4 lanes x 4 states per channel, NCH=64 ========
// Phase A: local scan; emit final local h + sdt = sum(dt) over chunk (P = exp2(A2*sdt)).
__global__ __launch_bounds__(256) void k_scan_a(const float* __restrict__ dt, const float* __restrict__ xp,
                                                const float* __restrict__ Bm, const float* __restrict__ A_log,
                                                float* __restrict__ hloc, float* __restrict__ sdt_out) {
    const int tid = threadIdx.x;
    const int q = tid & 3, dloc = tid >> 2;
    const int d0 = blockIdx.x * 64, c = blockIdx.y, b = blockIdx.z;
    const int d = d0 + dloc;
    const int l0 = c * CL;
    __shared__ float s_B[CL * 16];
    if (tid < CL * 4) *(f32x4*)(s_B + tid * 4) = *(const f32x4*)(Bm + (size_t)(b * LSEQ + l0) * DST_ + tid * 4);
    f32x4 Av = *(const f32x4*)(A_log + (size_t)d * DST_ + q * 4);
    float A2[4];
#pragma unroll
    for (int j = 0; j < 4; ++j) A2[j] = -expf(Av[j]) * LOG2E;
    __syncthreads();
    const float* dtp = dt + (size_t)(b * LSEQ + l0) * DIN_ + d;
    const float* xpp = xp + (size_t)(b * LSEQ + l0) * DIN_ + d;
    float h[4] = {};
    float sdt = 0.f;
    float dtv = *dtp, xv = *xpp;
    for (int l = 0; l < CL; ++l) {
        float ndt = 0.f, nx = 0.f;
        if (l + 1 < CL) { ndt = dtp[(size_t)(l + 1) * DIN_]; nx = xpp[(size_t)(l + 1) * DIN_]; }
        f32x4 Bv = *(const f32x4*)(s_B + l * 16 + q * 4);
        float dtx = dtv * xv;
        sdt += dtv;
#pragma unroll
        for (int j = 0; j < 4; ++j) {
            float dA = __builtin_amdgcn_exp2f(A2[j] * dtv);
            h[j] = fmaf(dA, h[j], Bv[j] * dtx);
        }
        dtv = ndt; xv = nx;
    }
    size_t base = (size_t)(b * NCH + c) * 20480 + (size_t)d * 16 + q * 4;
    *(f32x4*)(hloc + base) = (f32x4){h[0], h[1], h[2], h[3]};
    if (q == 0) sdt_out[(size_t)(b * NCH + c) * DIN_ + d] = sdt;
}

// Phase B: serial combine; P reconstructed from sdt. Hinit written in place over hloc.
__global__ __launch_bounds__(256) void k_scan_b(float* __restrict__ hloc, const float* __restrict__ sdt,
                                                const float* __restrict__ A_log) {
    int i = blockIdx.x * 256 + threadIdx.x;        // 0 .. 2*20480-1
    int b = i / 20480, dn = i % 20480;
    int d = dn >> 4;
    float A2 = -expf(A_log[dn]) * LOG2E;
    size_t base = (size_t)b * NCH * 20480 + dn;
    size_t sbase = (size_t)b * NCH * DIN_ + d;
    float H = 0.f;
    for (int c = 0; c < NCH; ++c) {
        size_t off = base + (size_t)c * 20480;
        float hl = hloc[off];
        float P = __builtin_amdgcn_exp2f(A2 * sdt[sbase + (size_t)c * DIN_]);
        hloc[off] = H;
        H = fmaf(P, H, hl);
    }
}

// Phase C: per-chunk scan from Hinit + C-dot + epilogue.
__global__ __launch_bounds__(256) void k_scan_c(const float* __restrict__ dt, const float* __restrict__ xp,
                                                const float* __restrict__ Bm, const float* __restrict__ Cm,
                                                const float* __restrict__ xz, const float* __restrict__ A_log,
                                                const float* __restrict__ Dvec, const float* __restrict__ Hinit,
                                                float* __restrict__ y) {
    const int tid = threadIdx.x;
    const int q = tid & 3, dloc = tid >> 2;
    const int d0 = blockIdx.x * 64, c = blockIdx.y, b = blockIdx.z;
    const int d = d0 + dloc;
    const int l0 = c * CL;
    __shared__ float s_B[CL * 16], s_C[CL * 16];
    if (tid < CL * 4)
        *(f32x4*)(s_B + tid * 4) = *(const f32x4*)(Bm + (size_t)(b * LSEQ + l0) * DST_ + tid * 4);
    else if (tid < CL * 8)
        *(f32x4*)(s_C + (tid - CL * 4) * 4) = *(const f32x4*)(Cm + (size_t)(b * LSEQ + l0) * DST_ + (tid - CL * 4) * 4);
    f32x4 Av = *(const f32x4*)(A_log + (size_t)d * DST_ + q * 4);
    float A2[4];
#pragma unroll
    for (int j = 0; j < 4; ++j) A2[j] = -expf(Av[j]) * LOG2E;
    const float Dd = Dvec[d];
    __syncthreads();
    const float* dtp = dt + (size_t)(b * LSEQ + l0) * DIN_ + d;
    const float* xpp = xp + (size_t)(b * LSEQ + l0) * DIN_ + d;
    const float* zp  = xz + (size_t)(b * LSEQ + l0) * DXZ + DIN_ + d;
    float* yp = y + (size_t)(b * LSEQ + l0) * DIN_ + d;
    size_t base = (size_t)(b * NCH + c) * 20480 + (size_t)d * 16 + q * 4;
    f32x4 hv = *(const f32x4*)(Hinit + base);
    float h[4] = {hv[0], hv[1], hv[2], hv[3]};
    float dtv = *dtp, xv = *xpp, zv = *zp;
    for (int l = 0; l < CL; ++l) {
        float ndt = 0.f, nx = 0.f, nz = 0.f;
        if (l + 1 < CL) {
            ndt = dtp[(size_t)(l + 1) * DIN_];
            nx  = xpp[(size_t)(l + 1) * DIN_];
            nz  = zp[(size_t)(l + 1) * DXZ];
        }
        f32x4 Bv = *(const f32x4*)(s_B + l * 16 + q * 4);
        f32x4 Cv = *(const f32x4*)(s_C + l * 16 + q * 4);
        float dtx = dtv * xv;
        float yv = 0.f;
#pragma unroll
        for (int j = 0; j < 4; ++j) {
            float dA = __builtin_amdgcn_exp2f(A2[j] * dtv);
            h[j] = fmaf(dA, h[j], Bv[j] * dtx);
            yv = fmaf(h[j], Cv[j], yv);
        }
        yv += __shfl_xor(yv, 1);
        yv += __shfl_xor(yv, 2);
        if (q == 0) {
            float sig = 1.f / (1.f + __builtin_amdgcn_exp2f(-zv * LOG2E));
            yp[(size_t)l * DIN_] = (yv + xv * Dd) * (zv * sig);
        }
        dtv = ndt; xv = nx; zv = nz;
    }
}

// ---------------- rmsnorm(y,out_nw) + quant (bf16 out) ----------------
__global__ __launch_bounds__(256) void k_norm_y(const float* __restrict__ y,
                                                const float* __restrict__ out_nw,
                                                __hip_bfloat16* __restrict__ yq, float* __restrict__ gy) {
    const int r = blockIdx.x, tid = threadIdx.x;
    const float* yr = y + (size_t)r * DIN_;
    __shared__ float red4[8];
    float v[5];
    float ss = 0.f;
#pragma unroll
    for (int j = 0; j < 5; j++) { v[j] = yr[tid + j * 256]; ss += v[j] * v[j]; }
    float sum = block_sum4(ss, red4);
    float rms = 1.f / sqrtf(sum / DIN_ + EPS_);
    float mx = 0.f;
#pragma unroll
    for (int j = 0; j < 5; j++) {
        int i = tid + j * 256;
        v[j] = v[j] * rms * out_nw[i];
        mx = fmaxf(mx, fabsf(v[j]));
    }
    float g = fmaxf(block_max4(mx, red4 + 4), 1e-10f);
    if (tid == 0) gy[r] = g;
    float s = 127.f / g;
#pragma unroll
    for (int j = 0; j < 5; j++) {
        int i = tid + j * 256;
        yq[(size_t)r * DIN_ + i] = __float2bfloat16(fminf(fmaxf(rintf(v[j] * s), -128.f), 127.f));
    }
}

extern "C" void kernel_launch(void* const* d_in, const int* in_sizes, int n_in,
                              void* d_out, int out_size, void* d_ws, size_t ws_size,
                              hipStream_t stream) {
    (void)in_sizes; (void)n_in; (void)out_size;
    const float* x      = (const float*)d_in[0];
    const float* norm_w = (const float*)d_in[1];
    const float* in_w   = (const float*)d_in[2];
    const float* in_nw  = (const float*)d_in[3];
    const float* conv_w = (const float*)d_in[4];
    const float* conv_b = (const float*)d_in[5];
    const float* dtu_w  = (const float*)d_in[6];
    const float* dtu_nw = (const float*)d_in[7];
    const float* dtd_w  = (const float*)d_in[8];
    const float* dtd_b  = (const float*)d_in[9];
    const float* Bp_w   = (const float*)d_in[10];
    const float* Bp_nw  = (const float*)d_in[11];
    const float* Cp_w   = (const float*)d_in[12];
    const float* Cp_nw  = (const float*)d_in[13];
    const float* A_log  = (const float*)d_in[14];
    const float* Dv     = (const float*)d_in[15];
    const float* out_w  = (const float*)d_in[16];
    const float* out_nw = (const float*)d_in[17];

    float* ws = (float*)d_ws;
    float* alphas   = ws;                      // 8
    float* partials = ws + 8;                  // 5*256
    float* xq1      = ws + 8 + 5 * 256;        // bf16 activations; reused as hloc (2*64*20480 = 2.62M floats)
    float* gamma1   = xq1 + (size_t)NROWS * H_;
    float* xz       = gamma1 + NROWS;
    float* xp       = xz + (size_t)NROWS * DXZ;
    float* xpn     = xp + (size_t)NROWS * DIN_;        // y (scan output)
    float* g3       = xpn + (size_t)NROWS * DIN_;
    float* dtu_out  = g3 + 3 * NROWS;                  // raw integer dots (memset 0 each call)
    float* Bmat     = dtu_out + (size_t)NROWS * DTR_;
    float* Cmat     = Bmat + (size_t)NROWS * DST_;
    float* dtb      = Cmat + (size_t)NROWS * DST_;     // later reused as yq (bf16)
    float* gy       = dtb + (size_t)NROWS * DIN_;
    float* wq_in    = gy + NROWS;                      // bf16
    float* wq_dtu   = wq_in + (size_t)DXZ * H_;        // (unused, kept for layout)
    float* wq_Bp    = wq_dtu + (size_t)DTR_ * DIN_;
    float* wq_Cp    = wq_Bp + (size_t)DST_ * DIN_;
    float* wq_out   = wq_Cp + (size_t)DST_ * DIN_;     // bf16
    float* rinv     = wq_out + (size_t)H_ * DIN_;      // NROWS
    float* wq_sk    = rinv + NROWS;                    // 51200 float slots
    float* sdt      = wq_sk + 51200;                   // 2*NCH*DIN_ = 163840 floats
    size_t need = (size_t)((sdt + 2 * NCH * DIN_) - ws) * sizeof(float);
    if (ws_size < need) return;

    float* hloc = xq1;   // 2*NCH*20480 = 2,621,440 floats == NROWS*H_ exactly

    hipMemsetAsync(dtu_out, 0, (size_t)NROWS * 72 * sizeof(float), stream);

    const int n0 = DXZ * H_, n1 = DTR_ * DIN_, n2 = DST_ * DIN_, n3 = DST_ * DIN_, n4 = H_ * DIN_;
    hipLaunchKernelGGL(absmean_partial5, dim3(256, 5), dim3(256), 0, stream,
                       in_w, dtu_w, Bp_w, Cp_w, out_w, n0, n1, n2, n3, n4, partials);
    hipLaunchKernelGGL(absmean_final5, dim3(5), dim3(256), 0, stream, partials, n0, n1, n2, n3, n4, alphas);
    hipLaunchKernelGGL(quant_w2, dim3((n0 + 255) / 256, 2), dim3(256), 0, stream,
                       in_w, out_w, n0, n4, alphas, (__hip_bfloat16*)wq_in, (__hip_bfloat16*)wq_out);
    hipLaunchKernelGGL(build_wq_sk, dim3(50), dim3(256), 0, stream,
                       dtu_w, Bp_w, Cp_w, alphas, (ushort_t*)wq_sk);

    hipLaunchKernelGGL(k_norm_quant_in, dim3(NROWS), dim3(256), 0, stream,
                       x, norm_w, in_nw, (__hip_bfloat16*)xq1, gamma1);
    hipLaunchKernelGGL((k_gemm_mfma<128, 128>), dim3(DXZ / 128, NROWS / 128), dim3(256), 0, stream,
                       (const ushort_t*)xq1, (const ushort_t*)wq_in, alphas + 0, gamma1,
                       (const float*)nullptr, xz, NROWS, DXZ, H_);
    hipLaunchKernelGGL(k_conv_norm, dim3(NROWS), dim3(256), 0, stream,
                       xz, conv_w, conv_b, dtu_nw, Bp_nw, Cp_nw, xp, rinv, g3);
    hipLaunchKernelGGL(k_skinny_mfma, dim3(NROWS / 64, KSPLIT), dim3(256), 0, stream,
                       xp, rinv, dtu_nw, Bp_nw, Cp_nw, g3, (const ushort_t*)wq_sk,
                       dtu_out, Bmat, Cmat);
    hipLaunchKernelGGL(k_scale_bc, dim3((NROWS * DST_) / 256), dim3(256), 0, stream, Bmat, Cmat, g3, alphas);
    hipLaunchKernelGGL(k_dtd, dim3(DIN_ / 128, NROWS / 32), dim3(256), 0, stream,
                       dtu_out, dtd_w, dtd_b, g3, alphas, dtb);

    hipLaunchKernelGGL(k_scan_a, dim3(DIN_ / 64, NCH, 2), dim3(256), 0, stream,
                       dtb, xp, Bmat, A_log, hloc, sdt);
    hipLaunchKernelGGL(k_scan_b, dim3((2 * 20480) / 256), dim3(256), 0, stream, hloc, sdt, A_log);
    hipLaunchKernelGGL(k_scan_c, dim3(DIN_ / 64, NCH, 2), dim3(256), 0, stream,
                       dtb, xp, Bmat, Cmat, xz, A_log, Dv, hloc, xpn /*y*/);

    hipLaunchKernelGGL(k_norm_y, dim3(NROWS), dim3(256), 0, stream, xpn /*y*/, out_nw,
                       (__hip_bfloat16*)dtb /*yq*/, gy);
    hipLaunchKernelGGL((k_gemm_mfma<64, 64>), dim3(H_ / 64, NROWS / 64), dim3(256), 0, stream,
                       (const ushort_t*)dtb /*yq*/, (const ushort_t*)wq_out, alphas + 4, gy,
                       x /*residual*/, (float*)d_out, NROWS, H_, DIN_);
}

// Round 10
// 227.499 us; speedup vs baseline: 7.4691x; 1.0049x over previous
//
#include <hip/hip_runtime.h>
#include <hip/hip_bf16.h>
#include <cmath>

#define NROWS 4096   // B*L
#define H_    640
#define DIN_  1280
#define DXZ   2560
#define DTR_  40
#define DST_  16
#define LSEQ  2048
#define EPS_  1e-6f
#define NCH   64     // scan chunks
#define CL    32     // chunk length (NCH*CL == LSEQ)
#define NDG   20     // DIN_/64 channel groups
#define KSPLIT 8
#define KCH (DIN_ / KSPLIT)   // 160
#define LOG2E 1.4426950408889634f
#define RLOG2E 0.6931471805599453f

typedef __attribute__((ext_vector_type(8))) short short8;
typedef __attribute__((ext_vector_type(4))) float f32x4;
typedef unsigned short ushort_t;

__device__ __forceinline__ float bf2f(short u) {
    return __uint_as_float((unsigned)(unsigned short)u << 16);
}
// exact for integer-valued floats |x| <= 256 (low mantissa bits are zero)
__device__ __forceinline__ short f2bfs(float x) { return (short)(__float_as_uint(x) >> 16); }

// async global->LDS, 16B per lane
#define GLD16(gp, lp) __builtin_amdgcn_global_load_lds( \
    (const __attribute__((address_space(1))) unsigned int*)(unsigned long long)(gp), \
    (__attribute__((address_space(3))) unsigned int*)(unsigned int)(unsigned long long)(lp), 16, 0, 0)

// ---------------- fast reductions ----------------
__device__ __forceinline__ float wave_sum64(float v) {
    v += __shfl_xor(v, 1);  v += __shfl_xor(v, 2);  v += __shfl_xor(v, 4);
    v += __shfl_xor(v, 8);  v += __shfl_xor(v, 16); v += __shfl_xor(v, 32);
    return v;
}
__device__ __forceinline__ float wave_max64(float v) {
    v = fmaxf(v, __shfl_xor(v, 1));  v = fmaxf(v, __shfl_xor(v, 2));
    v = fmaxf(v, __shfl_xor(v, 4));  v = fmaxf(v, __shfl_xor(v, 8));
    v = fmaxf(v, __shfl_xor(v, 16)); v = fmaxf(v, __shfl_xor(v, 32));
    return v;
}
__device__ __forceinline__ float block_sum4(float v, float* red4) {
    v = wave_sum64(v);
    if ((threadIdx.x & 63) == 0) red4[threadIdx.x >> 6] = v;
    __syncthreads();
    return (red4[0] + red4[1]) + (red4[2] + red4[3]);
}
__device__ __forceinline__ float block_max4(float v, float* red4) {
    v = wave_max64(v);
    if ((threadIdx.x & 63) == 0) red4[threadIdx.x >> 6] = v;
    __syncthreads();
    return fmaxf(fmaxf(red4[0], red4[1]), fmaxf(red4[2], red4[3]));
}
__device__ __forceinline__ float block_reduce_sum256(float v, float* red) {
    int tid = threadIdx.x;
    red[tid] = v; __syncthreads();
    for (int o = 128; o; o >>= 1) { if (tid < o) red[tid] += red[tid + o]; __syncthreads(); }
    float r = red[0]; __syncthreads();
    return r;
}

// ---------------- fused: rmsnorm+quant of x (blocks 0..4095) + absmean partials (blocks 4096..5375) ----
__global__ __launch_bounds__(256) void k_pre(const float* __restrict__ x,
                                             const float* __restrict__ norm_w,
                                             const float* __restrict__ in_nw,
                                             const float* __restrict__ w0, const float* __restrict__ w1,
                                             const float* __restrict__ w2, const float* __restrict__ w3,
                                             const float* __restrict__ w4,
                                             int n0, int n1, int n2, int n3, int n4,
                                             __hip_bfloat16* __restrict__ xq, float* __restrict__ gamma,
                                             float* __restrict__ partials) {
    __shared__ float red[256];
    const int tid = threadIdx.x;
    if (blockIdx.x < NROWS) {
        const int r = blockIdx.x;
        const float* xr = x + (size_t)r * H_;
        const bool has2 = (tid < H_ - 512);
        float v0 = xr[tid], v1 = xr[tid + 256], v2 = has2 ? xr[tid + 512] : 0.f;
        float sum = block_sum4(v0 * v0 + v1 * v1 + v2 * v2, red);
        float r1 = 1.f / sqrtf(sum / H_ + EPS_);
        v0 *= r1 * norm_w[tid];
        v1 *= r1 * norm_w[tid + 256];
        if (has2) v2 *= r1 * norm_w[tid + 512];
        sum = block_sum4(v0 * v0 + v1 * v1 + v2 * v2, red + 4);
        float r2 = 1.f / sqrtf(sum / H_ + EPS_);
        v0 *= r2 * in_nw[tid];
        v1 *= r2 * in_nw[tid + 256];
        if (has2) v2 *= r2 * in_nw[tid + 512];
        float mx = fmaxf(fmaxf(fabsf(v0), fabsf(v1)), fabsf(v2));
        float g = fmaxf(block_max4(mx, red + 8), 1e-10f);
        if (tid == 0) gamma[r] = g;
        float s = 127.f / g;
        __hip_bfloat16* o = xq + (size_t)r * H_;
        o[tid]       = __float2bfloat16(fminf(fmaxf(rintf(v0 * s), -128.f), 127.f));
        o[tid + 256] = __float2bfloat16(fminf(fmaxf(rintf(v1 * s), -128.f), 127.f));
        if (has2) o[tid + 512] = __float2bfloat16(fminf(fmaxf(rintf(v2 * s), -128.f), 127.f));
    } else {
        const int flat = blockIdx.x - NROWS;     // 0..1279
        const int wi = flat >> 8, xb = flat & 255;
        const float* w = (wi == 0) ? w0 : (wi == 1) ? w1 : (wi == 2) ? w2 : (wi == 3) ? w3 : w4;
        const int n = (wi == 0) ? n0 : (wi == 1) ? n1 : (wi == 2) ? n2 : (wi == 3) ? n3 : n4;
        float s = 0.f;
        for (int i = xb * 256 + tid; i < n; i += 65536) s += fabsf(w[i]);
        float t = block_reduce_sum256(s, red);
        if (tid == 0) partials[wi * 256 + xb] = t;
    }
}

__global__ __launch_bounds__(256) void absmean_final5(const float* __restrict__ partials,
                                                      int n0, int n1, int n2, int n3, int n4,
                                                      float* __restrict__ alphas) {
    const int wi = blockIdx.x;
    const int n = (wi == 0) ? n0 : (wi == 1) ? n1 : (wi == 2) ? n2 : (wi == 3) ? n3 : n4;
    __shared__ double red[256];
    double s = (double)partials[wi * 256 + threadIdx.x];
    red[threadIdx.x] = s; __syncthreads();
    for (int o = 128; o; o >>= 1) { if (threadIdx.x < o) red[threadIdx.x] += red[threadIdx.x + o]; __syncthreads(); }
    if (threadIdx.x == 0) alphas[wi] = fmaxf((float)(red[0] / (double)n), 1e-10f);
}

// ---------------- fused: ternary quant of big weights + skinny MFMA-layout build ----------------
// blocks [0,6400): wq_in; [6400,9600): wq_out; [9600,9650): wq_sk
__global__ __launch_bounds__(256) void k_quant_build(const float* __restrict__ in_w,
                                                     const float* __restrict__ out_w,
                                                     const float* __restrict__ dtu_w,
                                                     const float* __restrict__ Bp_w,
                                                     const float* __restrict__ Cp_w,
                                                     const float* __restrict__ alphas,
                                                     __hip_bfloat16* __restrict__ q_in,
                                                     __hip_bfloat16* __restrict__ q_out,
                                                     ushort_t* __restrict__ wq_sk) {
    const int tid = threadIdx.x;
    if (blockIdx.x < 6400) {
        int i = blockIdx.x * 256 + tid;          // exactly covers DXZ*H_
        float a = alphas[0];
        ((ushort_t*)q_in)[i] = (ushort_t)f2bfs(fminf(fmaxf(rintf(in_w[i] / a), -1.f), 1.f));
    } else if (blockIdx.x < 9600) {
        int i = (blockIdx.x - 6400) * 256 + tid; // exactly covers H_*DIN_
        float a = alphas[4];
        ((ushort_t*)q_out)[i] = (ushort_t)f2bfs(fminf(fmaxf(rintf(out_w[i] / a), -1.f), 1.f));
    } else {
        int idx = (blockIdx.x - 9600) * 256 + tid;  // exactly 5*40*64 = 12800
        int t = idx / 2560, rem = idx % 2560, kb = rem / 64, l = rem % 64;
        int nloc = l & 15, kg = l >> 4;
        float alpha; const float* src; int row; bool valid = true;
        if (t < 3)      { alpha = alphas[1]; src = dtu_w; row = t * 16 + nloc; valid = (row < 40); }
        else if (t == 3){ alpha = alphas[2]; src = Bp_w;  row = nloc; }
        else            { alpha = alphas[3]; src = Cp_w;  row = nloc; }
        int k0 = kb * 32 + kg * 8;
        short8 outv;
#pragma unroll
        for (int e = 0; e < 8; ++e) {
            float q = valid ? fminf(fmaxf(rintf(src[(size_t)row * DIN_ + k0 + e] / alpha), -1.f), 1.f) : 0.f;
            outv[e] = f2bfs(q);
        }
        *(short8*)(wq_sk + (size_t)idx * 8) = outv;
    }
}

// ---------------- MFMA bf16 quantized GEMM: double-buffered, counted-vmcnt pipeline ----------------
template<int BM, int BN>
__global__ __launch_bounds__(256) void k_gemm_mfma(const ushort_t* __restrict__ Aq,
                                                   const ushort_t* __restrict__ Wq,
                                                   const float* __restrict__ alpha_p,
                                                   const float* __restrict__ gamma,
                                                   const float* __restrict__ residual,
                                                   float* __restrict__ out,
                                                   int M, int N, int K) {
    constexpr int FM = BM / 32, FN = BN / 32;
    constexpr int NL = (BM + BN) / 64;
    __shared__ ushort_t As[2][BM * 32];
    __shared__ ushort_t Bs[2][BN * 32];
    const int tid = threadIdx.x;
    const int w = tid >> 6, lane = tid & 63;
    const int wm = w >> 1, wn = w & 1;
    const int nwg = gridDim.x * gridDim.y;
    const int hw = blockIdx.y * gridDim.x + blockIdx.x;
    const int work = (nwg % 8 == 0) ? ((hw & 7) * (nwg >> 3) + (hw >> 3)) : hw;
    const int row0 = (work / gridDim.x) * BM;
    const int col0 = (work % gridDim.x) * BN;
    f32x4 acc[FM][FN] = {};

    auto stage = [&](int buf, int k0) {
        #pragma unroll
        for (int q = 0; q < BM / 64; ++q) {
            int c = w * BM + q * 64 + lane;
            int row = c >> 2;
            int uslot = (c & 3) ^ (row & 3);
            GLD16(Aq + (size_t)(row0 + row) * K + k0 + uslot * 8,
                  (char*)As[buf] + (w * BM + q * 64) * 16);
        }
        #pragma unroll
        for (int q = 0; q < BN / 64; ++q) {
            int c = w * BN + q * 64 + lane;
            int row = c >> 2;
            int uslot = (c & 3) ^ (row & 3);
            GLD16(Wq + (size_t)(col0 + row) * K + k0 + uslot * 8,
                  (char*)Bs[buf] + (w * BN + q * 64) * 16);
        }
    };

    stage(0, 0);
    const int NT = K >> 5;
    for (int t = 0; t < NT; ++t) {
        const int cur = t & 1;
        if (t + 1 < NT) {
            stage(cur ^ 1, (t + 1) << 5);
            if constexpr (NL == 2)      asm volatile("s_waitcnt vmcnt(2)" ::: "memory");
            else if constexpr (NL == 3) asm volatile("s_waitcnt vmcnt(3)" ::: "memory");
            else                        asm volatile("s_waitcnt vmcnt(4)" ::: "memory");
        } else {
            asm volatile("s_waitcnt vmcnt(0)" ::: "memory");
        }
        __builtin_amdgcn_s_barrier();

        short8 a[FM], b[FN];
        #pragma unroll
        for (int i = 0; i < FM; ++i) {
            int row = wm * (BM / 2) + i * 16 + (lane & 15);
            int byt = row * 64 + (((lane >> 4) ^ (row & 3)) << 4);
            a[i] = *(const short8*)((const char*)As[cur] + byt);
        }
        #pragma unroll
        for (int j = 0; j < FN; ++j) {
            int row = wn * (BN / 2) + j * 16 + (lane & 15);
            int byt = row * 64 + (((lane >> 4) ^ (row & 3)) << 4);
            b[j] = *(const short8*)((const char*)Bs[cur] + byt);
        }
        #pragma unroll
        for (int i = 0; i < FM; ++i)
            #pragma unroll
            for (int j = 0; j < FN; ++j)
                acc[i][j] = __builtin_amdgcn_mfma_f32_16x16x32_bf16(a[i], b[j], acc[i][j], 0, 0, 0);
        asm volatile("" ::: "memory");
        __builtin_amdgcn_s_barrier();
    }

    const float alpha = alpha_p[0];
    #pragma unroll
    for (int i = 0; i < FM; ++i) {
        #pragma unroll
        for (int r = 0; r < 4; ++r) {
            int row = row0 + wm * (BM / 2) + i * 16 + (lane >> 4) * 4 + r;
            float s = alpha * gamma[row] * (1.f / 127.f);
            #pragma unroll
            for (int j = 0; j < FN; ++j) {
                int col = col0 + wn * (BN / 2) + j * 16 + (lane & 15);
                float o = acc[i][j][r] * s;
                if (residual) o += residual[(size_t)row * N + col];
                out[(size_t)row * N + col] = o;
            }
        }
    }
}

// ---------------- fused causal conv(k=4)+silu + rmsnorm scales ----------------
__global__ __launch_bounds__(256) void k_conv_norm(const float* __restrict__ xz,
                                                   const float* __restrict__ cw, const float* __restrict__ cb,
                                                   const float* __restrict__ dtu_nw,
                                                   const float* __restrict__ Bp_nw,
                                                   const float* __restrict__ Cp_nw,
                                                   float* __restrict__ xp,
                                                   float* __restrict__ rinv_out, float* __restrict__ g3) {
    const int row = blockIdx.x, tid = threadIdx.x;
    const int l = row & (LSEQ - 1);
    __shared__ float red4[16];
    float vv[5];
    float ss = 0.f;
#pragma unroll
    for (int j = 0; j < 5; ++j) {
        int d = tid + j * 256;
        f32x4 c4 = *(const f32x4*)(cw + (size_t)d * 4);
        const float* base = xz + (size_t)row * DXZ + d;
        float s = cb[d] + base[0] * c4[0];
        if (l >= 1) s += base[-(ptrdiff_t)DXZ] * c4[1];
        if (l >= 2) s += base[-(ptrdiff_t)(2 * DXZ)] * c4[2];
        if (l >= 3) s += base[-(ptrdiff_t)(3 * DXZ)] * c4[3];
        float v = s / (1.f + __builtin_amdgcn_exp2f(-s * LOG2E));
        vv[j] = v;
        ss += v * v;
        xp[(size_t)row * DIN_ + d] = v;
    }
    float sum = block_sum4(ss, red4);
    float rms = 1.f / sqrtf(sum / DIN_ + EPS_);
    float m0 = 0.f, m1 = 0.f, m2 = 0.f;
#pragma unroll
    for (int j = 0; j < 5; ++j) {
        int d = tid + j * 256;
        float t = vv[j] * rms;
        m0 = fmaxf(m0, fabsf(t * dtu_nw[d]));
        m1 = fmaxf(m1, fabsf(t * Bp_nw[d]));
        m2 = fmaxf(m2, fabsf(t * Cp_nw[d]));
    }
    float g0 = block_max4(m0, red4 + 4);
    float g1 = block_max4(m1, red4 + 8);
    float g2 = block_max4(m2, red4 + 12);
    if (tid == 0) {
        rinv_out[row]       = rms;
        g3[row]             = fmaxf(g0, 1e-10f);
        g3[NROWS + row]     = fmaxf(g1, 1e-10f);
        g3[2 * NROWS + row] = fmaxf(g2, 1e-10f);
    }
}

// ---------------- fused quant + 3 skinny MFMA GEMMs, K-split with exact f32 atomics ----------------
__global__ __launch_bounds__(256) void k_skinny_mfma(const float* __restrict__ xp,
                                                     const float* __restrict__ rinv,
                                                     const float* __restrict__ dtu_nw,
                                                     const float* __restrict__ Bp_nw,
                                                     const float* __restrict__ Cp_nw,
                                                     const float* __restrict__ g3,
                                                     const ushort_t* __restrict__ wq_sk,
                                                     float* __restrict__ dtu_acc,
                                                     float* __restrict__ B_acc,
                                                     float* __restrict__ C_acc) {
    const int tid = threadIdx.x;
    const int w = tid >> 6, l = tid & 63;
    const int row0 = blockIdx.x * 64;
    const int kc0 = blockIdx.y * KCH;
    __shared__ float s_xp[64 * 36];
    __shared__ float s_nw[3 * KCH];
    for (int i = tid; i < 3 * KCH; i += 256) {
        int m = i / KCH, j = i - m * KCH;
        const float* nw = (m == 0) ? dtu_nw : (m == 1) ? Bp_nw : Cp_nw;
        s_nw[i] = nw[kc0 + j];
    }
    const int arow = row0 + w * 16 + (l & 15);
    const float ri = rinv[arow];
    const float s0 = 127.f / g3[arow];
    const float s1 = 127.f / g3[NROWS + arow];
    const float s2 = 127.f / g3[2 * NROWS + arow];
    const int kgrp = l >> 4;
    f32x4 acc[5] = {};

    for (int ks = 0; ks < KCH / 32; ++ks) {
        const int kc = kc0 + ks * 32;
        __syncthreads();
        {
            int srow = tid >> 2, scol = (tid & 3) * 8;
            const float* gp = xp + (size_t)(row0 + srow) * DIN_ + kc + scol;
            f32x4 u0 = *(const f32x4*)gp;
            f32x4 u1 = *(const f32x4*)(gp + 4);
            *(f32x4*)(s_xp + srow * 36 + scol)     = u0;
            *(f32x4*)(s_xp + srow * 36 + scol + 4) = u1;
        }
        __syncthreads();
        const float* sp = s_xp + (w * 16 + (l & 15)) * 36 + kgrp * 8;
        f32x4 t0 = *(const f32x4*)sp;
        f32x4 t1 = *(const f32x4*)(sp + 4);
        float t[8] = { t0[0]*ri, t0[1]*ri, t0[2]*ri, t0[3]*ri,
                       t1[0]*ri, t1[1]*ri, t1[2]*ri, t1[3]*ri };
        short8 a0, a1, a2;
        #pragma unroll
        for (int e = 0; e < 8; ++e) {
            int kk = ks * 32 + kgrp * 8 + e;
            float q0 = fminf(fmaxf(rintf(t[e] * s_nw[kk]           * s0), -128.f), 127.f);
            float q1 = fminf(fmaxf(rintf(t[e] * s_nw[KCH + kk]     * s1), -128.f), 127.f);
            float q2 = fminf(fmaxf(rintf(t[e] * s_nw[2 * KCH + kk] * s2), -128.f), 127.f);
            a0[e] = f2bfs(q0); a1[e] = f2bfs(q1); a2[e] = f2bfs(q2);
        }
        const int kbg = kc >> 5;
        short8 b0 = *(const short8*)(wq_sk + ((size_t)(0 * 40 + kbg) * 64 + l) * 8);
        short8 b1 = *(const short8*)(wq_sk + ((size_t)(1 * 40 + kbg) * 64 + l) * 8);
        short8 b2 = *(const short8*)(wq_sk + ((size_t)(2 * 40 + kbg) * 64 + l) * 8);
        short8 b3 = *(const short8*)(wq_sk + ((size_t)(3 * 40 + kbg) * 64 + l) * 8);
        short8 b4 = *(const short8*)(wq_sk + ((size_t)(4 * 40 + kbg) * 64 + l) * 8);
        acc[0] = __builtin_amdgcn_mfma_f32_16x16x32_bf16(a0, b0, acc[0], 0, 0, 0);
        acc[1] = __builtin_amdgcn_mfma_f32_16x16x32_bf16(a0, b1, acc[1], 0, 0, 0);
        acc[2] = __builtin_amdgcn_mfma_f32_16x16x32_bf16(a0, b2, acc[2], 0, 0, 0);
        acc[3] = __builtin_amdgcn_mfma_f32_16x16x32_bf16(a1, b3, acc[3], 0, 0, 0);
        acc[4] = __builtin_amdgcn_mfma_f32_16x16x32_bf16(a2, b4, acc[4], 0, 0, 0);
    }

    const int col = l & 15;
    const int rbase = row0 + w * 16 + (l >> 4) * 4;
    #pragma unroll
    for (int j = 0; j < 4; ++j) {
        int r = rbase + j;
        atomicAdd(&dtu_acc[(size_t)r * DTR_ + col],      acc[0][j]);
        atomicAdd(&dtu_acc[(size_t)r * DTR_ + 16 + col], acc[1][j]);
        if (col < 8) atomicAdd(&dtu_acc[(size_t)r * DTR_ + 32 + col], acc[2][j]);
        atomicAdd(&B_acc[(size_t)r * DST_ + col], acc[3][j]);
        atomicAdd(&C_acc[(size_t)r * DST_ + col], acc[4][j]);
    }
}

// ---------------- dt = softplus((raw_dot*scale) @ dtd_w.T + b), 64 cols x 32 rows ----------------
__global__ __launch_bounds__(256) void k_dtd(const float* __restrict__ U,
                                             const float* __restrict__ W,
                                             const float* __restrict__ bias,
                                             const float* __restrict__ g3,
                                             const float* __restrict__ alphas,
                                             float* __restrict__ dt) {
    const int c0 = blockIdx.x * 64;
    const int r0 = blockIdx.y * 32;
    const int tid = threadIdx.x;
    const int col = tid & 63, rg = tid >> 6;
    __shared__ float s_w[64 * 41];
    __shared__ float s_u[32 * 40];
    for (int i = tid; i < 64 * 40; i += 256) {
        int cc = i / 40, t = i - cc * 40;
        s_w[cc * 41 + t] = W[(size_t)c0 * 40 + i];
    }
    const float alpha = alphas[1];
    for (int i = tid; i < 32 * 40; i += 256) {
        int rr = i / 40;
        s_u[i] = ((U[(size_t)r0 * 40 + i] * alpha) * g3[r0 + rr]) * (1.f / 127.f);
    }
    __syncthreads();
    float w[40];
#pragma unroll
    for (int t = 0; t < 40; t++) w[t] = s_w[col * 41 + t];
    const float b = bias[c0 + col];
    for (int r8 = 0; r8 < 8; ++r8) {
        const int row = rg * 8 + r8;
        const float* ur = s_u + row * 40;
        float a0 = b, a1 = 0.f, a2 = 0.f, a3 = 0.f;
#pragma unroll
        for (int t = 0; t < 40; t += 4) {
            f32x4 uv = *(const f32x4*)(ur + t);
            a0 = fmaf(uv[0], w[t],     a0);
            a1 = fmaf(uv[1], w[t + 1], a1);
            a2 = fmaf(uv[2], w[t + 2], a2);
            a3 = fmaf(uv[3], w[t + 3], a3);
        }
        float s = (a0 + a1) + (a2 + a3);
        float e = __builtin_amdgcn_exp2f(-fabsf(s) * LOG2E);
        float sp = fmaxf(s, 0.f) + __builtin_amdgcn_logf(1.f + e) * RLOG2E;
        dt[(size_t)(r0 + row) * DIN_ + c0 + col] = sp;
    }
}

// ======== chunked selective scan (NCH=64, CL=32) ========
// hloc layout: [b][dg(20)][c(64)][1024], sdt: [b][dg][c][64]
// Phase A: local scan; B scaled inline (replaces k_scale_bc — same op order, bit-identical).
__global__ __launch_bounds__(256) void k_scan_a(const float* __restrict__ dt, const float* __restrict__ xp,
                                                const float* __restrict__ Bm, const float* __restrict__ A_log,
                                                const float* __restrict__ g3, const float* __restrict__ alphas,
                                                float* __restrict__ hloc, float* __restrict__ sdt_out) {
    const int tid = threadIdx.x;
    const int q = tid & 3, dloc = tid >> 2;
    const int dg = blockIdx.x, c = blockIdx.y, b = blockIdx.z;
    const int d = dg * 64 + dloc;
    const int l0 = c * CL;
    __shared__ float s_B[CL * 16];
    if (tid < CL * 4) {
        int rg = b * LSEQ + l0 + (tid >> 2);
        float a2 = alphas[2];
        float gB = g3[NROWS + rg];
        f32x4 Bv = *(const f32x4*)(Bm + (size_t)rg * DST_ + (tid & 3) * 4);
        f32x4 o;
#pragma unroll
        for (int k = 0; k < 4; ++k) o[k] = ((Bv[k] * a2) * gB) * (1.f / 127.f);
        *(f32x4*)(s_B + tid * 4) = o;
    }
    f32x4 Av = *(const f32x4*)(A_log + (size_t)d * DST_ + q * 4);
    float A2[4];
#pragma unroll
    for (int j = 0; j < 4; ++j) A2[j] = -expf(Av[j]) * LOG2E;
    __syncthreads();
    const float* dtp = dt + (size_t)(b * LSEQ + l0) * DIN_ + d;
    const float* xpp = xp + (size_t)(b * LSEQ + l0) * DIN_ + d;
    float h[4] = {};
    float sdt = 0.f;
    float dtv = *dtp, xv = *xpp;
    for (int l = 0; l < CL; ++l) {
        float ndt = 0.f, nx = 0.f;
        if (l + 1 < CL) { ndt = dtp[(size_t)(l + 1) * DIN_]; nx = xpp[(size_t)(l + 1) * DIN_]; }
        f32x4 Bv = *(const f32x4*)(s_B + l * 16 + q * 4);
        float dtx = dtv * xv;
        sdt += dtv;
#pragma unroll
        for (int j = 0; j < 4; ++j) {
            float dA = __builtin_amdgcn_exp2f(A2[j] * dtv);
            h[j] = fmaf(dA, h[j], Bv[j] * dtx);
        }
        dtv = ndt; xv = nx;
    }
    size_t base = ((size_t)(b * NDG + dg) * 64 + c) * 1024 + tid * 4;
    *(f32x4*)(hloc + base) = (f32x4){h[0], h[1], h[2], h[3]};
    if (q == 0) sdt_out[((size_t)(b * NDG + dg) * 64 + c) * 64 + dloc] = sdt;
}

// Phase B: block-tiled wave prefix-scan over the 64 chunks (lanes = chunks).
// One block per (b, dg, dloc): tile = 64 c x 16 n, LDS-transposed, 6-step shfl compose.
__global__ __launch_bounds__(256) void k_scan_b(float* __restrict__ hloc, const float* __restrict__ sdt,
                                                const float* __restrict__ A_log) {
    const int tid = threadIdx.x;
    const int idx = blockIdx.x;
    const int b = idx / (NDG * 64);
    const int rem = idx % (NDG * 64);
    const int dg = rem / 64, dloc = rem % 64;
    const int d = dg * 64 + dloc;
    __shared__ float s_h[64 * 17];
    __shared__ float s_sdt[64];
    __shared__ float s_A2[16];
    const size_t gb = (size_t)(b * NDG + dg) * 64;
#pragma unroll
    for (int i = 0; i < 4; ++i) {
        int c = i * 16 + (tid >> 4), n = tid & 15;
        s_h[c * 17 + n] = hloc[(gb + c) * 1024 + dloc * 16 + n];
    }
    if (tid < 64) s_sdt[tid] = sdt[(gb + tid) * 64 + dloc];
    else if (tid < 80) s_A2[tid - 64] = -expf(A_log[(size_t)d * DST_ + (tid - 64)]) * LOG2E;
    __syncthreads();
    const int w = tid >> 6, lane = tid & 63;
#pragma unroll
    for (int nn = 0; nn < 4; ++nn) {
        int n = w * 4 + nn;
        float h = s_h[lane * 17 + n];
        float P = __builtin_amdgcn_exp2f(s_A2[n] * s_sdt[lane]);
#pragma unroll
        for (int s = 1; s < 64; s <<= 1) {
            float hp = __shfl_up(h, s);
            float Pp = __shfl_up(P, s);
            if (lane >= s) { h = fmaf(P, hp, h); P *= Pp; }
        }
        float Hi = __shfl_up(h, 1);
        if (lane == 0) Hi = 0.f;
        s_h[lane * 17 + n] = Hi;
    }
    __syncthreads();
#pragma unroll
    for (int i = 0; i < 4; ++i) {
        int c = i * 16 + (tid >> 4), n = tid & 15;
        hloc[(gb + c) * 1024 + dloc * 16 + n] = s_h[c * 17 + n];
    }
}

// Phase C: per-chunk scan from Hinit + C-dot + epilogue; B/C scaled inline.
__global__ __launch_bounds__(256) void k_scan_c(const float* __restrict__ dt, const float* __restrict__ xp,
                                                const float* __restrict__ Bm, const float* __restrict__ Cm,
                                                const float* __restrict__ xz, const float* __restrict__ A_log,
                                                const float* __restrict__ Dvec, const float* __restrict__ g3,
                                                const float* __restrict__ alphas,
                                                const float* __restrict__ Hinit, float* __restrict__ y) {
    const int tid = threadIdx.x;
    const int q = tid & 3, dloc = tid >> 2;
    const int dg = blockIdx.x, c = blockIdx.y, b = blockIdx.z;
    const int d = dg * 64 + dloc;
    const int l0 = c * CL;
    __shared__ float s_B[CL * 16], s_C[CL * 16];
    if (tid < CL * 4) {
        int rg = b * LSEQ + l0 + (tid >> 2);
        float a2 = alphas[2];
        float gB = g3[NROWS + rg];
        f32x4 Bv = *(const f32x4*)(Bm + (size_t)rg * DST_ + (tid & 3) * 4);
        f32x4 o;
#pragma unroll
        for (int k = 0; k < 4; ++k) o[k] = ((Bv[k] * a2) * gB) * (1.f / 127.f);
        *(f32x4*)(s_B + tid * 4) = o;
    } else {
        int t2 = tid - CL * 4;
        int rg = b * LSEQ + l0 + (t2 >> 2);
        float a3 = alphas[3];
        float gC = g3[2 * NROWS + rg];
        f32x4 Cv = *(const f32x4*)(Cm + (size_t)rg * DST_ + (t2 & 3) * 4);
        f32x4 o;
#pragma unroll
        for (int k = 0; k < 4; ++k) o[k] = ((Cv[k] * a3) * gC) * (1.f / 127.f);
        *(f32x4*)(s_C + t2 * 4) = o;
    }
    f32x4 Av = *(const f32x4*)(A_log + (size_t)d * DST_ + q * 4);
    float A2[4];
#pragma unroll
    for (int j = 0; j < 4; ++j) A2[j] = -expf(Av[j]) * LOG2E;
    const float Dd = Dvec[d];
    __syncthreads();
    const float* dtp = dt + (size_t)(b * LSEQ + l0) * DIN_ + d;
    const float* xpp = xp + (size_t)(b * LSEQ + l0) * DIN_ + d;
    const float* zp  = xz + (size_t)(b * LSEQ + l0) * DXZ + DIN_ + d;
    float* yp = y + (size_t)(b * LSEQ + l0) * DIN_ + d;
    size_t base = ((size_t)(b * NDG + dg) * 64 + c) * 1024 + tid * 4;
    f32x4 hv = *(const f32x4*)(Hinit + base);
    float h[4] = {hv[0], hv[1], hv[2], hv[3]};
    float dtv = *dtp, xv = *xpp, zv = *zp;
    for (int l = 0; l < CL; ++l) {
        float ndt = 0.f, nx = 0.f, nz = 0.f;
        if (l + 1 < CL) {
            ndt = dtp[(size_t)(l + 1) * DIN_];
            nx  = xpp[(size_t)(l + 1) * DIN_];
            nz  = zp[(size_t)(l + 1) * DXZ];
        }
        f32x4 Bv = *(const f32x4*)(s_B + l * 16 + q * 4);
        f32x4 Cv = *(const f32x4*)(s_C + l * 16 + q * 4);
        float dtx = dtv * xv;
        float yv = 0.f;
#pragma unroll
        for (int j = 0; j < 4; ++j) {
            float dA = __builtin_amdgcn_exp2f(A2[j] * dtv);
            h[j] = fmaf(dA, h[j], Bv[j] * dtx);
            yv = fmaf(h[j], Cv[j], yv);
        }
        yv += __shfl_xor(yv, 1);
        yv += __shfl_xor(yv, 2);
        if (q == 0) {
            float sig = 1.f / (1.f + __builtin_amdgcn_exp2f(-zv * LOG2E));
            yp[(size_t)l * DIN_] = (yv + xv * Dd) * (zv * sig);
        }
        dtv = ndt; xv = nx; zv = nz;
    }
}

// ---------------- rmsnorm(y,out_nw) + quant (bf16 out) ----------------
__global__ __launch_bounds__(256) void k_norm_y(const float* __restrict__ y,
                                                const float* __restrict__ out_nw,
                                                __hip_bfloat16* __restrict__ yq, float* __restrict__ gy) {
    const int r = blockIdx.x, tid = threadIdx.x;
    const float* yr = y + (size_t)r * DIN_;
    __shared__ float red4[8];
    float v[5];
    float ss = 0.f;
#pragma unroll
    for (int j = 0; j < 5; j++) { v[j] = yr[tid + j * 256]; ss += v[j] * v[j]; }
    float sum = block_sum4(ss, red4);
    float rms = 1.f / sqrtf(sum / DIN_ + EPS_);
    float mx = 0.f;
#pragma unroll
    for (int j = 0; j < 5; j++) {
        int i = tid + j * 256;
        v[j] = v[j] * rms * out_nw[i];
        mx = fmaxf(mx, fabsf(v[j]));
    }
    float g = fmaxf(block_max4(mx, red4 + 4), 1e-10f);
    if (tid == 0) gy[r] = g;
    float s = 127.f / g;
#pragma unroll
    for (int j = 0; j < 5; j++) {
        int i = tid + j * 256;
        yq[(size_t)r * DIN_ + i] = __float2bfloat16(fminf(fmaxf(rintf(v[j] * s), -128.f), 127.f));
    }
}

extern "C" void kernel_launch(void* const* d_in, const int* in_sizes, int n_in,
                              void* d_out, int out_size, void* d_ws, size_t ws_size,
                              hipStream_t stream) {
    (void)in_sizes; (void)n_in; (void)out_size;
    const float* x      = (const float*)d_in[0];
    const float* norm_w = (const float*)d_in[1];
    const float* in_w   = (const float*)d_in[2];
    const float* in_nw  = (const float*)d_in[3];
    const float* conv_w = (const float*)d_in[4];
    const float* conv_b = (const float*)d_in[5];
    const float* dtu_w  = (const float*)d_in[6];
    const float* dtu_nw = (const float*)d_in[7];
    const float* dtd_w  = (const float*)d_in[8];
    const float* dtd_b  = (const float*)d_in[9];
    const float* Bp_w   = (const float*)d_in[10];
    const float* Bp_nw  = (const float*)d_in[11];
    const float* Cp_w   = (const float*)d_in[12];
    const float* Cp_nw  = (const float*)d_in[13];
    const float* A_log  = (const float*)d_in[14];
    const float* Dv     = (const float*)d_in[15];
    const float* out_w  = (const float*)d_in[16];
    const float* out_nw = (const float*)d_in[17];

    float* ws = (float*)d_ws;
    float* alphas   = ws;                      // 8
    float* partials = ws + 8;                  // 5*256
    float* xq1      = ws + 8 + 5 * 256;        // bf16 activations; reused as hloc (2.62M floats)
    float* gamma1   = xq1 + (size_t)NROWS * H_;
    float* xz       = gamma1 + NROWS;
    float* xp       = xz + (size_t)NROWS * DXZ;
    float* xpn     = xp + (size_t)NROWS * DIN_;        // y (scan output)
    float* g3       = xpn + (size_t)NROWS * DIN_;
    float* dtu_out  = g3 + 3 * NROWS;                  // raw integer dots (memset 0 each call)
    float* Bmat     = dtu_out + (size_t)NROWS * DTR_;
    float* Cmat     = Bmat + (size_t)NROWS * DST_;
    float* dtb      = Cmat + (size_t)NROWS * DST_;     // later reused as yq (bf16)
    float* gy       = dtb + (size_t)NROWS * DIN_;
    float* wq_in    = gy + NROWS;                      // bf16
    float* wq_dtu   = wq_in + (size_t)DXZ * H_;        // (unused, kept for layout)
    float* wq_Bp    = wq_dtu + (size_t)DTR_ * DIN_;
    float* wq_Cp    = wq_Bp + (size_t)DST_ * DIN_;
    float* wq_out   = wq_Cp + (size_t)DST_ * DIN_;     // bf16
    float* rinv     = wq_out + (size_t)H_ * DIN_;      // NROWS
    float* wq_sk    = rinv + NROWS;                    // 51200 float slots
    float* sdt      = wq_sk + 51200;                   // 2*NDG*64*64 = 163840 floats
    size_t need = (size_t)((sdt + 2 * NDG * 64 * 64) - ws) * sizeof(float);
    if (ws_size < need) return;

    float* hloc = xq1;   // 2*20*64*1024 = 2,621,440 floats == NROWS*H_ exactly

    hipMemsetAsync(dtu_out, 0, (size_t)NROWS * 72 * sizeof(float), stream);

    const int n0 = DXZ * H_, n1 = DTR_ * DIN_, n2 = DST_ * DIN_, n3 = DST_ * DIN_, n4 = H_ * DIN_;
    hipLaunchKernelGGL(k_pre, dim3(NROWS + 5 * 256), dim3(256), 0, stream,
                       x, norm_w, in_nw, in_w, dtu_w, Bp_w, Cp_w, out_w,
                       n0, n1, n2, n3, n4, (__hip_bfloat16*)xq1, gamma1, partials);
    hipLaunchKernelGGL(absmean_final5, dim3(5), dim3(256), 0, stream, partials, n0, n1, n2, n3, n4, alphas);
    hipLaunchKernelGGL(k_quant_build, dim3(9650), dim3(256), 0, stream,
                       in_w, out_w, dtu_w, Bp_w, Cp_w, alphas,
                       (__hip_bfloat16*)wq_in, (__hip_bfloat16*)wq_out, (ushort_t*)wq_sk);

    hipLaunchKernelGGL((k_gemm_mfma<128, 128>), dim3(DXZ / 128, NROWS / 128), dim3(256), 0, stream,
                       (const ushort_t*)xq1, (const ushort_t*)wq_in, alphas + 0, gamma1,
                       (const float*)nullptr, xz, NROWS, DXZ, H_);
    hipLaunchKernelGGL(k_conv_norm, dim3(NROWS), dim3(256), 0, stream,
                       xz, conv_w, conv_b, dtu_nw, Bp_nw, Cp_nw, xp, rinv, g3);
    hipLaunchKernelGGL(k_skinny_mfma, dim3(NROWS / 64, KSPLIT), dim3(256), 0, stream,
                       xp, rinv, dtu_nw, Bp_nw, Cp_nw, g3, (const ushort_t*)wq_sk,
                       dtu_out, Bmat, Cmat);
    hipLaunchKernelGGL(k_dtd, dim3(DIN_ / 64, NROWS / 32), dim3(256), 0, stream,
                       dtu_out, dtd_w, dtd_b, g3, alphas, dtb);

    hipLaunchKernelGGL(k_scan_a, dim3(NDG, NCH, 2), dim3(256), 0, stream,
                       dtb, xp, Bmat, A_log, g3, alphas, hloc, sdt);
    hipLaunchKernelGGL(k_scan_b, dim3(2 * NDG * 64), dim3(256), 0, stream, hloc, sdt, A_log);
    hipLaunchKernelGGL(k_scan_c, dim3(NDG, NCH, 2), dim3(256), 0, stream,
                       dtb, xp, Bmat, Cmat, xz, A_log, Dv, g3, alphas, hloc, xpn /*y*/);

    hipLaunchKernelGGL(k_norm_y, dim3(NROWS), dim3(256), 0, stream, xpn /*y*/, out_nw,
                       (__hip_bfloat16*)dtb /*yq*/, gy);
    hipLaunchKernelGGL((k_gemm_mfma<64, 64>), dim3(H_ / 64, NROWS / 64), dim3(256), 0, stream,
                       (const ushort_t*)dtb /*yq*/, (const ushort_t*)wq_out, alphas + 4, gy,
                       x /*residual*/, (float*)d_out, NROWS, H_, DIN_);
}